// Round 5
// baseline (280.459 us; speedup 1.0000x reference)
//
#include <hip/hip_runtime.h>

// RelativePositionSDPA — R12: recombine R7's occupancy (Ps aliases Kb, 3
// barriers -> LDS 33936 B -> 3 blocks/CU under the ~124KB usable pool) with
// R11's inner-loop wins (XOR-swizzled tiles, gather fast-path, C-init softmax
// shift, exp2-domain, reg-prefetch staging).
//
// Pool model (4 data points): R7 38400B->3blk(37.9%), R9 47616->2(20.3%),
// R10 26624->4(44.4%), R11 42496->2(19.6%) => usable ~124KB. R11 beat R7
// (92.4 vs 102) DESPITE losing a block; R12 takes both.
//
// Barrier C restored => ring WAR race gone => band() writes the ring directly
// (R7-proven), deleting ringW regs; A->B window is just stageWrite.
// Ordering: content Kb-reads < C < Ps-writes(alias Kb); pA/PV/band < A' <
// stageWrite'; ring writes (post-C) < B' < next gathers.
//
// Shift algebra unchanged (verified R0..R11): e = b-a, u = (e>0), ring col
// c = e-1-u, slot = c&127, row i = ii+u, zero at e==1. Fixed-shift softmax
// p = 2^(s' - 57.7078), s' = log2e*s (C-init = -57.7078); l = sum(p) via
// Vt ones-row 64 in the PV MFMA (ct=4; garbage B-rows 65..79 only affect
// output columns that are never read).

#define SQ    1024
#define HD    64
#define NHD   16
#define RMAX  2048

typedef _Float16 f16x8 __attribute__((ext_vector_type(8)));
typedef _Float16 f16x4 __attribute__((ext_vector_type(4)));
typedef short    b16x8 __attribute__((ext_vector_type(8)));
typedef float    f32x4 __attribute__((ext_vector_type(4)));

#define MFMA_F16(A,B,C)  __builtin_amdgcn_mfma_f32_16x16x32_f16((A),(B),(C),0,0,0)
#define MFMA_BF16(A,B,C) __builtin_amdgcn_mfma_f32_16x16x32_bf16((A),(B),(C),0,0,0)

#define L2E    1.44269504088896f    // log2(e)
#define NSHIFT (-57.7078016f)       // -40 * log2(e)

// ws layout
#define KH_OFF   0                       // f16 [64][1024][64]   8 MB
#define VT_OFF   (8u << 20)              // bf16 [64][80][1024]  10 MB
#define R16_OFF  (18u << 20)             // f16 [16][1024][64]   2 MB
#define WS_NEED  (20u << 20)

__device__ __forceinline__ float exp2fast(float x) {
#if __has_builtin(__builtin_amdgcn_exp2f)
  return __builtin_amdgcn_exp2f(x);          // v_exp_f32 (2^x native)
#else
  return __expf(x * 0.693147180559945f);
#endif
}

__device__ __forceinline__ short f2b(float f) {          // fp32 -> bf16 RTN-even
  unsigned u = __builtin_bit_cast(unsigned, f);
  u += 0x7FFFu + ((u >> 16) & 1u);
  return (short)(u >> 16);
}
__device__ __forceinline__ unsigned pkh(float a, float b) {  // 2xf32 -> packed f16 RTN
  _Float16 h0 = (_Float16)a, h1 = (_Float16)b;
  return (unsigned)__builtin_bit_cast(unsigned short, h0)
       | ((unsigned)__builtin_bit_cast(unsigned short, h1) << 16);
}
// 2xf32 -> packed bf16, round-half-away (differs from RTN-even only on ties)
__device__ __forceinline__ unsigned pkb2(float a, float b) {
  unsigned ua = __builtin_bit_cast(unsigned, a) + 0x8000u;
  unsigned ub = __builtin_bit_cast(unsigned, b) + 0x8000u;
  return (ub & 0xFFFF0000u) | (ua >> 16);
}
// XOR-swizzled element address inside a [rows][64] 2B-elem tile.
__device__ __forceinline__ int swz(int row, int col) {
  return row*64 + ((((col >> 3) ^ row) & 7) << 3) + (col & 7);
}

// ---------------- merged precompute kernel (unchanged) ----------------
// blocks [0,1024): V transpose+cvt (n = b>>4, seg = b&15)
// blocks [1024,6144): K and R fp32->f16 copies

__global__ __launch_bounds__(256) void preprep(
    const float* __restrict__ K, const float* __restrict__ R,
    const float* __restrict__ V,
    _Float16* __restrict__ Kh, _Float16* __restrict__ R16,
    short* __restrict__ Vt)
{
  __shared__ float t[64][65];
  const int bid = blockIdx.x, tid = threadIdx.x;
  if (bid < 1024) {
    const int n = bid >> 4, st = bid & 15;
    {
      const int row = tid >> 2, c0 = (tid & 3) * 16;
      const float* src = V + ((size_t)n * SQ + st * 64 + row) * HD + c0;
#pragma unroll
      for (int i = 0; i < 4; ++i) {
        float4 x = ((const float4*)src)[i];
        t[row][c0 + 4*i + 0] = x.x; t[row][c0 + 4*i + 1] = x.y;
        t[row][c0 + 4*i + 2] = x.z; t[row][c0 + 4*i + 3] = x.w;
      }
    }
    __syncthreads();
    {
      const int d = tid >> 2, s0 = (tid & 3) * 16;
      short* dst = Vt + ((size_t)n * 80 + d) * SQ + st * 64 + s0;
#pragma unroll
      for (int i = 0; i < 8; ++i)
        *(unsigned*)(dst + 2*i) = pkb2(t[s0 + 2*i][d], t[s0 + 2*i + 1][d]);
    }
    if (tid < 64) {          // ones row (l accumulator) + zero pad rows
      const int s = st * 64 + tid;
      Vt[((size_t)n * 80 + 64) * SQ + s] = (short)0x3F80;
#pragma unroll
      for (int r = 65; r < 80; ++r) Vt[((size_t)n * 80 + r) * SQ + s] = 0;
    }
  } else {
    const int idx = (bid - 1024) * 256 + tid;            // float4 index
    const int nk4 = (64 * SQ * HD) / 4;                  // 1048576
    if (idx < nk4) {
      float4 v = ((const float4*)K)[idx];
      f16x4 o = { (_Float16)v.x, (_Float16)v.y, (_Float16)v.z, (_Float16)v.w };
      *(f16x4*)(Kh + 4 * (size_t)idx) = o;
    } else {
      int rr = idx - nk4;                                // < 262144
      int h  = rr >> 14, off = rr & 16383;               // 16384 float4/head
      float4 v = ((const float4*)R)[((size_t)h << 15) + off];  // src stride 2048 rows
      f16x4 o = { (_Float16)v.x, (_Float16)v.y, (_Float16)v.z, (_Float16)v.w };
      *(f16x4*)(R16 + 4 * (((size_t)h << 14) + off)) = o;
    }
  }
}

// ---------------- main flash kernel (R12) ----------------

__global__ __launch_bounds__(256, 4) void relpos_sdpa_r12(
    const float* __restrict__ Q, const _Float16* __restrict__ Kh,
    const short* __restrict__ Vtg, const _Float16* __restrict__ R16,
    const float* __restrict__ Ub, const float* __restrict__ Vb,
    float* __restrict__ O)
{
  const int n    = blockIdx.x;
  const int h    = n & (NHD - 1);
  const int a0   = blockIdx.y * 64;
  const int tid  = threadIdx.x;
  const int lane = tid & 63, wave = tid >> 6;
  const int l15  = lane & 15, quad = lane >> 4;

  const float*    Qn  = Q   + (size_t)n * SQ * HD;
  const _Float16* Khn = Kh  + (size_t)n * SQ * HD;
  const short*    Vgn = Vtg + (size_t)n * 80 * SQ;
  const _Float16* Rh  = R16 + (size_t)h * SQ * HD;

  // LDS (fragment tiles stride-64 + XOR swizzle):
  //   Kb f16 [64][64]  8192 B @ 0      (Ps u16 [64][64] ALIASES Kb after C)
  //   Vt bf16[65][64]  8320 B @ 8192   (ct=4 over-reads rows 65..79 -> ring
  //                                     region; garbage cols never read)
  //   ring u32 [33][132] 17424 B @ 16512
  // total 33936 B -> 3 blocks/CU at the measured ~124KB usable pool.
  __shared__ __align__(16) char lds[33936];
  _Float16*       Kb   = (_Float16*)lds;
  unsigned short* Ps   = (unsigned short*)lds;           // alias of Kb
  short*          Vt   = (short*)(lds + 8192);
  unsigned*       Pb2  = (unsigned*)(lds + 16512);
  const _Float16* Pb2h = (const _Float16*)Pb2;

  // ---- persistent q fragments, pre-scaled by log2(e) ----
  // (A-layout: m=l15, k=quad*8+j, frag per 32-k)
  f16x8 quF[2], qvF[5][2];
#pragma unroll
  for (int ks = 0; ks < 2; ++ks) {
    const int db = ks * 32 + quad * 8;
    float ub[8], vb[8];
#pragma unroll
    for (int j = 0; j < 8; ++j) {
      ub[j] = Ub[h*HD + db + j] * L2E;
      vb[j] = Vb[h*HD + db + j] * L2E;
    }
    {
      const float* p = Qn + (size_t)(a0 + 16*wave + l15) * HD + db;
      float4 x0 = ((const float4*)p)[0], x1 = ((const float4*)p)[1];
      f16x8 f;
#pragma unroll
      for (int t = 0; t < 4; ++t) {
        f[t]   = (_Float16)((&x0.x)[t] * (0.125f * L2E) + ub[t]);
        f[t+4] = (_Float16)((&x1.x)[t] * (0.125f * L2E) + ub[t+4]);
      }
      quF[ks] = f;
    }
#pragma unroll
    for (int rt = 0; rt < 5; ++rt) {
      int row = a0 + 16*rt + l15; if (row > SQ-1) row = SQ-1;  // clamp rows unused
      const float* p = Qn + (size_t)row * HD + db;
      float4 x0 = ((const float4*)p)[0], x1 = ((const float4*)p)[1];
      f16x8 f;
#pragma unroll
      for (int t = 0; t < 4; ++t) {
        f[t]   = (_Float16)((&x0.x)[t] * (0.125f * L2E) + vb[t]);
        f[t+4] = (_Float16)((&x1.x)[t] * (0.125f * L2E) + vb[t+4]);
      }
      qvF[rt][ks] = f;
    }
  }

  if (tid < 64) Vt[swz(64, tid)] = (short)0x3F80;   // ones row (row 64: swz = id)

  f32x4 Oacc[5];
#pragma unroll
  for (int ct = 0; ct < 5; ++ct) Oacc[ct] = (f32x4){0.f, 0.f, 0.f, 0.f};

  // ---- band: B-frags from precomputed f16 R16; ring written DIRECTLY
  //      (safe: called post-C, next gathers are post-B') ----
  auto band = [&](int jstart) {
    const int c    = jstart + 16*wave + l15;
    const int j    = (c + 2048) & (SQ - 1);
    const int slot = (c + 2048) & 127;
    const _Float16* rp = Rh + (size_t)j * HD + quad * 8;
    f16x8 B0 = *(const f16x8*)rp;
    f16x8 B1 = *(const f16x8*)(rp + 32);
#pragma unroll
    for (int rt = 0; rt < 5; ++rt) {
      f32x4 acc = (f32x4){0.f, 0.f, 0.f, 0.f};
      acc = MFMA_F16(qvF[rt][0], B0, acc);
      acc = MFMA_F16(qvF[rt][1], B1, acc);
      if (rt < 4) {
        const int rp0 = 8*rt + 2*quad;                 // rows 16rt+4q .. +3
        Pb2[rp0*132 + slot]       = pkh(acc[0], acc[1]);
        Pb2[(rp0 + 1)*132 + slot] = pkh(acc[2], acc[3]);
      } else if (quad == 0) {
        Pb2[32*132 + slot] = pkh(acc[0], acc[1]);      // row 64
      }
    }
  };

  // prologue: fill all 128 ring slots for iter 0 (pre-loop, no races)
  band(-a0 - 65);
  band(-a0 - 1);

  // ---- T14 prefetch regs (row = lane, chunks wave / wave+4) ----
  f16x8 kPre[2]; b16x8 vPre[2];
  auto stageLoad = [&](int k0) {
    const _Float16* ks = Khn + (size_t)(k0 + lane) * HD + wave*8;
    kPre[0] = *(const f16x8*)ks;
    kPre[1] = *(const f16x8*)(ks + 32);
    const short* vs = Vgn + (size_t)lane * SQ + k0 + wave*8;
    vPre[0] = *(const b16x8*)vs;
    vPre[1] = *(const b16x8*)(vs + 32);
  };
  auto stageWrite = [&]() {
    *(f16x8*)&Kb[swz(lane, wave*8)]      = kPre[0];
    *(f16x8*)&Kb[swz(lane, 32 + wave*8)] = kPre[1];
    *(b16x8*)&Vt[swz(lane, wave*8)]      = vPre[0];
    *(b16x8*)&Vt[swz(lane, 32 + wave*8)] = vPre[1];
  };

  stageLoad(0);

  const int iiB = 16*wave + 4*quad;

  for (int k0 = 0; k0 < SQ; k0 += 64) {
    __syncthreads();   // A: prev iter's Ps(pA)/Vt reads done -> safe to clobber

    stageWrite();                     // tile k0 regs -> LDS (Kb clobbers Ps)

    __syncthreads();   // B: Kb/Vt staged + ring writes (post-C of prev) visible

    if (k0 < SQ - 64) stageLoad(k0 + 64);   // prefetch next tile (used next A)

    // ---- content scores (C-init = softmax shift) ----
    f32x4 sc[4];
#pragma unroll
    for (int ct = 0; ct < 4; ++ct) {
      f16x8 b0 = *(const f16x8*)&Kb[swz(16*ct + l15, quad*8)];
      f16x8 b1 = *(const f16x8*)&Kb[swz(16*ct + l15, 32 + quad*8)];
      f32x4 acc = (f32x4){NSHIFT, NSHIFT, NSHIFT, NSHIFT};
      acc = MFMA_F16(quF[0], b0, acc);
      acc = MFMA_F16(quF[1], b1, acc);
      sc[ct] = acc;
    }

    // ---- ring gather + exp2 (specialized: dlt = 64*s; u/zero-check uniform
    //      except s in {0,1}) ----
    const int dlt = k0 - a0;
    if (dlt == 0 || dlt == 64) {
      // general path (2 of 16 iterations at most)
#pragma unroll
      for (int r = 0; r < 4; ++r) {
        const int ii = iiB + r;
        const int adA = (ii >> 1) * 264 + (ii & 1);              // u=0 row base
        const int adB = ((ii + 1) >> 1) * 264 + ((ii + 1) & 1);  // u=1 row base
#pragma unroll
        for (int ct = 0; ct < 4; ++ct) {
          const int e    = dlt + 16*ct + l15 - ii;
          const int u    = (e > 0) ? 1 : 0;
          const int slot = (e - 1 - u) & 127;
          float pos = (float)Pb2h[(u ? adB : adA) + 2*slot];
          float s   = sc[ct][r] + ((e == 1) ? 0.f : pos);
          sc[ct][r] = exp2fast(s);
        }
      }
    } else {
      const int uu    = (dlt > 0) ? 1 : 0;
      const int cbase = dlt - 1 - uu + l15 - iiB + 2048;   // + (-r) per row
#pragma unroll
      for (int r = 0; r < 4; ++r) {
        const int iu = iiB + r + uu;
        const int ad = (iu >> 1) * 264 + (iu & 1);
        const int c0 = cbase - r;
#pragma unroll
        for (int ct = 0; ct < 4; ++ct) {
          const int slot = (c0 + 16*ct) & 127;
          float pos = (float)Pb2h[ad + 2*slot];
          sc[ct][r] = exp2fast(sc[ct][r] + pos);
        }
      }
    }

    __syncthreads();   // C: all waves' Kb content-reads + ring gathers done

    // ---- Ps (aliases Kb; swizzled; wave-private rows) ----
#pragma unroll
    for (int r = 0; r < 4; ++r) {
      unsigned w0 = pkb2(sc[0][r], sc[1][r]);
      unsigned w1 = pkb2(sc[2][r], sc[3][r]);
      const int row = iiB + r;
      Ps[swz(row, l15)]      = (unsigned short)w0;
      Ps[swz(row, 16 + l15)] = (unsigned short)(w0 >> 16);
      Ps[swz(row, 32 + l15)] = (unsigned short)w1;
      Ps[swz(row, 48 + l15)] = (unsigned short)(w1 >> 16);
    }

    b16x8 pA0 = *(const b16x8*)&Ps[swz(16*wave + l15, quad*8)];
    b16x8 pA1 = *(const b16x8*)&Ps[swz(16*wave + l15, 32 + quad*8)];
#pragma unroll
    for (int ct = 0; ct < 5; ++ct) {       // ct=4: ones row -> l = sum(p)
      b16x8 v0 = *(const b16x8*)&Vt[swz(16*ct + l15, quad*8)];
      b16x8 v1 = *(const b16x8*)&Vt[swz(16*ct + l15, 32 + quad*8)];
      Oacc[ct] = MFMA_BF16(pA0, v0, Oacc[ct]);
      Oacc[ct] = MFMA_BF16(pA1, v1, Oacc[ct]);
    }

    if (k0 < SQ - 64) band(k0 + 64 - a0 - 1);   // next iter's 64 new ring cols
  }

  // ---- epilogue: O = Oacc / l, l broadcast from l15==0 lane of own quad ----
#pragma unroll
  for (int r = 0; r < 4; ++r) {
    float l   = __shfl(Oacc[4][r], lane & 48);
    float inv = 1.0f / l;
    const size_t rowo = (size_t)n * SQ * HD + (size_t)(a0 + iiB + r) * HD;
#pragma unroll
    for (int ct = 0; ct < 4; ++ct)
      O[rowo + 16*ct + l15] = Oacc[ct][r] * inv;
  }
}

// ---------------- fallback (R3-style, raw inputs) for small ws ----------------

__global__ __launch_bounds__(256, 4) void relpos_sdpa_fb(
    const float* __restrict__ Q, const float* __restrict__ K,
    const float* __restrict__ V, const float* __restrict__ Ub,
    const float* __restrict__ Vb, const float* __restrict__ R,
    float* __restrict__ O)
{
  const int n    = blockIdx.x;
  const int h    = n & (NHD - 1);
  const int a0   = blockIdx.y * 64;
  const int tid  = threadIdx.x;
  const int lane = tid & 63, wave = tid >> 6;
  const int l15  = lane & 15, quad = lane >> 4;

  const float* Qn = Q + (size_t)n * SQ * HD;
  const float* Kn = K + (size_t)n * SQ * HD;
  const float* Vn = V + (size_t)n * SQ * HD;
  const float* Rh = R + (size_t)h * RMAX * HD;

  __shared__ __align__(16) char lds[38656];
  _Float16* Kb = (_Float16*)lds;
  short*    Ps = (short*)lds;
  short*    Vt = (short*)(lds + 9216);
  _Float16* Pb = (_Float16*)(lds + 9216 + 11520);

  f16x8 quF[2], qvF[5][2];
#pragma unroll
  for (int ks = 0; ks < 2; ++ks) {
    const int db = ks * 32 + quad * 8;
    float ub[8], vb[8];
#pragma unroll
    for (int j = 0; j < 8; ++j) { ub[j] = Ub[h*HD + db + j]; vb[j] = Vb[h*HD + db + j]; }
    {
      const float* p = Qn + (size_t)(a0 + 16*wave + l15) * HD + db;
      f16x8 f;
#pragma unroll
      for (int j = 0; j < 8; ++j) f[j] = (_Float16)(p[j] * 0.125f + ub[j]);
      quF[ks] = f;
    }
#pragma unroll
    for (int rt = 0; rt < 5; ++rt) {
      int row = a0 + 16*rt + l15; if (row > SQ-1) row = SQ-1;
      const float* p = Qn + (size_t)row * HD + db;
      f16x8 f;
#pragma unroll
      for (int j = 0; j < 8; ++j) f[j] = (_Float16)(p[j] * 0.125f + vb[j]);
      qvF[rt][ks] = f;
    }
  }

  if (tid < 64) Vt[64*72 + tid] = (short)0x3F80;

  f32x4 Oacc[5];
#pragma unroll
  for (int ct = 0; ct < 5; ++ct) Oacc[ct] = (f32x4){0.f, 0.f, 0.f, 0.f};

  auto band = [&](int jstart) {
    const int c    = jstart + 16*wave + l15;
    const int j    = (c + 2048) & (SQ - 1);
    const int slot = (c + 2048) & 127;
    const float* rp = Rh + (size_t)j * HD + quad * 8;
    f16x8 B0, B1;
    {
      float4 x0 = *(const float4*)(rp),      x1 = *(const float4*)(rp + 4);
      float4 y0 = *(const float4*)(rp + 32), y1 = *(const float4*)(rp + 36);
#pragma unroll
      for (int t = 0; t < 4; ++t) { B0[t] = (_Float16)(&x0.x)[t]; B0[t+4] = (_Float16)(&x1.x)[t]; }
#pragma unroll
      for (int t = 0; t < 4; ++t) { B1[t] = (_Float16)(&y0.x)[t]; B1[t+4] = (_Float16)(&y1.x)[t]; }
    }
#pragma unroll
    for (int rt = 0; rt < 5; ++rt) {
      f32x4 acc = (f32x4){0.f, 0.f, 0.f, 0.f};
      acc = MFMA_F16(qvF[rt][0], B0, acc);
      acc = MFMA_F16(qvF[rt][1], B1, acc);
      const int row = 16*rt + 4*quad;
      if (rt < 4) {
        *(unsigned*)&Pb[slot*70 + row]     = pkh(acc[0], acc[1]);
        *(unsigned*)&Pb[slot*70 + row + 2] = pkh(acc[2], acc[3]);
      } else if (quad == 0) {
        *(unsigned*)&Pb[slot*70 + row]     = pkh(acc[0], acc[1]);
      }
    }
  };

  band(-a0 - 65);
  band(-a0 - 1);

  const int sr = tid >> 2, sc4 = tid & 3;
  const int iiB = 16*wave + 4*quad;

  for (int k0 = 0; k0 < SQ; k0 += 64) {
    __syncthreads();
    {
      const float* src = Kn + (size_t)(k0 + sr) * HD + sc4 * 16;
      float4 x0 = *(const float4*)(src),     x1 = *(const float4*)(src + 4);
      float4 y0 = *(const float4*)(src + 8), y1 = *(const float4*)(src + 12);
      f16x8 lo, hi;
#pragma unroll
      for (int t = 0; t < 4; ++t) { lo[t] = (_Float16)(&x0.x)[t]; lo[t+4] = (_Float16)(&x1.x)[t]; }
#pragma unroll
      for (int t = 0; t < 4; ++t) { hi[t] = (_Float16)(&y0.x)[t]; hi[t+4] = (_Float16)(&y1.x)[t]; }
      *(f16x8*)&Kb[sr*72 + sc4*16]     = lo;
      *(f16x8*)&Kb[sr*72 + sc4*16 + 8] = hi;
    }
    {
      const int g = lane >> 3;
#pragma unroll
      for (int i = 0; i < 8; ++i) {
        int bp = 8*wave + (i ^ g);
        float v0 = Vn[(size_t)(k0 + 2*bp)     * HD + lane];
        float v1 = Vn[(size_t)(k0 + 2*bp + 1) * HD + lane];
        *(unsigned*)&Vt[lane*72 + 2*bp] = pkb2(v0, v1);
      }
    }
    __syncthreads();

    f32x4 sc[4];
#pragma unroll
    for (int ct = 0; ct < 4; ++ct) {
      f16x8 b0 = *(const f16x8*)&Kb[(16*ct + l15)*72 + quad*8];
      f16x8 b1 = *(const f16x8*)&Kb[(16*ct + l15)*72 + 32 + quad*8];
      f32x4 acc = (f32x4){0.f, 0.f, 0.f, 0.f};
      acc = MFMA_F16(quF[0], b0, acc);
      acc = MFMA_F16(quF[1], b1, acc);
      sc[ct] = acc;
    }

    const int dlt = k0 - a0;
#pragma unroll
    for (int r = 0; r < 4; ++r) {
      const int ii = iiB + r;
#pragma unroll
      for (int ct = 0; ct < 4; ++ct) {
        const int e    = dlt + 16*ct + l15 - ii;
        const int u    = (e > 0) ? 1 : 0;
        const int slot = (e - 1 - u + 2048) & 127;
        float pos = (float)Pb[slot*70 + ii + u];
        float s   = sc[ct][r] + ((e == 1) ? 0.f : pos);
        sc[ct][r] = __expf(s - 40.0f);
      }
    }
    __syncthreads();

#pragma unroll
    for (int r = 0; r < 4; ++r)
#pragma unroll
      for (int ct = 0; ct < 4; ++ct)
        Ps[(iiB + r)*68 + 16*ct + l15] = f2b(sc[ct][r]);

    b16x8 pA0 = *(const b16x8*)&Ps[(16*wave + l15)*68 + quad*8];
    b16x8 pA1 = *(const b16x8*)&Ps[(16*wave + l15)*68 + 32 + quad*8];
#pragma unroll
    for (int ct = 0; ct < 5; ++ct) {
      b16x8 v0 = *(const b16x8*)&Vt[(16*ct + l15)*72 + quad*8];
      b16x8 v1 = *(const b16x8*)&Vt[(16*ct + l15)*72 + 32 + quad*8];
      Oacc[ct] = MFMA_BF16(pA0, v0, Oacc[ct]);
      Oacc[ct] = MFMA_BF16(pA1, v1, Oacc[ct]);
    }

    if (k0 < SQ - 64) band(k0 + 64 - a0 - 1);
  }

#pragma unroll
  for (int r = 0; r < 4; ++r) {
    float l   = __shfl(Oacc[4][r], lane & 48);
    float inv = 1.0f / l;
    const size_t rowo = (size_t)n * SQ * HD + (size_t)(a0 + iiB + r) * HD;
#pragma unroll
    for (int ct = 0; ct < 4; ++ct)
      O[rowo + 16*ct + l15] = Oacc[ct][r] * inv;
  }
}

extern "C" void kernel_launch(void* const* d_in, const int* in_sizes, int n_in,
                              void* d_out, int out_size, void* d_ws, size_t ws_size,
                              hipStream_t stream) {
  const float* Q  = (const float*)d_in[0];
  const float* K  = (const float*)d_in[1];
  const float* V  = (const float*)d_in[2];
  const float* Ub = (const float*)d_in[3];  // (1,16,1,64)
  const float* Vb = (const float*)d_in[4];
  const float* R  = (const float*)d_in[5];  // (16,2048,64)
  float* O = (float*)d_out;

  if (ws_size >= WS_NEED) {
    _Float16* Kh  = (_Float16*)((char*)d_ws + KH_OFF);
    short*    Vt  = (short*)((char*)d_ws + VT_OFF);
    _Float16* R16 = (_Float16*)((char*)d_ws + R16_OFF);

    preprep<<<6144, 256, 0, stream>>>(K, R, V, Kh, R16, Vt);

    dim3 grid(64, 16);   // x = n (XCD locality), y = q-tile
    relpos_sdpa_r12<<<grid, 256, 0, stream>>>(Q, Kh, Vt, R16, Ub, Vb, O);
  } else {
    dim3 grid(64, 16);
    relpos_sdpa_fb<<<grid, 256, 0, stream>>>(Q, K, V, Ub, Vb, R, O);
  }
}

// Round 6
// 223.935 us; speedup vs baseline: 1.2524x; 1.2524x over previous
//
#include <hip/hip_runtime.h>

// RelativePositionSDPA — R13: R12 + __launch_bounds__(256, 3).
//
// R12 post-mortem: __launch_bounds__(256,4) capped VGPR at 128; the structure
// needs ~130. Allocator cascaded to a 64-VGPR allocation and spilled the
// persistent state (Oacc / Q-fragments / prefetch regs) to scratch every
// iteration: FETCH 23->407 MB, WRITE 16->116 MB, HBM-bound at 2.8 TB/s,
// main kernel 192us. Occupancy DID reach 3 blocks/CU (43%) — the pool model
// is confirmed; the spill killed it.
//
// Fix: min-waves 3/EU -> VGPR cap ~170 (fits ~130 live set, no spill).
// Occupancy is LDS-bound at 3 blocks/CU (33936 B vs ~124KB usable pool),
// so the looser reg cap costs nothing.
//
// Everything else identical to R12: 3-barrier schedule, Ps aliases Kb,
// XOR-swizzled tiles, direct ring writes in band(), reg-prefetch staging,
// gather fast-path, C-init softmax shift, exp2 domain.
//
// Shift algebra unchanged (verified R0..R12): e = b-a, u = (e>0), ring col
// c = e-1-u, slot = c&127, row i = ii+u, zero at e==1. Fixed-shift softmax
// p = 2^(s' - 57.7078), s' = log2e*s (C-init = -57.7078); l = sum(p) via
// Vt ones-row 64 in the PV MFMA (ct=4).

#define SQ    1024
#define HD    64
#define NHD   16
#define RMAX  2048

typedef _Float16 f16x8 __attribute__((ext_vector_type(8)));
typedef _Float16 f16x4 __attribute__((ext_vector_type(4)));
typedef short    b16x8 __attribute__((ext_vector_type(8)));
typedef float    f32x4 __attribute__((ext_vector_type(4)));

#define MFMA_F16(A,B,C)  __builtin_amdgcn_mfma_f32_16x16x32_f16((A),(B),(C),0,0,0)
#define MFMA_BF16(A,B,C) __builtin_amdgcn_mfma_f32_16x16x32_bf16((A),(B),(C),0,0,0)

#define L2E    1.44269504088896f    // log2(e)
#define NSHIFT (-57.7078016f)       // -40 * log2(e)

// ws layout
#define KH_OFF   0                       // f16 [64][1024][64]   8 MB
#define VT_OFF   (8u << 20)              // bf16 [64][80][1024]  10 MB
#define R16_OFF  (18u << 20)             // f16 [16][1024][64]   2 MB
#define WS_NEED  (20u << 20)

__device__ __forceinline__ float exp2fast(float x) {
#if __has_builtin(__builtin_amdgcn_exp2f)
  return __builtin_amdgcn_exp2f(x);          // v_exp_f32 (2^x native)
#else
  return __expf(x * 0.693147180559945f);
#endif
}

__device__ __forceinline__ short f2b(float f) {          // fp32 -> bf16 RTN-even
  unsigned u = __builtin_bit_cast(unsigned, f);
  u += 0x7FFFu + ((u >> 16) & 1u);
  return (short)(u >> 16);
}
__device__ __forceinline__ unsigned pkh(float a, float b) {  // 2xf32 -> packed f16 RTN
  _Float16 h0 = (_Float16)a, h1 = (_Float16)b;
  return (unsigned)__builtin_bit_cast(unsigned short, h0)
       | ((unsigned)__builtin_bit_cast(unsigned short, h1) << 16);
}
// 2xf32 -> packed bf16, round-half-away (differs from RTN-even only on ties)
__device__ __forceinline__ unsigned pkb2(float a, float b) {
  unsigned ua = __builtin_bit_cast(unsigned, a) + 0x8000u;
  unsigned ub = __builtin_bit_cast(unsigned, b) + 0x8000u;
  return (ub & 0xFFFF0000u) | (ua >> 16);
}
// XOR-swizzled element address inside a [rows][64] 2B-elem tile.
__device__ __forceinline__ int swz(int row, int col) {
  return row*64 + ((((col >> 3) ^ row) & 7) << 3) + (col & 7);
}

// ---------------- merged precompute kernel (unchanged) ----------------
// blocks [0,1024): V transpose+cvt (n = b>>4, seg = b&15)
// blocks [1024,6144): K and R fp32->f16 copies

__global__ __launch_bounds__(256) void preprep(
    const float* __restrict__ K, const float* __restrict__ R,
    const float* __restrict__ V,
    _Float16* __restrict__ Kh, _Float16* __restrict__ R16,
    short* __restrict__ Vt)
{
  __shared__ float t[64][65];
  const int bid = blockIdx.x, tid = threadIdx.x;
  if (bid < 1024) {
    const int n = bid >> 4, st = bid & 15;
    {
      const int row = tid >> 2, c0 = (tid & 3) * 16;
      const float* src = V + ((size_t)n * SQ + st * 64 + row) * HD + c0;
#pragma unroll
      for (int i = 0; i < 4; ++i) {
        float4 x = ((const float4*)src)[i];
        t[row][c0 + 4*i + 0] = x.x; t[row][c0 + 4*i + 1] = x.y;
        t[row][c0 + 4*i + 2] = x.z; t[row][c0 + 4*i + 3] = x.w;
      }
    }
    __syncthreads();
    {
      const int d = tid >> 2, s0 = (tid & 3) * 16;
      short* dst = Vt + ((size_t)n * 80 + d) * SQ + st * 64 + s0;
#pragma unroll
      for (int i = 0; i < 8; ++i)
        *(unsigned*)(dst + 2*i) = pkb2(t[s0 + 2*i][d], t[s0 + 2*i + 1][d]);
    }
    if (tid < 64) {          // ones row (l accumulator) + zero pad rows
      const int s = st * 64 + tid;
      Vt[((size_t)n * 80 + 64) * SQ + s] = (short)0x3F80;
#pragma unroll
      for (int r = 65; r < 80; ++r) Vt[((size_t)n * 80 + r) * SQ + s] = 0;
    }
  } else {
    const int idx = (bid - 1024) * 256 + tid;            // float4 index
    const int nk4 = (64 * SQ * HD) / 4;                  // 1048576
    if (idx < nk4) {
      float4 v = ((const float4*)K)[idx];
      f16x4 o = { (_Float16)v.x, (_Float16)v.y, (_Float16)v.z, (_Float16)v.w };
      *(f16x4*)(Kh + 4 * (size_t)idx) = o;
    } else {
      int rr = idx - nk4;                                // < 262144
      int h  = rr >> 14, off = rr & 16383;               // 16384 float4/head
      float4 v = ((const float4*)R)[((size_t)h << 15) + off];  // src stride 2048 rows
      f16x4 o = { (_Float16)v.x, (_Float16)v.y, (_Float16)v.z, (_Float16)v.w };
      *(f16x4*)(R16 + 4 * (((size_t)h << 14) + off)) = o;
    }
  }
}

// ---------------- main flash kernel (R13) ----------------

__global__ __launch_bounds__(256, 3) void relpos_sdpa_r13(
    const float* __restrict__ Q, const _Float16* __restrict__ Kh,
    const short* __restrict__ Vtg, const _Float16* __restrict__ R16,
    const float* __restrict__ Ub, const float* __restrict__ Vb,
    float* __restrict__ O)
{
  const int n    = blockIdx.x;
  const int h    = n & (NHD - 1);
  const int a0   = blockIdx.y * 64;
  const int tid  = threadIdx.x;
  const int lane = tid & 63, wave = tid >> 6;
  const int l15  = lane & 15, quad = lane >> 4;

  const float*    Qn  = Q   + (size_t)n * SQ * HD;
  const _Float16* Khn = Kh  + (size_t)n * SQ * HD;
  const short*    Vgn = Vtg + (size_t)n * 80 * SQ;
  const _Float16* Rh  = R16 + (size_t)h * SQ * HD;

  // LDS (fragment tiles stride-64 + XOR swizzle):
  //   Kb f16 [64][64]  8192 B @ 0      (Ps u16 [64][64] ALIASES Kb after C)
  //   Vt bf16[65][64]  8320 B @ 8192   (ct=4 over-reads rows 65..79 -> ring
  //                                     region; garbage cols never read)
  //   ring u32 [33][132] 17424 B @ 16512
  // total 33936 B -> 3 blocks/CU (LDS-bound; reg cap 170 not binding).
  __shared__ __align__(16) char lds[33936];
  _Float16*       Kb   = (_Float16*)lds;
  unsigned short* Ps   = (unsigned short*)lds;           // alias of Kb
  short*          Vt   = (short*)(lds + 8192);
  unsigned*       Pb2  = (unsigned*)(lds + 16512);
  const _Float16* Pb2h = (const _Float16*)Pb2;

  // ---- persistent q fragments, pre-scaled by log2(e) ----
  // (A-layout: m=l15, k=quad*8+j, frag per 32-k)
  f16x8 quF[2], qvF[5][2];
#pragma unroll
  for (int ks = 0; ks < 2; ++ks) {
    const int db = ks * 32 + quad * 8;
    float ub[8], vb[8];
#pragma unroll
    for (int j = 0; j < 8; ++j) {
      ub[j] = Ub[h*HD + db + j] * L2E;
      vb[j] = Vb[h*HD + db + j] * L2E;
    }
    {
      const float* p = Qn + (size_t)(a0 + 16*wave + l15) * HD + db;
      float4 x0 = ((const float4*)p)[0], x1 = ((const float4*)p)[1];
      f16x8 f;
#pragma unroll
      for (int t = 0; t < 4; ++t) {
        f[t]   = (_Float16)((&x0.x)[t] * (0.125f * L2E) + ub[t]);
        f[t+4] = (_Float16)((&x1.x)[t] * (0.125f * L2E) + ub[t+4]);
      }
      quF[ks] = f;
    }
#pragma unroll
    for (int rt = 0; rt < 5; ++rt) {
      int row = a0 + 16*rt + l15; if (row > SQ-1) row = SQ-1;  // clamp rows unused
      const float* p = Qn + (size_t)row * HD + db;
      float4 x0 = ((const float4*)p)[0], x1 = ((const float4*)p)[1];
      f16x8 f;
#pragma unroll
      for (int t = 0; t < 4; ++t) {
        f[t]   = (_Float16)((&x0.x)[t] * (0.125f * L2E) + vb[t]);
        f[t+4] = (_Float16)((&x1.x)[t] * (0.125f * L2E) + vb[t+4]);
      }
      qvF[rt][ks] = f;
    }
  }

  if (tid < 64) Vt[swz(64, tid)] = (short)0x3F80;   // ones row (row 64: swz = id)

  f32x4 Oacc[5];
#pragma unroll
  for (int ct = 0; ct < 5; ++ct) Oacc[ct] = (f32x4){0.f, 0.f, 0.f, 0.f};

  // ---- band: B-frags from precomputed f16 R16; ring written DIRECTLY
  //      (safe: called post-C, next gathers are post-B') ----
  auto band = [&](int jstart) {
    const int c    = jstart + 16*wave + l15;
    const int j    = (c + 2048) & (SQ - 1);
    const int slot = (c + 2048) & 127;
    const _Float16* rp = Rh + (size_t)j * HD + quad * 8;
    f16x8 B0 = *(const f16x8*)rp;
    f16x8 B1 = *(const f16x8*)(rp + 32);
#pragma unroll
    for (int rt = 0; rt < 5; ++rt) {
      f32x4 acc = (f32x4){0.f, 0.f, 0.f, 0.f};
      acc = MFMA_F16(qvF[rt][0], B0, acc);
      acc = MFMA_F16(qvF[rt][1], B1, acc);
      if (rt < 4) {
        const int rp0 = 8*rt + 2*quad;                 // rows 16rt+4q .. +3
        Pb2[rp0*132 + slot]       = pkh(acc[0], acc[1]);
        Pb2[(rp0 + 1)*132 + slot] = pkh(acc[2], acc[3]);
      } else if (quad == 0) {
        Pb2[32*132 + slot] = pkh(acc[0], acc[1]);      // row 64
      }
    }
  };

  // prologue: fill all 128 ring slots for iter 0 (pre-loop, no races)
  band(-a0 - 65);
  band(-a0 - 1);

  // ---- T14 prefetch regs (row = lane, chunks wave / wave+4) ----
  f16x8 kPre[2]; b16x8 vPre[2];
  auto stageLoad = [&](int k0) {
    const _Float16* ks = Khn + (size_t)(k0 + lane) * HD + wave*8;
    kPre[0] = *(const f16x8*)ks;
    kPre[1] = *(const f16x8*)(ks + 32);
    const short* vs = Vgn + (size_t)lane * SQ + k0 + wave*8;
    vPre[0] = *(const b16x8*)vs;
    vPre[1] = *(const b16x8*)(vs + 32);
  };
  auto stageWrite = [&]() {
    *(f16x8*)&Kb[swz(lane, wave*8)]      = kPre[0];
    *(f16x8*)&Kb[swz(lane, 32 + wave*8)] = kPre[1];
    *(b16x8*)&Vt[swz(lane, wave*8)]      = vPre[0];
    *(b16x8*)&Vt[swz(lane, 32 + wave*8)] = vPre[1];
  };

  stageLoad(0);

  const int iiB = 16*wave + 4*quad;

  for (int k0 = 0; k0 < SQ; k0 += 64) {
    __syncthreads();   // A: prev iter's Ps(pA)/Vt reads done -> safe to clobber

    stageWrite();                     // tile k0 regs -> LDS (Kb clobbers Ps)

    __syncthreads();   // B: Kb/Vt staged + ring writes (post-C of prev) visible

    if (k0 < SQ - 64) stageLoad(k0 + 64);   // prefetch next tile (used next A)

    // ---- content scores (C-init = softmax shift) ----
    f32x4 sc[4];
#pragma unroll
    for (int ct = 0; ct < 4; ++ct) {
      f16x8 b0 = *(const f16x8*)&Kb[swz(16*ct + l15, quad*8)];
      f16x8 b1 = *(const f16x8*)&Kb[swz(16*ct + l15, 32 + quad*8)];
      f32x4 acc = (f32x4){NSHIFT, NSHIFT, NSHIFT, NSHIFT};
      acc = MFMA_F16(quF[0], b0, acc);
      acc = MFMA_F16(quF[1], b1, acc);
      sc[ct] = acc;
    }

    // ---- ring gather + exp2 (specialized: dlt = 64*s; u/zero-check uniform
    //      except s in {0,1}) ----
    const int dlt = k0 - a0;
    if (dlt == 0 || dlt == 64) {
      // general path (2 of 16 iterations at most)
#pragma unroll
      for (int r = 0; r < 4; ++r) {
        const int ii = iiB + r;
        const int adA = (ii >> 1) * 264 + (ii & 1);              // u=0 row base
        const int adB = ((ii + 1) >> 1) * 264 + ((ii + 1) & 1);  // u=1 row base
#pragma unroll
        for (int ct = 0; ct < 4; ++ct) {
          const int e    = dlt + 16*ct + l15 - ii;
          const int u    = (e > 0) ? 1 : 0;
          const int slot = (e - 1 - u) & 127;
          float pos = (float)Pb2h[(u ? adB : adA) + 2*slot];
          float s   = sc[ct][r] + ((e == 1) ? 0.f : pos);
          sc[ct][r] = exp2fast(s);
        }
      }
    } else {
      const int uu    = (dlt > 0) ? 1 : 0;
      const int cbase = dlt - 1 - uu + l15 - iiB + 2048;   // + (-r) per row
#pragma unroll
      for (int r = 0; r < 4; ++r) {
        const int iu = iiB + r + uu;
        const int ad = (iu >> 1) * 264 + (iu & 1);
        const int c0 = cbase - r;
#pragma unroll
        for (int ct = 0; ct < 4; ++ct) {
          const int slot = (c0 + 16*ct) & 127;
          float pos = (float)Pb2h[ad + 2*slot];
          sc[ct][r] = exp2fast(sc[ct][r] + pos);
        }
      }
    }

    __syncthreads();   // C: all waves' Kb content-reads + ring gathers done

    // ---- Ps (aliases Kb; swizzled; wave-private rows) ----
#pragma unroll
    for (int r = 0; r < 4; ++r) {
      unsigned w0 = pkb2(sc[0][r], sc[1][r]);
      unsigned w1 = pkb2(sc[2][r], sc[3][r]);
      const int row = iiB + r;
      Ps[swz(row, l15)]      = (unsigned short)w0;
      Ps[swz(row, 16 + l15)] = (unsigned short)(w0 >> 16);
      Ps[swz(row, 32 + l15)] = (unsigned short)w1;
      Ps[swz(row, 48 + l15)] = (unsigned short)(w1 >> 16);
    }

    b16x8 pA0 = *(const b16x8*)&Ps[swz(16*wave + l15, quad*8)];
    b16x8 pA1 = *(const b16x8*)&Ps[swz(16*wave + l15, 32 + quad*8)];
#pragma unroll
    for (int ct = 0; ct < 5; ++ct) {       // ct=4: ones row -> l = sum(p)
      b16x8 v0 = *(const b16x8*)&Vt[swz(16*ct + l15, quad*8)];
      b16x8 v1 = *(const b16x8*)&Vt[swz(16*ct + l15, 32 + quad*8)];
      Oacc[ct] = MFMA_BF16(pA0, v0, Oacc[ct]);
      Oacc[ct] = MFMA_BF16(pA1, v1, Oacc[ct]);
    }

    if (k0 < SQ - 64) band(k0 + 64 - a0 - 1);   // next iter's 64 new ring cols
  }

  // ---- epilogue: O = Oacc / l, l broadcast from l15==0 lane of own quad ----
#pragma unroll
  for (int r = 0; r < 4; ++r) {
    float l   = __shfl(Oacc[4][r], lane & 48);
    float inv = 1.0f / l;
    const size_t rowo = (size_t)n * SQ * HD + (size_t)(a0 + iiB + r) * HD;
#pragma unroll
    for (int ct = 0; ct < 4; ++ct)
      O[rowo + 16*ct + l15] = Oacc[ct][r] * inv;
  }
}

// ---------------- fallback (R3-style, raw inputs) for small ws ----------------

__global__ __launch_bounds__(256, 4) void relpos_sdpa_fb(
    const float* __restrict__ Q, const float* __restrict__ K,
    const float* __restrict__ V, const float* __restrict__ Ub,
    const float* __restrict__ Vb, const float* __restrict__ R,
    float* __restrict__ O)
{
  const int n    = blockIdx.x;
  const int h    = n & (NHD - 1);
  const int a0   = blockIdx.y * 64;
  const int tid  = threadIdx.x;
  const int lane = tid & 63, wave = tid >> 6;
  const int l15  = lane & 15, quad = lane >> 4;

  const float* Qn = Q + (size_t)n * SQ * HD;
  const float* Kn = K + (size_t)n * SQ * HD;
  const float* Vn = V + (size_t)n * SQ * HD;
  const float* Rh = R + (size_t)h * RMAX * HD;

  __shared__ __align__(16) char lds[38656];
  _Float16* Kb = (_Float16*)lds;
  short*    Ps = (short*)lds;
  short*    Vt = (short*)(lds + 9216);
  _Float16* Pb = (_Float16*)(lds + 9216 + 11520);

  f16x8 quF[2], qvF[5][2];
#pragma unroll
  for (int ks = 0; ks < 2; ++ks) {
    const int db = ks * 32 + quad * 8;
    float ub[8], vb[8];
#pragma unroll
    for (int j = 0; j < 8; ++j) { ub[j] = Ub[h*HD + db + j]; vb[j] = Vb[h*HD + db + j]; }
    {
      const float* p = Qn + (size_t)(a0 + 16*wave + l15) * HD + db;
      f16x8 f;
#pragma unroll
      for (int j = 0; j < 8; ++j) f[j] = (_Float16)(p[j] * 0.125f + ub[j]);
      quF[ks] = f;
    }
#pragma unroll
    for (int rt = 0; rt < 5; ++rt) {
      int row = a0 + 16*rt + l15; if (row > SQ-1) row = SQ-1;
      const float* p = Qn + (size_t)row * HD + db;
      f16x8 f;
#pragma unroll
      for (int j = 0; j < 8; ++j) f[j] = (_Float16)(p[j] * 0.125f + vb[j]);
      qvF[rt][ks] = f;
    }
  }

  if (tid < 64) Vt[64*72 + tid] = (short)0x3F80;

  f32x4 Oacc[5];
#pragma unroll
  for (int ct = 0; ct < 5; ++ct) Oacc[ct] = (f32x4){0.f, 0.f, 0.f, 0.f};

  auto band = [&](int jstart) {
    const int c    = jstart + 16*wave + l15;
    const int j    = (c + 2048) & (SQ - 1);
    const int slot = (c + 2048) & 127;
    const float* rp = Rh + (size_t)j * HD + quad * 8;
    f16x8 B0, B1;
    {
      float4 x0 = *(const float4*)(rp),      x1 = *(const float4*)(rp + 4);
      float4 y0 = *(const float4*)(rp + 32), y1 = *(const float4*)(rp + 36);
#pragma unroll
      for (int t = 0; t < 4; ++t) { B0[t] = (_Float16)(&x0.x)[t]; B0[t+4] = (_Float16)(&x1.x)[t]; }
#pragma unroll
      for (int t = 0; t < 4; ++t) { B1[t] = (_Float16)(&y0.x)[t]; B1[t+4] = (_Float16)(&y1.x)[t]; }
    }
#pragma unroll
    for (int rt = 0; rt < 5; ++rt) {
      f32x4 acc = (f32x4){0.f, 0.f, 0.f, 0.f};
      acc = MFMA_F16(qvF[rt][0], B0, acc);
      acc = MFMA_F16(qvF[rt][1], B1, acc);
      const int row = 16*rt + 4*quad;
      if (rt < 4) {
        *(unsigned*)&Pb[slot*70 + row]     = pkh(acc[0], acc[1]);
        *(unsigned*)&Pb[slot*70 + row + 2] = pkh(acc[2], acc[3]);
      } else if (quad == 0) {
        *(unsigned*)&Pb[slot*70 + row]     = pkh(acc[0], acc[1]);
      }
    }
  };

  band(-a0 - 65);
  band(-a0 - 1);

  const int sr = tid >> 2, sc4 = tid & 3;
  const int iiB = 16*wave + 4*quad;

  for (int k0 = 0; k0 < SQ; k0 += 64) {
    __syncthreads();
    {
      const float* src = Kn + (size_t)(k0 + sr) * HD + sc4 * 16;
      float4 x0 = *(const float4*)(src),     x1 = *(const float4*)(src + 4);
      float4 y0 = *(const float4*)(src + 8), y1 = *(const float4*)(src + 12);
      f16x8 lo, hi;
#pragma unroll
      for (int t = 0; t < 4; ++t) { lo[t] = (_Float16)(&x0.x)[t]; lo[t+4] = (_Float16)(&x1.x)[t]; }
#pragma unroll
      for (int t = 0; t < 4; ++t) { hi[t] = (_Float16)(&y0.x)[t]; hi[t+4] = (_Float16)(&y1.x)[t]; }
      *(f16x8*)&Kb[sr*72 + sc4*16]     = lo;
      *(f16x8*)&Kb[sr*72 + sc4*16 + 8] = hi;
    }
    {
      const int g = lane >> 3;
#pragma unroll
      for (int i = 0; i < 8; ++i) {
        int bp = 8*wave + (i ^ g);
        float v0 = Vn[(size_t)(k0 + 2*bp)     * HD + lane];
        float v1 = Vn[(size_t)(k0 + 2*bp + 1) * HD + lane];
        *(unsigned*)&Vt[lane*72 + 2*bp] = pkb2(v0, v1);
      }
    }
    __syncthreads();

    f32x4 sc[4];
#pragma unroll
    for (int ct = 0; ct < 4; ++ct) {
      f16x8 b0 = *(const f16x8*)&Kb[(16*ct + l15)*72 + quad*8];
      f16x8 b1 = *(const f16x8*)&Kb[(16*ct + l15)*72 + 32 + quad*8];
      f32x4 acc = (f32x4){0.f, 0.f, 0.f, 0.f};
      acc = MFMA_F16(quF[0], b0, acc);
      acc = MFMA_F16(quF[1], b1, acc);
      sc[ct] = acc;
    }

    const int dlt = k0 - a0;
#pragma unroll
    for (int r = 0; r < 4; ++r) {
      const int ii = iiB + r;
#pragma unroll
      for (int ct = 0; ct < 4; ++ct) {
        const int e    = dlt + 16*ct + l15 - ii;
        const int u    = (e > 0) ? 1 : 0;
        const int slot = (e - 1 - u + 2048) & 127;
        float pos = (float)Pb[slot*70 + ii + u];
        float s   = sc[ct][r] + ((e == 1) ? 0.f : pos);
        sc[ct][r] = __expf(s - 40.0f);
      }
    }
    __syncthreads();

#pragma unroll
    for (int r = 0; r < 4; ++r)
#pragma unroll
      for (int ct = 0; ct < 4; ++ct)
        Ps[(iiB + r)*68 + 16*ct + l15] = f2b(sc[ct][r]);

    b16x8 pA0 = *(const b16x8*)&Ps[(16*wave + l15)*68 + quad*8];
    b16x8 pA1 = *(const b16x8*)&Ps[(16*wave + l15)*68 + 32 + quad*8];
#pragma unroll
    for (int ct = 0; ct < 5; ++ct) {
      b16x8 v0 = *(const b16x8*)&Vt[(16*ct + l15)*72 + quad*8];
      b16x8 v1 = *(const b16x8*)&Vt[(16*ct + l15)*72 + 32 + quad*8];
      Oacc[ct] = MFMA_BF16(pA0, v0, Oacc[ct]);
      Oacc[ct] = MFMA_BF16(pA1, v1, Oacc[ct]);
    }

    if (k0 < SQ - 64) band(k0 + 64 - a0 - 1);
  }

#pragma unroll
  for (int r = 0; r < 4; ++r) {
    float l   = __shfl(Oacc[4][r], lane & 48);
    float inv = 1.0f / l;
    const size_t rowo = (size_t)n * SQ * HD + (size_t)(a0 + iiB + r) * HD;
#pragma unroll
    for (int ct = 0; ct < 4; ++ct)
      O[rowo + 16*ct + l15] = Oacc[ct][r] * inv;
  }
}

extern "C" void kernel_launch(void* const* d_in, const int* in_sizes, int n_in,
                              void* d_out, int out_size, void* d_ws, size_t ws_size,
                              hipStream_t stream) {
  const float* Q  = (const float*)d_in[0];
  const float* K  = (const float*)d_in[1];
  const float* V  = (const float*)d_in[2];
  const float* Ub = (const float*)d_in[3];  // (1,16,1,64)
  const float* Vb = (const float*)d_in[4];
  const float* R  = (const float*)d_in[5];  // (16,2048,64)
  float* O = (float*)d_out;

  if (ws_size >= WS_NEED) {
    _Float16* Kh  = (_Float16*)((char*)d_ws + KH_OFF);
    short*    Vt  = (short*)((char*)d_ws + VT_OFF);
    _Float16* R16 = (_Float16*)((char*)d_ws + R16_OFF);

    preprep<<<6144, 256, 0, stream>>>(K, R, V, Kh, R16, Vt);

    dim3 grid(64, 16);   // x = n (XCD locality), y = q-tile
    relpos_sdpa_r13<<<grid, 256, 0, stream>>>(Q, Kh, Vt, R16, Ub, Vb, O);
  } else {
    dim3 grid(64, 16);
    relpos_sdpa_fb<<<grid, 256, 0, stream>>>(Q, K, V, Ub, Vb, R, O);
  }
}

// Round 7
// 175.262 us; speedup vs baseline: 1.6002x; 1.2777x over previous
//
#include <hip/hip_runtime.h>

// RelativePositionSDPA — R14: R11's proven 2-barrier schedule with Ps LDS
// ELIMINATED via swapped-operand QK^T.
//
// Key idea: compute sc = mfma(A=K-frag, B=Q-frag) (operand swap; both frags
// already have the (l15, quad*8+j) layout). Output is S^T: lane (quad,l15)
// holds scores for key = 16ct+4quad+r, qrow = 16w+l15. Each lane's 4 scores
// per ct are 4 CONSECUTIVE keys = exactly a K=16 MFMA A-fragment, so PV runs
// as 4x4 mfma_f32_16x16x16_bf16 consuming P straight from registers:
//   - no Ps buffer (-8.2KB), no transpose, stays 2-barrier (R11 schedule)
//   - l via ones-B MFMA (register constant) -> Vt ones row dies (-128B),
//     l lands in-lane -> epilogue shfl dies
//   - C/D layout is shape-determined: Oacc/epilogue layout unchanged
// LDS = Kb 8192 + Vt 8192 + ring 17424 = 33808 B -> 3 blocks/CU (this size
// proved 3-resident in R12/R13 at 43% occ). R12/R13's spilling 3-barrier
// alias structure is abandoned; this keeps R11's clean allocator behavior.
//
// Gather re-index: e = (k0-a0-16w) + 16ct + 4q + r - l15; general path only
// when k0-a0 in {0,64} (covers all e==1 / mixed-u cases; proof: e==1 needs
// g = k0-a0+16(ct-w) in {0,16}, which happens only at those two iters).
//
// Fixed-shift softmax p = 2^(s' - 57.7078) (C-init = NSHIFT), bf16 P values
// (range to 2^127 — f16 would overflow at s ~ 50+).

#define SQ    1024
#define HD    64
#define NHD   16
#define RMAX  2048

typedef _Float16 f16x8 __attribute__((ext_vector_type(8)));
typedef _Float16 f16x4 __attribute__((ext_vector_type(4)));
typedef short    b16x8 __attribute__((ext_vector_type(8)));
typedef short    b16x4 __attribute__((ext_vector_type(4)));
typedef float    f32x4 __attribute__((ext_vector_type(4)));
typedef unsigned u32x2 __attribute__((ext_vector_type(2)));

#define MFMA_F16(A,B,C)  __builtin_amdgcn_mfma_f32_16x16x32_f16((A),(B),(C),0,0,0)
#define MFMA_BF16(A,B,C) __builtin_amdgcn_mfma_f32_16x16x32_bf16((A),(B),(C),0,0,0)

#define L2E    1.44269504088896f    // log2(e)
#define NSHIFT (-57.7078016f)       // -40 * log2(e)

// ws layout
#define KH_OFF   0                       // f16 [64][1024][64]   8 MB
#define VT_OFF   (8u << 20)              // bf16 [64][80][1024]  10 MB
#define R16_OFF  (18u << 20)             // f16 [16][1024][64]   2 MB
#define WS_NEED  (20u << 20)

__device__ __forceinline__ float exp2fast(float x) {
#if __has_builtin(__builtin_amdgcn_exp2f)
  return __builtin_amdgcn_exp2f(x);          // v_exp_f32 (2^x native)
#else
  return __expf(x * 0.693147180559945f);
#endif
}

// K=16 bf16 MFMA; zero-padded K=32 fallback is mathematically identical
// (pads are zero in BOTH operands; C/D layout is shape-determined).
__device__ __forceinline__ f32x4 mfma16bf(b16x4 a, b16x4 b, f32x4 c) {
#if __has_builtin(__builtin_amdgcn_mfma_f32_16x16x16bf16_1k)
  return __builtin_amdgcn_mfma_f32_16x16x16bf16_1k(a, b, c, 0, 0, 0);
#else
  b16x8 az = {a[0], a[1], a[2], a[3], 0, 0, 0, 0};
  b16x8 bz = {b[0], b[1], b[2], b[3], 0, 0, 0, 0};
  return MFMA_BF16(az, bz, c);
#endif
}

__device__ __forceinline__ short f2b(float f) {          // fp32 -> bf16 RTN-even
  unsigned u = __builtin_bit_cast(unsigned, f);
  u += 0x7FFFu + ((u >> 16) & 1u);
  return (short)(u >> 16);
}
__device__ __forceinline__ unsigned pkh(float a, float b) {  // 2xf32 -> packed f16 RTN
  _Float16 h0 = (_Float16)a, h1 = (_Float16)b;
  return (unsigned)__builtin_bit_cast(unsigned short, h0)
       | ((unsigned)__builtin_bit_cast(unsigned short, h1) << 16);
}
// 2xf32 -> packed bf16, round-half-away (differs from RTN-even only on ties)
__device__ __forceinline__ unsigned pkb2(float a, float b) {
  unsigned ua = __builtin_bit_cast(unsigned, a) + 0x8000u;
  unsigned ub = __builtin_bit_cast(unsigned, b) + 0x8000u;
  return (ub & 0xFFFF0000u) | (ua >> 16);
}
// XOR-swizzled element address inside a [rows][64] 2B-elem tile.
__device__ __forceinline__ int swz(int row, int col) {
  return row*64 + ((((col >> 3) ^ row) & 7) << 3) + (col & 7);
}

// ---------------- merged precompute kernel (unchanged) ----------------

__global__ __launch_bounds__(256) void preprep(
    const float* __restrict__ K, const float* __restrict__ R,
    const float* __restrict__ V,
    _Float16* __restrict__ Kh, _Float16* __restrict__ R16,
    short* __restrict__ Vt)
{
  __shared__ float t[64][65];
  const int bid = blockIdx.x, tid = threadIdx.x;
  if (bid < 1024) {
    const int n = bid >> 4, st = bid & 15;
    {
      const int row = tid >> 2, c0 = (tid & 3) * 16;
      const float* src = V + ((size_t)n * SQ + st * 64 + row) * HD + c0;
#pragma unroll
      for (int i = 0; i < 4; ++i) {
        float4 x = ((const float4*)src)[i];
        t[row][c0 + 4*i + 0] = x.x; t[row][c0 + 4*i + 1] = x.y;
        t[row][c0 + 4*i + 2] = x.z; t[row][c0 + 4*i + 3] = x.w;
      }
    }
    __syncthreads();
    {
      const int d = tid >> 2, s0 = (tid & 3) * 16;
      short* dst = Vt + ((size_t)n * 80 + d) * SQ + st * 64 + s0;
#pragma unroll
      for (int i = 0; i < 8; ++i)
        *(unsigned*)(dst + 2*i) = pkb2(t[s0 + 2*i][d], t[s0 + 2*i + 1][d]);
    }
    if (tid < 64) {          // (rows 64..79 unused by R14 main; kept harmless)
      const int s = st * 64 + tid;
      Vt[((size_t)n * 80 + 64) * SQ + s] = (short)0x3F80;
#pragma unroll
      for (int r = 65; r < 80; ++r) Vt[((size_t)n * 80 + r) * SQ + s] = 0;
    }
  } else {
    const int idx = (bid - 1024) * 256 + tid;            // float4 index
    const int nk4 = (64 * SQ * HD) / 4;                  // 1048576
    if (idx < nk4) {
      float4 v = ((const float4*)K)[idx];
      f16x4 o = { (_Float16)v.x, (_Float16)v.y, (_Float16)v.z, (_Float16)v.w };
      *(f16x4*)(Kh + 4 * (size_t)idx) = o;
    } else {
      int rr = idx - nk4;                                // < 262144
      int h  = rr >> 14, off = rr & 16383;               // 16384 float4/head
      float4 v = ((const float4*)R)[((size_t)h << 15) + off];
      f16x4 o = { (_Float16)v.x, (_Float16)v.y, (_Float16)v.z, (_Float16)v.w };
      *(f16x4*)(R16 + 4 * (((size_t)h << 14) + off)) = o;
    }
  }
}

// ---------------- main flash kernel (R14) ----------------

__global__ __launch_bounds__(256, 3) void relpos_sdpa_r14(
    const float* __restrict__ Q, const _Float16* __restrict__ Kh,
    const short* __restrict__ Vtg, const _Float16* __restrict__ R16,
    const float* __restrict__ Ub, const float* __restrict__ Vb,
    float* __restrict__ O)
{
  const int n    = blockIdx.x;
  const int h    = n & (NHD - 1);
  const int a0   = blockIdx.y * 64;
  const int tid  = threadIdx.x;
  const int lane = tid & 63, wave = tid >> 6;
  const int l15  = lane & 15, quad = lane >> 4;

  const float*    Qn  = Q   + (size_t)n * SQ * HD;
  const _Float16* Khn = Kh  + (size_t)n * SQ * HD;
  const short*    Vgn = Vtg + (size_t)n * 80 * SQ;
  const _Float16* Rh  = R16 + (size_t)h * SQ * HD;

  // LDS: Kb f16 [64][64] swz 8192 @ 0
  //      Vt bf16 [64][64] swz 8192 @ 8192      (no ones row needed)
  //      ring u32 [33][132] 17424 @ 16384
  // total 33808 B -> 3 blocks/CU (proven resident x3 at this size).
  __shared__ __align__(16) char lds[33808];
  _Float16*       Kb   = (_Float16*)lds;
  short*          Vt   = (short*)(lds + 8192);
  unsigned*       Pb2  = (unsigned*)(lds + 16384);
  const _Float16* Pb2h = (const _Float16*)Pb2;

  // ---- persistent q fragments, pre-scaled by log2(e) ----
  f16x8 quF[2], qvF[5][2];
#pragma unroll
  for (int ks = 0; ks < 2; ++ks) {
    const int db = ks * 32 + quad * 8;
    float ub[8], vb[8];
#pragma unroll
    for (int j = 0; j < 8; ++j) {
      ub[j] = Ub[h*HD + db + j] * L2E;
      vb[j] = Vb[h*HD + db + j] * L2E;
    }
    {
      const float* p = Qn + (size_t)(a0 + 16*wave + l15) * HD + db;
      float4 x0 = ((const float4*)p)[0], x1 = ((const float4*)p)[1];
      f16x8 f;
#pragma unroll
      for (int t = 0; t < 4; ++t) {
        f[t]   = (_Float16)((&x0.x)[t] * (0.125f * L2E) + ub[t]);
        f[t+4] = (_Float16)((&x1.x)[t] * (0.125f * L2E) + ub[t+4]);
      }
      quF[ks] = f;
    }
#pragma unroll
    for (int rt = 0; rt < 5; ++rt) {
      int row = a0 + 16*rt + l15; if (row > SQ-1) row = SQ-1;
      const float* p = Qn + (size_t)row * HD + db;
      float4 x0 = ((const float4*)p)[0], x1 = ((const float4*)p)[1];
      f16x8 f;
#pragma unroll
      for (int t = 0; t < 4; ++t) {
        f[t]   = (_Float16)((&x0.x)[t] * (0.125f * L2E) + vb[t]);
        f[t+4] = (_Float16)((&x1.x)[t] * (0.125f * L2E) + vb[t+4]);
      }
      qvF[rt][ks] = f;
    }
  }

  f32x4 Oacc[4], acc_l;
#pragma unroll
  for (int ct = 0; ct < 4; ++ct) Oacc[ct] = (f32x4){0.f, 0.f, 0.f, 0.f};
  acc_l = (f32x4){0.f, 0.f, 0.f, 0.f};

  const b16x4 ONESB = {(short)0x3F80, (short)0x3F80, (short)0x3F80, (short)0x3F80};

  // ---- band: MFMA into regs; ring write deferred (ringFlush, R11-proven) ----
  unsigned ringW[9];
  int ringSlot;
  auto band = [&](int jstart) {
    const int c    = jstart + 16*wave + l15;
    const int j    = (c + 2048) & (SQ - 1);
    ringSlot       = (c + 2048) & 127;
    const _Float16* rp = Rh + (size_t)j * HD + quad * 8;
    f16x8 B0 = *(const f16x8*)rp;
    f16x8 B1 = *(const f16x8*)(rp + 32);
#pragma unroll
    for (int rt = 0; rt < 5; ++rt) {
      f32x4 acc = (f32x4){0.f, 0.f, 0.f, 0.f};
      acc = MFMA_F16(qvF[rt][0], B0, acc);
      acc = MFMA_F16(qvF[rt][1], B1, acc);
      if (rt < 4) {
        ringW[2*rt]     = pkh(acc[0], acc[1]);
        ringW[2*rt + 1] = pkh(acc[2], acc[3]);
      } else {
        ringW[8] = pkh(acc[0], acc[1]);   // row 64 (only quad 0's used)
      }
    }
  };
  auto ringFlush = [&]() {
#pragma unroll
    for (int rt = 0; rt < 4; ++rt) {
      const int rp0 = 8*rt + 2*quad;                 // rows 16rt+4q .. +3
      Pb2[rp0*132 + ringSlot]       = ringW[2*rt];
      Pb2[(rp0 + 1)*132 + ringSlot] = ringW[2*rt + 1];
    }
    if (quad == 0) Pb2[32*132 + ringSlot] = ringW[8];
  };

  // prologue: fill all 128 ring slots for iter 0 (pre-loop, no races)
  band(-a0 - 65);  ringFlush();
  band(-a0 - 1);   ringFlush();

  // ---- T14 prefetch regs (row = lane, chunks wave / wave+4) ----
  f16x8 kPre[2]; b16x8 vPre[2];
  auto stageLoad = [&](int k0) {
    const _Float16* ks = Khn + (size_t)(k0 + lane) * HD + wave*8;
    kPre[0] = *(const f16x8*)ks;
    kPre[1] = *(const f16x8*)(ks + 32);
    const short* vs = Vgn + (size_t)lane * SQ + k0 + wave*8;
    vPre[0] = *(const b16x8*)vs;
    vPre[1] = *(const b16x8*)(vs + 32);
  };
  auto stageWrite = [&]() {
    *(f16x8*)&Kb[swz(lane, wave*8)]      = kPre[0];
    *(f16x8*)&Kb[swz(lane, 32 + wave*8)] = kPre[1];
    *(b16x8*)&Vt[swz(lane, wave*8)]      = vPre[0];
    *(b16x8*)&Vt[swz(lane, 32 + wave*8)] = vPre[1];
  };

  stageLoad(0);

  const int iiB = 16*wave + 4*quad;
  const int iQ  = 16*wave + l15;          // this lane's q-local row (swapped)

  for (int k0 = 0; k0 < SQ; k0 += 64) {
    __syncthreads();   // A: prev iter's Kb/Vt fragment reads + ring gathers done

    stageWrite();                     // tile k0 regs -> LDS
    if (k0 > 0) ringFlush();          // cols computed at end of prev iter

    __syncthreads();   // B: Kb/Vt staged + new ring cols visible

    if (k0 < SQ - 64) stageLoad(k0 + 64);   // prefetch next tile (used next A)

    // ---- content scores, SWAPPED: sc[ct][r] = S[key=16ct+4q+r][q=16w+l15] ----
    f32x4 sc[4];
#pragma unroll
    for (int ct = 0; ct < 4; ++ct) {
      f16x8 ka = *(const f16x8*)&Kb[swz(16*ct + l15, quad*8)];
      f16x8 kb = *(const f16x8*)&Kb[swz(16*ct + l15, 32 + quad*8)];
      f32x4 acc = (f32x4){NSHIFT, NSHIFT, NSHIFT, NSHIFT};
      acc = MFMA_F16(ka, quF[0], acc);        // A = K-frag, B = Q-frag
      acc = MFMA_F16(kb, quF[1], acc);
      sc[ct] = acc;
    }

    // ---- ring gather + exp2 (swapped indexing) ----
    // e = base + 16ct + 4q + r - l15, base = k0 - a0 - 16w (wave-uniform).
    // general path only when k0-a0 in {0,64} (covers all e==1 / mixed-u).
    const int base = k0 - a0 - 16*wave;
    if (k0 == a0 || k0 == a0 + 64) {
      const int adA = (iQ >> 1) * 264 + (iQ & 1);                // u=0
      const int adB = ((iQ + 1) >> 1) * 264 + ((iQ + 1) & 1);    // u=1
#pragma unroll
      for (int ct = 0; ct < 4; ++ct) {
        const int e0 = base + 16*ct + 4*quad - l15;
#pragma unroll
        for (int r = 0; r < 4; ++r) {
          const int e    = e0 + r;
          const int u    = (e > 0) ? 1 : 0;
          const int slot = (e - 1 - u) & 127;
          float pos = (float)Pb2h[(u ? adB : adA) + 2*slot];
          float s   = sc[ct][r] + ((e == 1) ? 0.f : pos);
          sc[ct][r] = exp2fast(s);
        }
      }
    } else {
      const int u  = (k0 > a0) ? 1 : 0;      // uniform; no e==1 possible here
      const int iu = iQ + u;
      const int ad = (iu >> 1) * 264 + (iu & 1);
      const int sb = base - 1 - u + 4*quad - l15 + 2048;
#pragma unroll
      for (int ct = 0; ct < 4; ++ct) {
#pragma unroll
        for (int r = 0; r < 4; ++r) {
          const int slot = (sb + 16*ct + r) & 127;
          float pos = (float)Pb2h[ad + 2*slot];
          sc[ct][r] = exp2fast(sc[ct][r] + pos);
        }
      }
    }

    // ---- PV straight from registers: 4x4 K=16 bf16 MFMAs + ones-l ----
#pragma unroll
    for (int ctk = 0; ctk < 4; ++ctk) {
      unsigned lo = pkb2(sc[ctk][0], sc[ctk][1]);
      unsigned hi = pkb2(sc[ctk][2], sc[ctk][3]);
      b16x4 aF = __builtin_bit_cast(b16x4, (u32x2){lo, hi});
      acc_l = mfma16bf(aF, ONESB, acc_l);     // l partial (all cols equal)
#pragma unroll
      for (int ctd = 0; ctd < 4; ++ctd) {
        b16x4 bF = *(const b16x4*)&Vt[swz(16*ctd + l15, 16*ctk + 4*quad)];
        Oacc[ctd] = mfma16bf(aF, bF, Oacc[ctd]);
      }
    }

    if (k0 < SQ - 64) band(k0 + 64 - a0 - 1);   // next iter's 64 new ring cols
  }

  // ---- epilogue: O = Oacc / l, l in-lane from ones-MFMA ----
#pragma unroll
  for (int r = 0; r < 4; ++r) {
    float inv = 1.0f / acc_l[r];
    const size_t rowo = (size_t)n * SQ * HD + (size_t)(a0 + iiB + r) * HD;
#pragma unroll
    for (int ct = 0; ct < 4; ++ct)
      O[rowo + 16*ct + l15] = Oacc[ct][r] * inv;
  }
}

// ---------------- fallback (R3-style, raw inputs) for small ws ----------------

__global__ __launch_bounds__(256, 4) void relpos_sdpa_fb(
    const float* __restrict__ Q, const float* __restrict__ K,
    const float* __restrict__ V, const float* __restrict__ Ub,
    const float* __restrict__ Vb, const float* __restrict__ R,
    float* __restrict__ O)
{
  const int n    = blockIdx.x;
  const int h    = n & (NHD - 1);
  const int a0   = blockIdx.y * 64;
  const int tid  = threadIdx.x;
  const int lane = tid & 63, wave = tid >> 6;
  const int l15  = lane & 15, quad = lane >> 4;

  const float* Qn = Q + (size_t)n * SQ * HD;
  const float* Kn = K + (size_t)n * SQ * HD;
  const float* Vn = V + (size_t)n * SQ * HD;
  const float* Rh = R + (size_t)h * RMAX * HD;

  __shared__ __align__(16) char lds[38656];
  _Float16* Kb = (_Float16*)lds;
  short*    Ps = (short*)lds;
  short*    Vt = (short*)(lds + 9216);
  _Float16* Pb = (_Float16*)(lds + 9216 + 11520);

  f16x8 quF[2], qvF[5][2];
#pragma unroll
  for (int ks = 0; ks < 2; ++ks) {
    const int db = ks * 32 + quad * 8;
    float ub[8], vb[8];
#pragma unroll
    for (int j = 0; j < 8; ++j) { ub[j] = Ub[h*HD + db + j]; vb[j] = Vb[h*HD + db + j]; }
    {
      const float* p = Qn + (size_t)(a0 + 16*wave + l15) * HD + db;
      f16x8 f;
#pragma unroll
      for (int j = 0; j < 8; ++j) f[j] = (_Float16)(p[j] * 0.125f + ub[j]);
      quF[ks] = f;
    }
#pragma unroll
    for (int rt = 0; rt < 5; ++rt) {
      int row = a0 + 16*rt + l15; if (row > SQ-1) row = SQ-1;
      const float* p = Qn + (size_t)row * HD + db;
      f16x8 f;
#pragma unroll
      for (int j = 0; j < 8; ++j) f[j] = (_Float16)(p[j] * 0.125f + vb[j]);
      qvF[rt][ks] = f;
    }
  }

  if (tid < 64) Vt[64*72 + tid] = (short)0x3F80;

  f32x4 Oacc[5];
#pragma unroll
  for (int ct = 0; ct < 5; ++ct) Oacc[ct] = (f32x4){0.f, 0.f, 0.f, 0.f};

  auto band = [&](int jstart) {
    const int c    = jstart + 16*wave + l15;
    const int j    = (c + 2048) & (SQ - 1);
    const int slot = (c + 2048) & 127;
    const float* rp = Rh + (size_t)j * HD + quad * 8;
    f16x8 B0, B1;
    {
      float4 x0 = *(const float4*)(rp),      x1 = *(const float4*)(rp + 4);
      float4 y0 = *(const float4*)(rp + 32), y1 = *(const float4*)(rp + 36);
#pragma unroll
      for (int t = 0; t < 4; ++t) { B0[t] = (_Float16)(&x0.x)[t]; B0[t+4] = (_Float16)(&x1.x)[t]; }
#pragma unroll
      for (int t = 0; t < 4; ++t) { B1[t] = (_Float16)(&y0.x)[t]; B1[t+4] = (_Float16)(&y1.x)[t]; }
    }
#pragma unroll
    for (int rt = 0; rt < 5; ++rt) {
      f32x4 acc = (f32x4){0.f, 0.f, 0.f, 0.f};
      acc = MFMA_F16(qvF[rt][0], B0, acc);
      acc = MFMA_F16(qvF[rt][1], B1, acc);
      const int row = 16*rt + 4*quad;
      if (rt < 4) {
        *(unsigned*)&Pb[slot*70 + row]     = pkh(acc[0], acc[1]);
        *(unsigned*)&Pb[slot*70 + row + 2] = pkh(acc[2], acc[3]);
      } else if (quad == 0) {
        *(unsigned*)&Pb[slot*70 + row]     = pkh(acc[0], acc[1]);
      }
    }
  };

  band(-a0 - 65);
  band(-a0 - 1);

  const int sr = tid >> 2, sc4 = tid & 3;
  const int iiB = 16*wave + 4*quad;

  for (int k0 = 0; k0 < SQ; k0 += 64) {
    __syncthreads();
    {
      const float* src = Kn + (size_t)(k0 + sr) * HD + sc4 * 16;
      float4 x0 = *(const float4*)(src),     x1 = *(const float4*)(src + 4);
      float4 y0 = *(const float4*)(src + 8), y1 = *(const float4*)(src + 12);
      f16x8 lo, hi;
#pragma unroll
      for (int t = 0; t < 4; ++t) { lo[t] = (_Float16)(&x0.x)[t]; lo[t+4] = (_Float16)(&x1.x)[t]; }
#pragma unroll
      for (int t = 0; t < 4; ++t) { hi[t] = (_Float16)(&y0.x)[t]; hi[t+4] = (_Float16)(&y1.x)[t]; }
      *(f16x8*)&Kb[sr*72 + sc4*16]     = lo;
      *(f16x8*)&Kb[sr*72 + sc4*16 + 8] = hi;
    }
    {
      const int g = lane >> 3;
#pragma unroll
      for (int i = 0; i < 8; ++i) {
        int bp = 8*wave + (i ^ g);
        float v0 = Vn[(size_t)(k0 + 2*bp)     * HD + lane];
        float v1 = Vn[(size_t)(k0 + 2*bp + 1) * HD + lane];
        *(unsigned*)&Vt[lane*72 + 2*bp] = pkb2(v0, v1);
      }
    }
    __syncthreads();

    f32x4 sc[4];
#pragma unroll
    for (int ct = 0; ct < 4; ++ct) {
      f16x8 b0 = *(const f16x8*)&Kb[(16*ct + l15)*72 + quad*8];
      f16x8 b1 = *(const f16x8*)&Kb[(16*ct + l15)*72 + 32 + quad*8];
      f32x4 acc = (f32x4){0.f, 0.f, 0.f, 0.f};
      acc = MFMA_F16(quF[0], b0, acc);
      acc = MFMA_F16(quF[1], b1, acc);
      sc[ct] = acc;
    }

    const int dlt = k0 - a0;
#pragma unroll
    for (int r = 0; r < 4; ++r) {
      const int ii = iiB + r;
#pragma unroll
      for (int ct = 0; ct < 4; ++ct) {
        const int e    = dlt + 16*ct + l15 - ii;
        const int u    = (e > 0) ? 1 : 0;
        const int slot = (e - 1 - u + 2048) & 127;
        float pos = (float)Pb[slot*70 + ii + u];
        float s   = sc[ct][r] + ((e == 1) ? 0.f : pos);
        sc[ct][r] = __expf(s - 40.0f);
      }
    }
    __syncthreads();

#pragma unroll
    for (int r = 0; r < 4; ++r)
#pragma unroll
      for (int ct = 0; ct < 4; ++ct)
        Ps[(iiB + r)*68 + 16*ct + l15] = f2b(sc[ct][r]);

    b16x8 pA0 = *(const b16x8*)&Ps[(16*wave + l15)*68 + quad*8];
    b16x8 pA1 = *(const b16x8*)&Ps[(16*wave + l15)*68 + 32 + quad*8];
#pragma unroll
    for (int ct = 0; ct < 5; ++ct) {
      b16x8 v0 = *(const b16x8*)&Vt[(16*ct + l15)*72 + quad*8];
      b16x8 v1 = *(const b16x8*)&Vt[(16*ct + l15)*72 + 32 + quad*8];
      Oacc[ct] = MFMA_BF16(pA0, v0, Oacc[ct]);
      Oacc[ct] = MFMA_BF16(pA1, v1, Oacc[ct]);
    }

    if (k0 < SQ - 64) band(k0 + 64 - a0 - 1);
  }

#pragma unroll
  for (int r = 0; r < 4; ++r) {
    float l   = __shfl(Oacc[4][r], lane & 48);
    float inv = 1.0f / l;
    const size_t rowo = (size_t)n * SQ * HD + (size_t)(a0 + iiB + r) * HD;
#pragma unroll
    for (int ct = 0; ct < 4; ++ct)
      O[rowo + 16*ct + l15] = Oacc[ct][r] * inv;
  }
}

extern "C" void kernel_launch(void* const* d_in, const int* in_sizes, int n_in,
                              void* d_out, int out_size, void* d_ws, size_t ws_size,
                              hipStream_t stream) {
  const float* Q  = (const float*)d_in[0];
  const float* K  = (const float*)d_in[1];
  const float* V  = (const float*)d_in[2];
  const float* Ub = (const float*)d_in[3];  // (1,16,1,64)
  const float* Vb = (const float*)d_in[4];
  const float* R  = (const float*)d_in[5];  // (16,2048,64)
  float* O = (float*)d_out;

  if (ws_size >= WS_NEED) {
    _Float16* Kh  = (_Float16*)((char*)d_ws + KH_OFF);
    short*    Vt  = (short*)((char*)d_ws + VT_OFF);
    _Float16* R16 = (_Float16*)((char*)d_ws + R16_OFF);

    preprep<<<6144, 256, 0, stream>>>(K, R, V, Kh, R16, Vt);

    dim3 grid(64, 16);   // x = n (XCD locality), y = q-tile
    relpos_sdpa_r14<<<grid, 256, 0, stream>>>(Q, Kh, Vt, R16, Ub, Vb, O);
  } else {
    dim3 grid(64, 16);
    relpos_sdpa_fb<<<grid, 256, 0, stream>>>(Q, K, V, Ub, Vb, R, O);
  }
}

// Round 8
// 170.946 us; speedup vs baseline: 1.6406x; 1.0252x over previous
//
#include <hip/hip_runtime.h>

// RelativePositionSDPA — R15: R14 + LDS-pipe surgery.
//
// R14 post-mortem: per-wave-iter LDS instruction cycles (~420) x 8 waves
// matches the 3.3K cycles/iter wall budget => LDS-THROUGHPUT-BOUND. The
// +4.2M bank-conflict delta localizes to the PV b16x4 Vt reads: bank =
// 4*chunk + 2*(quad&1) is invariant to l15 bit3, so quad0's 16 lanes use
// only 16 banks (2x conflict in 16-lane phases).
//
// R15 changes (numerics bit-identical):
//  1. Vt-only half-XOR swizzle: off = (col&7) ^ 4*(row>>3 &1). PV read bank
//     becomes 4*chunk + 2*((quad&1)^(l15>>3)) -> 16 lanes span 32 banks ->
//     conflict-free. Vt staging = 4x b64 writes (uniform 4/bank, free).
//     Kb unchanged (b16x8 QK reads would break under half-XOR; already free).
//  2. Band-load hoist: band() split into bandLoad (right after stageLoad,
//     top of compute) and bandMFMA (end). R16 L2 latency (~300cy) no longer
//     sits right before barrier A where all waves convoy on it.
//
// Everything else identical to R14: swapped-operand QK^T (S^T in regs), PV
// as 4x4 K=16 bf16 MFMAs straight from registers, ones-B MFMA for l,
// 2-barrier schedule, deferred ring flush, gather fast-path, C-init shift.

#define SQ    1024
#define HD    64
#define NHD   16
#define RMAX  2048

typedef _Float16 f16x8 __attribute__((ext_vector_type(8)));
typedef _Float16 f16x4 __attribute__((ext_vector_type(4)));
typedef short    b16x8 __attribute__((ext_vector_type(8)));
typedef short    b16x4 __attribute__((ext_vector_type(4)));
typedef float    f32x4 __attribute__((ext_vector_type(4)));
typedef unsigned u32x2 __attribute__((ext_vector_type(2)));

#define MFMA_F16(A,B,C)  __builtin_amdgcn_mfma_f32_16x16x32_f16((A),(B),(C),0,0,0)
#define MFMA_BF16(A,B,C) __builtin_amdgcn_mfma_f32_16x16x32_bf16((A),(B),(C),0,0,0)

#define L2E    1.44269504088896f    // log2(e)
#define NSHIFT (-57.7078016f)       // -40 * log2(e)

// ws layout
#define KH_OFF   0                       // f16 [64][1024][64]   8 MB
#define VT_OFF   (8u << 20)              // bf16 [64][80][1024]  10 MB
#define R16_OFF  (18u << 20)             // f16 [16][1024][64]   2 MB
#define WS_NEED  (20u << 20)

__device__ __forceinline__ float exp2fast(float x) {
#if __has_builtin(__builtin_amdgcn_exp2f)
  return __builtin_amdgcn_exp2f(x);          // v_exp_f32 (2^x native)
#else
  return __expf(x * 0.693147180559945f);
#endif
}

// K=16 bf16 MFMA; zero-padded K=32 fallback is mathematically identical.
__device__ __forceinline__ f32x4 mfma16bf(b16x4 a, b16x4 b, f32x4 c) {
#if __has_builtin(__builtin_amdgcn_mfma_f32_16x16x16bf16_1k)
  return __builtin_amdgcn_mfma_f32_16x16x16bf16_1k(a, b, c, 0, 0, 0);
#else
  b16x8 az = {a[0], a[1], a[2], a[3], 0, 0, 0, 0};
  b16x8 bz = {b[0], b[1], b[2], b[3], 0, 0, 0, 0};
  return MFMA_BF16(az, bz, c);
#endif
}

__device__ __forceinline__ short f2b(float f) {          // fp32 -> bf16 RTN-even
  unsigned u = __builtin_bit_cast(unsigned, f);
  u += 0x7FFFu + ((u >> 16) & 1u);
  return (short)(u >> 16);
}
__device__ __forceinline__ unsigned pkh(float a, float b) {  // 2xf32 -> packed f16 RTN
  _Float16 h0 = (_Float16)a, h1 = (_Float16)b;
  return (unsigned)__builtin_bit_cast(unsigned short, h0)
       | ((unsigned)__builtin_bit_cast(unsigned short, h1) << 16);
}
// 2xf32 -> packed bf16, round-half-away (differs from RTN-even only on ties)
__device__ __forceinline__ unsigned pkb2(float a, float b) {
  unsigned ua = __builtin_bit_cast(unsigned, a) + 0x8000u;
  unsigned ub = __builtin_bit_cast(unsigned, b) + 0x8000u;
  return (ub & 0xFFFF0000u) | (ua >> 16);
}
// XOR-swizzled element address inside a [rows][64] 2B-elem tile (Kb).
__device__ __forceinline__ int swz(int row, int col) {
  return row*64 + ((((col >> 3) ^ row) & 7) << 3) + (col & 7);
}
// Vt variant: + half-XOR with row bit3 (conflict-free b64 PV reads).
__device__ __forceinline__ int swzv(int row, int col) {
  return row*64 + ((((col >> 3) ^ row) & 7) << 3)
       + ((col & 7) ^ ((row & 8) >> 1));
}

// ---------------- merged precompute kernel (unchanged) ----------------

__global__ __launch_bounds__(256) void preprep(
    const float* __restrict__ K, const float* __restrict__ R,
    const float* __restrict__ V,
    _Float16* __restrict__ Kh, _Float16* __restrict__ R16,
    short* __restrict__ Vt)
{
  __shared__ float t[64][65];
  const int bid = blockIdx.x, tid = threadIdx.x;
  if (bid < 1024) {
    const int n = bid >> 4, st = bid & 15;
    {
      const int row = tid >> 2, c0 = (tid & 3) * 16;
      const float* src = V + ((size_t)n * SQ + st * 64 + row) * HD + c0;
#pragma unroll
      for (int i = 0; i < 4; ++i) {
        float4 x = ((const float4*)src)[i];
        t[row][c0 + 4*i + 0] = x.x; t[row][c0 + 4*i + 1] = x.y;
        t[row][c0 + 4*i + 2] = x.z; t[row][c0 + 4*i + 3] = x.w;
      }
    }
    __syncthreads();
    {
      const int d = tid >> 2, s0 = (tid & 3) * 16;
      short* dst = Vt + ((size_t)n * 80 + d) * SQ + st * 64 + s0;
#pragma unroll
      for (int i = 0; i < 8; ++i)
        *(unsigned*)(dst + 2*i) = pkb2(t[s0 + 2*i][d], t[s0 + 2*i + 1][d]);
    }
    if (tid < 64) {          // rows 64..79 unused by main; kept harmless
      const int s = st * 64 + tid;
      Vt[((size_t)n * 80 + 64) * SQ + s] = (short)0x3F80;
#pragma unroll
      for (int r = 65; r < 80; ++r) Vt[((size_t)n * 80 + r) * SQ + s] = 0;
    }
  } else {
    const int idx = (bid - 1024) * 256 + tid;            // float4 index
    const int nk4 = (64 * SQ * HD) / 4;                  // 1048576
    if (idx < nk4) {
      float4 v = ((const float4*)K)[idx];
      f16x4 o = { (_Float16)v.x, (_Float16)v.y, (_Float16)v.z, (_Float16)v.w };
      *(f16x4*)(Kh + 4 * (size_t)idx) = o;
    } else {
      int rr = idx - nk4;                                // < 262144
      int h  = rr >> 14, off = rr & 16383;               // 16384 float4/head
      float4 v = ((const float4*)R)[((size_t)h << 15) + off];
      f16x4 o = { (_Float16)v.x, (_Float16)v.y, (_Float16)v.z, (_Float16)v.w };
      *(f16x4*)(R16 + 4 * (((size_t)h << 14) + off)) = o;
    }
  }
}

// ---------------- main flash kernel (R15) ----------------

__global__ __launch_bounds__(256, 3) void relpos_sdpa_r15(
    const float* __restrict__ Q, const _Float16* __restrict__ Kh,
    const short* __restrict__ Vtg, const _Float16* __restrict__ R16,
    const float* __restrict__ Ub, const float* __restrict__ Vb,
    float* __restrict__ O)
{
  const int n    = blockIdx.x;
  const int h    = n & (NHD - 1);
  const int a0   = blockIdx.y * 64;
  const int tid  = threadIdx.x;
  const int lane = tid & 63, wave = tid >> 6;
  const int l15  = lane & 15, quad = lane >> 4;

  const float*    Qn  = Q   + (size_t)n * SQ * HD;
  const _Float16* Khn = Kh  + (size_t)n * SQ * HD;
  const short*    Vgn = Vtg + (size_t)n * 80 * SQ;
  const _Float16* Rh  = R16 + (size_t)h * SQ * HD;

  // LDS: Kb f16 [64][64] swz 8192 @ 0
  //      Vt bf16 [64][64] swzv 8192 @ 8192
  //      ring u32 [33][132] 17424 @ 16384      total 33808 B
  __shared__ __align__(16) char lds[33808];
  _Float16*       Kb   = (_Float16*)lds;
  short*          Vt   = (short*)(lds + 8192);
  unsigned*       Pb2  = (unsigned*)(lds + 16384);
  const _Float16* Pb2h = (const _Float16*)Pb2;

  // ---- persistent q fragments, pre-scaled by log2(e) ----
  f16x8 quF[2], qvF[5][2];
#pragma unroll
  for (int ks = 0; ks < 2; ++ks) {
    const int db = ks * 32 + quad * 8;
    float ub[8], vb[8];
#pragma unroll
    for (int j = 0; j < 8; ++j) {
      ub[j] = Ub[h*HD + db + j] * L2E;
      vb[j] = Vb[h*HD + db + j] * L2E;
    }
    {
      const float* p = Qn + (size_t)(a0 + 16*wave + l15) * HD + db;
      float4 x0 = ((const float4*)p)[0], x1 = ((const float4*)p)[1];
      f16x8 f;
#pragma unroll
      for (int t = 0; t < 4; ++t) {
        f[t]   = (_Float16)((&x0.x)[t] * (0.125f * L2E) + ub[t]);
        f[t+4] = (_Float16)((&x1.x)[t] * (0.125f * L2E) + ub[t+4]);
      }
      quF[ks] = f;
    }
#pragma unroll
    for (int rt = 0; rt < 5; ++rt) {
      int row = a0 + 16*rt + l15; if (row > SQ-1) row = SQ-1;
      const float* p = Qn + (size_t)row * HD + db;
      float4 x0 = ((const float4*)p)[0], x1 = ((const float4*)p)[1];
      f16x8 f;
#pragma unroll
      for (int t = 0; t < 4; ++t) {
        f[t]   = (_Float16)((&x0.x)[t] * (0.125f * L2E) + vb[t]);
        f[t+4] = (_Float16)((&x1.x)[t] * (0.125f * L2E) + vb[t+4]);
      }
      qvF[rt][ks] = f;
    }
  }

  f32x4 Oacc[4], acc_l;
#pragma unroll
  for (int ct = 0; ct < 4; ++ct) Oacc[ct] = (f32x4){0.f, 0.f, 0.f, 0.f};
  acc_l = (f32x4){0.f, 0.f, 0.f, 0.f};

  const b16x4 ONESB = {(short)0x3F80, (short)0x3F80, (short)0x3F80, (short)0x3F80};

  // ---- band, split: bandLoad (issue R16 loads early) / bandMFMA (compute) ----
  unsigned ringW[9];
  int ringSlot, ringSlotN;
  f16x8 bB0, bB1;
  auto bandLoad = [&](int jstart) {
    const int c = jstart + 16*wave + l15;
    const int j = (c + 2048) & (SQ - 1);
    ringSlotN   = (c + 2048) & 127;
    const _Float16* rp = Rh + (size_t)j * HD + quad * 8;
    bB0 = *(const f16x8*)rp;
    bB1 = *(const f16x8*)(rp + 32);
  };
  auto bandMFMA = [&]() {
    ringSlot = ringSlotN;
#pragma unroll
    for (int rt = 0; rt < 5; ++rt) {
      f32x4 acc = (f32x4){0.f, 0.f, 0.f, 0.f};
      acc = MFMA_F16(qvF[rt][0], bB0, acc);
      acc = MFMA_F16(qvF[rt][1], bB1, acc);
      if (rt < 4) {
        ringW[2*rt]     = pkh(acc[0], acc[1]);
        ringW[2*rt + 1] = pkh(acc[2], acc[3]);
      } else {
        ringW[8] = pkh(acc[0], acc[1]);   // row 64 (only quad 0's used)
      }
    }
  };
  auto ringFlush = [&]() {
#pragma unroll
    for (int rt = 0; rt < 4; ++rt) {
      const int rp0 = 8*rt + 2*quad;                 // rows 16rt+4q .. +3
      Pb2[rp0*132 + ringSlot]       = ringW[2*rt];
      Pb2[(rp0 + 1)*132 + ringSlot] = ringW[2*rt + 1];
    }
    if (quad == 0) Pb2[32*132 + ringSlot] = ringW[8];
  };

  // prologue: fill all 128 ring slots for iter 0 (pre-loop, no races)
  bandLoad(-a0 - 65);  bandMFMA();  ringFlush();
  bandLoad(-a0 - 1);   bandMFMA();  ringFlush();

  // ---- T14 prefetch regs (row = lane, chunks wave / wave+4) ----
  f16x8 kPre[2]; b16x8 vPre[2];
  auto stageLoad = [&](int k0) {
    const _Float16* ks = Khn + (size_t)(k0 + lane) * HD + wave*8;
    kPre[0] = *(const f16x8*)ks;
    kPre[1] = *(const f16x8*)(ks + 32);
    const short* vs = Vgn + (size_t)lane * SQ + k0 + wave*8;
    vPre[0] = *(const b16x8*)vs;
    vPre[1] = *(const b16x8*)(vs + 32);
  };
  auto stageWrite = [&]() {
    *(f16x8*)&Kb[swz(lane, wave*8)]      = kPre[0];
    *(f16x8*)&Kb[swz(lane, 32 + wave*8)] = kPre[1];
    // Vt: 4x b64 writes into the half-XOR layout (uniform 4/bank, free)
    const int hx = (lane & 8) >> 1;                      // 0 or 4
    const int c0 = ((wave       ^ lane) & 7) << 3;
    const int c1 = (((wave + 4) ^ lane) & 7) << 3;
    short* vr = &Vt[lane * 64];
    b16x8 v0 = vPre[0], v1 = vPre[1];
    b16x4 v0lo = {v0[0], v0[1], v0[2], v0[3]};
    b16x4 v0hi = {v0[4], v0[5], v0[6], v0[7]};
    b16x4 v1lo = {v1[0], v1[1], v1[2], v1[3]};
    b16x4 v1hi = {v1[4], v1[5], v1[6], v1[7]};
    *(b16x4*)&vr[c0 + hx]       = v0lo;
    *(b16x4*)&vr[c0 + (4 ^ hx)] = v0hi;
    *(b16x4*)&vr[c1 + hx]       = v1lo;
    *(b16x4*)&vr[c1 + (4 ^ hx)] = v1hi;
  };

  stageLoad(0);

  const int iiB = 16*wave + 4*quad;
  const int iQ  = 16*wave + l15;          // this lane's q-local row (swapped)

  for (int k0 = 0; k0 < SQ; k0 += 64) {
    __syncthreads();   // A: prev iter's Kb/Vt fragment reads + ring gathers done

    stageWrite();                     // tile k0 regs -> LDS
    if (k0 > 0) ringFlush();          // cols computed at end of prev iter

    __syncthreads();   // B: Kb/Vt staged + new ring cols visible

    if (k0 < SQ - 64) {
      stageLoad(k0 + 64);             // prefetch next tile (used next A)
      bandLoad(k0 + 64 - a0 - 1);     // hoisted: R16 latency hides under compute
    }

    // ---- content scores, SWAPPED: sc[ct][r] = S[key=16ct+4q+r][q=16w+l15] ----
    f32x4 sc[4];
#pragma unroll
    for (int ct = 0; ct < 4; ++ct) {
      f16x8 ka = *(const f16x8*)&Kb[swz(16*ct + l15, quad*8)];
      f16x8 kb = *(const f16x8*)&Kb[swz(16*ct + l15, 32 + quad*8)];
      f32x4 acc = (f32x4){NSHIFT, NSHIFT, NSHIFT, NSHIFT};
      acc = MFMA_F16(ka, quF[0], acc);        // A = K-frag, B = Q-frag
      acc = MFMA_F16(kb, quF[1], acc);
      sc[ct] = acc;
    }

    // ---- ring gather + exp2 (swapped indexing) ----
    const int base = k0 - a0 - 16*wave;
    if (k0 == a0 || k0 == a0 + 64) {
      const int adA = (iQ >> 1) * 264 + (iQ & 1);                // u=0
      const int adB = ((iQ + 1) >> 1) * 264 + ((iQ + 1) & 1);    // u=1
#pragma unroll
      for (int ct = 0; ct < 4; ++ct) {
        const int e0 = base + 16*ct + 4*quad - l15;
#pragma unroll
        for (int r = 0; r < 4; ++r) {
          const int e    = e0 + r;
          const int u    = (e > 0) ? 1 : 0;
          const int slot = (e - 1 - u) & 127;
          float pos = (float)Pb2h[(u ? adB : adA) + 2*slot];
          float s   = sc[ct][r] + ((e == 1) ? 0.f : pos);
          sc[ct][r] = exp2fast(s);
        }
      }
    } else {
      const int u  = (k0 > a0) ? 1 : 0;      // uniform; no e==1 possible here
      const int iu = iQ + u;
      const int ad = (iu >> 1) * 264 + (iu & 1);
      const int sb = base - 1 - u + 4*quad - l15 + 2048;
#pragma unroll
      for (int ct = 0; ct < 4; ++ct) {
#pragma unroll
        for (int r = 0; r < 4; ++r) {
          const int slot = (sb + 16*ct + r) & 127;
          float pos = (float)Pb2h[ad + 2*slot];
          sc[ct][r] = exp2fast(sc[ct][r] + pos);
        }
      }
    }

    // ---- PV straight from registers: 4x4 K=16 bf16 MFMAs + ones-l ----
#pragma unroll
    for (int ctk = 0; ctk < 4; ++ctk) {
      unsigned lo = pkb2(sc[ctk][0], sc[ctk][1]);
      unsigned hi = pkb2(sc[ctk][2], sc[ctk][3]);
      b16x4 aF = __builtin_bit_cast(b16x4, (u32x2){lo, hi});
      acc_l = mfma16bf(aF, ONESB, acc_l);     // l partial (all cols equal)
#pragma unroll
      for (int ctd = 0; ctd < 4; ++ctd) {
        b16x4 bF = *(const b16x4*)&Vt[swzv(16*ctd + l15, 16*ctk + 4*quad)];
        Oacc[ctd] = mfma16bf(aF, bF, Oacc[ctd]);
      }
    }

    if (k0 < SQ - 64) bandMFMA();     // next iter's 64 new ring cols (regs)
  }

  // ---- epilogue: O = Oacc / l, l in-lane from ones-MFMA ----
#pragma unroll
  for (int r = 0; r < 4; ++r) {
    float inv = 1.0f / acc_l[r];
    const size_t rowo = (size_t)n * SQ * HD + (size_t)(a0 + iiB + r) * HD;
#pragma unroll
    for (int ct = 0; ct < 4; ++ct)
      O[rowo + 16*ct + l15] = Oacc[ct][r] * inv;
  }
}

// ---------------- fallback (R3-style, raw inputs) for small ws ----------------

__global__ __launch_bounds__(256, 4) void relpos_sdpa_fb(
    const float* __restrict__ Q, const float* __restrict__ K,
    const float* __restrict__ V, const float* __restrict__ Ub,
    const float* __restrict__ Vb, const float* __restrict__ R,
    float* __restrict__ O)
{
  const int n    = blockIdx.x;
  const int h    = n & (NHD - 1);
  const int a0   = blockIdx.y * 64;
  const int tid  = threadIdx.x;
  const int lane = tid & 63, wave = tid >> 6;
  const int l15  = lane & 15, quad = lane >> 4;

  const float* Qn = Q + (size_t)n * SQ * HD;
  const float* Kn = K + (size_t)n * SQ * HD;
  const float* Vn = V + (size_t)n * SQ * HD;
  const float* Rh = R + (size_t)h * RMAX * HD;

  __shared__ __align__(16) char lds[38656];
  _Float16* Kb = (_Float16*)lds;
  short*    Ps = (short*)lds;
  short*    Vt = (short*)(lds + 9216);
  _Float16* Pb = (_Float16*)(lds + 9216 + 11520);

  f16x8 quF[2], qvF[5][2];
#pragma unroll
  for (int ks = 0; ks < 2; ++ks) {
    const int db = ks * 32 + quad * 8;
    float ub[8], vb[8];
#pragma unroll
    for (int j = 0; j < 8; ++j) { ub[j] = Ub[h*HD + db + j]; vb[j] = Vb[h*HD + db + j]; }
    {
      const float* p = Qn + (size_t)(a0 + 16*wave + l15) * HD + db;
      f16x8 f;
#pragma unroll
      for (int j = 0; j < 8; ++j) f[j] = (_Float16)(p[j] * 0.125f + ub[j]);
      quF[ks] = f;
    }
#pragma unroll
    for (int rt = 0; rt < 5; ++rt) {
      int row = a0 + 16*rt + l15; if (row > SQ-1) row = SQ-1;
      const float* p = Qn + (size_t)row * HD + db;
      f16x8 f;
#pragma unroll
      for (int j = 0; j < 8; ++j) f[j] = (_Float16)(p[j] * 0.125f + vb[j]);
      qvF[rt][ks] = f;
    }
  }

  if (tid < 64) Vt[64*72 + tid] = (short)0x3F80;

  f32x4 Oacc[5];
#pragma unroll
  for (int ct = 0; ct < 5; ++ct) Oacc[ct] = (f32x4){0.f, 0.f, 0.f, 0.f};

  auto band = [&](int jstart) {
    const int c    = jstart + 16*wave + l15;
    const int j    = (c + 2048) & (SQ - 1);
    const int slot = (c + 2048) & 127;
    const float* rp = Rh + (size_t)j * HD + quad * 8;
    f16x8 B0, B1;
    {
      float4 x0 = *(const float4*)(rp),      x1 = *(const float4*)(rp + 4);
      float4 y0 = *(const float4*)(rp + 32), y1 = *(const float4*)(rp + 36);
#pragma unroll
      for (int t = 0; t < 4; ++t) { B0[t] = (_Float16)(&x0.x)[t]; B0[t+4] = (_Float16)(&x1.x)[t]; }
#pragma unroll
      for (int t = 0; t < 4; ++t) { B1[t] = (_Float16)(&y0.x)[t]; B1[t+4] = (_Float16)(&y1.x)[t]; }
    }
#pragma unroll
    for (int rt = 0; rt < 5; ++rt) {
      f32x4 acc = (f32x4){0.f, 0.f, 0.f, 0.f};
      acc = MFMA_F16(qvF[rt][0], B0, acc);
      acc = MFMA_F16(qvF[rt][1], B1, acc);
      const int row = 16*rt + 4*quad;
      if (rt < 4) {
        *(unsigned*)&Pb[slot*70 + row]     = pkh(acc[0], acc[1]);
        *(unsigned*)&Pb[slot*70 + row + 2] = pkh(acc[2], acc[3]);
      } else if (quad == 0) {
        *(unsigned*)&Pb[slot*70 + row]     = pkh(acc[0], acc[1]);
      }
    }
  };

  band(-a0 - 65);
  band(-a0 - 1);

  const int sr = tid >> 2, sc4 = tid & 3;
  const int iiB = 16*wave + 4*quad;

  for (int k0 = 0; k0 < SQ; k0 += 64) {
    __syncthreads();
    {
      const float* src = Kn + (size_t)(k0 + sr) * HD + sc4 * 16;
      float4 x0 = *(const float4*)(src),     x1 = *(const float4*)(src + 4);
      float4 y0 = *(const float4*)(src + 8), y1 = *(const float4*)(src + 12);
      f16x8 lo, hi;
#pragma unroll
      for (int t = 0; t < 4; ++t) { lo[t] = (_Float16)(&x0.x)[t]; lo[t+4] = (_Float16)(&x1.x)[t]; }
#pragma unroll
      for (int t = 0; t < 4; ++t) { hi[t] = (_Float16)(&y0.x)[t]; hi[t+4] = (_Float16)(&y1.x)[t]; }
      *(f16x8*)&Kb[sr*72 + sc4*16]     = lo;
      *(f16x8*)&Kb[sr*72 + sc4*16 + 8] = hi;
    }
    {
      const int g = lane >> 3;
#pragma unroll
      for (int i = 0; i < 8; ++i) {
        int bp = 8*wave + (i ^ g);
        float v0 = Vn[(size_t)(k0 + 2*bp)     * HD + lane];
        float v1 = Vn[(size_t)(k0 + 2*bp + 1) * HD + lane];
        *(unsigned*)&Vt[lane*72 + 2*bp] = pkb2(v0, v1);
      }
    }
    __syncthreads();

    f32x4 sc[4];
#pragma unroll
    for (int ct = 0; ct < 4; ++ct) {
      f16x8 b0 = *(const f16x8*)&Kb[(16*ct + l15)*72 + quad*8];
      f16x8 b1 = *(const f16x8*)&Kb[(16*ct + l15)*72 + 32 + quad*8];
      f32x4 acc = (f32x4){0.f, 0.f, 0.f, 0.f};
      acc = MFMA_F16(quF[0], b0, acc);
      acc = MFMA_F16(quF[1], b1, acc);
      sc[ct] = acc;
    }

    const int dlt = k0 - a0;
#pragma unroll
    for (int r = 0; r < 4; ++r) {
      const int ii = iiB + r;
#pragma unroll
      for (int ct = 0; ct < 4; ++ct) {
        const int e    = dlt + 16*ct + l15 - ii;
        const int u    = (e > 0) ? 1 : 0;
        const int slot = (e - 1 - u + 2048) & 127;
        float pos = (float)Pb[slot*70 + ii + u];
        float s   = sc[ct][r] + ((e == 1) ? 0.f : pos);
        sc[ct][r] = __expf(s - 40.0f);
      }
    }
    __syncthreads();

#pragma unroll
    for (int r = 0; r < 4; ++r)
#pragma unroll
      for (int ct = 0; ct < 4; ++ct)
        Ps[(iiB + r)*68 + 16*ct + l15] = f2b(sc[ct][r]);

    b16x8 pA0 = *(const b16x8*)&Ps[(16*wave + l15)*68 + quad*8];
    b16x8 pA1 = *(const b16x8*)&Ps[(16*wave + l15)*68 + 32 + quad*8];
#pragma unroll
    for (int ct = 0; ct < 5; ++ct) {
      b16x8 v0 = *(const b16x8*)&Vt[(16*ct + l15)*72 + quad*8];
      b16x8 v1 = *(const b16x8*)&Vt[(16*ct + l15)*72 + 32 + quad*8];
      Oacc[ct] = MFMA_BF16(pA0, v0, Oacc[ct]);
      Oacc[ct] = MFMA_BF16(pA1, v1, Oacc[ct]);
    }

    if (k0 < SQ - 64) band(k0 + 64 - a0 - 1);
  }

#pragma unroll
  for (int r = 0; r < 4; ++r) {
    float l   = __shfl(Oacc[4][r], lane & 48);
    float inv = 1.0f / l;
    const size_t rowo = (size_t)n * SQ * HD + (size_t)(a0 + iiB + r) * HD;
#pragma unroll
    for (int ct = 0; ct < 4; ++ct)
      O[rowo + 16*ct + l15] = Oacc[ct][r] * inv;
  }
}

extern "C" void kernel_launch(void* const* d_in, const int* in_sizes, int n_in,
                              void* d_out, int out_size, void* d_ws, size_t ws_size,
                              hipStream_t stream) {
  const float* Q  = (const float*)d_in[0];
  const float* K  = (const float*)d_in[1];
  const float* V  = (const float*)d_in[2];
  const float* Ub = (const float*)d_in[3];  // (1,16,1,64)
  const float* Vb = (const float*)d_in[4];
  const float* R  = (const float*)d_in[5];  // (16,2048,64)
  float* O = (float*)d_out;

  if (ws_size >= WS_NEED) {
    _Float16* Kh  = (_Float16*)((char*)d_ws + KH_OFF);
    short*    Vt  = (short*)((char*)d_ws + VT_OFF);
    _Float16* R16 = (_Float16*)((char*)d_ws + R16_OFF);

    preprep<<<6144, 256, 0, stream>>>(K, R, V, Kh, R16, Vt);

    dim3 grid(64, 16);   // x = n (XCD locality), y = q-tile
    relpos_sdpa_r15<<<grid, 256, 0, stream>>>(Q, Kh, Vt, R16, Ub, Vb, O);
  } else {
    dim3 grid(64, 16);
    relpos_sdpa_fb<<<grid, 256, 0, stream>>>(Q, K, V, Ub, Vb, R, O);
  }
}

// Round 9
// 169.906 us; speedup vs baseline: 1.6507x; 1.0061x over previous
//
#include <hip/hip_runtime.h>

// RelativePositionSDPA — R16: R15 + batched ring gather + setprio.
//
// R15 post-mortem: conflicts 7.4M->3.2M as predicted (PV fix verified);
// main 82.8us. Residual 3211264 conflicts are BIT-IDENTICAL across
// R10/R11/R12/R13/R15 — only shared LDS code is ring writes + gather.
// LDS pipe ~61% of wall; gather (16x ds_read_u16 ~93cy/wave/iter) is the
// biggest reducible item.
//
// R16 changes:
//  1. Batched gather (fast path): per ct the 4 reads hit 4 CONSECUTIVE u32
//     ring words ((iu>>1)*132 + s0 + {0..3}, same f16 half) -> 4 adjacent
//     u32 loads (compiler merges to ds_read2_b32; 4B-aligned, no b128
//     alignment hazard). Wrap (s0>=125) handled by mirror cols 128..130
//     (stride 132 has room): ringFlush dups writes when slot<3 (exec-masked,
//     rare). General path (2/16 iters) unchanged.
//  2. T5 s_setprio(1/0) around QK / PV / band MFMA clusters — 2 blocks/CU
//     means waves from different blocks sit at different phases (the regime
//     where setprio measured +4-7% on attention).
//
// Everything else identical to R15: swapped-operand QK^T, reg-direct PV
// (K=16 bf16), Vt half-XOR swizzle, band-load hoist, 2-barrier schedule,
// deferred ring flush, C-init softmax shift, exp2 domain.

#define SQ    1024
#define HD    64
#define NHD   16
#define RMAX  2048

typedef _Float16 f16x8 __attribute__((ext_vector_type(8)));
typedef _Float16 f16x4 __attribute__((ext_vector_type(4)));
typedef short    b16x8 __attribute__((ext_vector_type(8)));
typedef short    b16x4 __attribute__((ext_vector_type(4)));
typedef float    f32x4 __attribute__((ext_vector_type(4)));
typedef unsigned u32x2 __attribute__((ext_vector_type(2)));

#define MFMA_F16(A,B,C)  __builtin_amdgcn_mfma_f32_16x16x32_f16((A),(B),(C),0,0,0)
#define MFMA_BF16(A,B,C) __builtin_amdgcn_mfma_f32_16x16x32_bf16((A),(B),(C),0,0,0)

#define L2E    1.44269504088896f    // log2(e)
#define NSHIFT (-57.7078016f)       // -40 * log2(e)

// ws layout
#define KH_OFF   0                       // f16 [64][1024][64]   8 MB
#define VT_OFF   (8u << 20)              // bf16 [64][80][1024]  10 MB
#define R16_OFF  (18u << 20)             // f16 [16][1024][64]   2 MB
#define WS_NEED  (20u << 20)

__device__ __forceinline__ float exp2fast(float x) {
#if __has_builtin(__builtin_amdgcn_exp2f)
  return __builtin_amdgcn_exp2f(x);          // v_exp_f32 (2^x native)
#else
  return __expf(x * 0.693147180559945f);
#endif
}

// K=16 bf16 MFMA; zero-padded K=32 fallback is mathematically identical.
__device__ __forceinline__ f32x4 mfma16bf(b16x4 a, b16x4 b, f32x4 c) {
#if __has_builtin(__builtin_amdgcn_mfma_f32_16x16x16bf16_1k)
  return __builtin_amdgcn_mfma_f32_16x16x16bf16_1k(a, b, c, 0, 0, 0);
#else
  b16x8 az = {a[0], a[1], a[2], a[3], 0, 0, 0, 0};
  b16x8 bz = {b[0], b[1], b[2], b[3], 0, 0, 0, 0};
  return MFMA_BF16(az, bz, c);
#endif
}

__device__ __forceinline__ short f2b(float f) {          // fp32 -> bf16 RTN-even
  unsigned u = __builtin_bit_cast(unsigned, f);
  u += 0x7FFFu + ((u >> 16) & 1u);
  return (short)(u >> 16);
}
__device__ __forceinline__ unsigned pkh(float a, float b) {  // 2xf32 -> packed f16 RTN
  _Float16 h0 = (_Float16)a, h1 = (_Float16)b;
  return (unsigned)__builtin_bit_cast(unsigned short, h0)
       | ((unsigned)__builtin_bit_cast(unsigned short, h1) << 16);
}
// 2xf32 -> packed bf16, round-half-away (differs from RTN-even only on ties)
__device__ __forceinline__ unsigned pkb2(float a, float b) {
  unsigned ua = __builtin_bit_cast(unsigned, a) + 0x8000u;
  unsigned ub = __builtin_bit_cast(unsigned, b) + 0x8000u;
  return (ub & 0xFFFF0000u) | (ua >> 16);
}
// f16 half (sh=0 lo, sh=16 hi) of a packed u32 -> float
__device__ __forceinline__ float h2f(unsigned w, int sh) {
  return (float)__builtin_bit_cast(_Float16, (unsigned short)(w >> sh));
}
// XOR-swizzled element address inside a [rows][64] 2B-elem tile (Kb).
__device__ __forceinline__ int swz(int row, int col) {
  return row*64 + ((((col >> 3) ^ row) & 7) << 3) + (col & 7);
}
// Vt variant: + half-XOR with row bit3 (conflict-free b64 PV reads).
__device__ __forceinline__ int swzv(int row, int col) {
  return row*64 + ((((col >> 3) ^ row) & 7) << 3)
       + ((col & 7) ^ ((row & 8) >> 1));
}

// ---------------- merged precompute kernel (unchanged) ----------------

__global__ __launch_bounds__(256) void preprep(
    const float* __restrict__ K, const float* __restrict__ R,
    const float* __restrict__ V,
    _Float16* __restrict__ Kh, _Float16* __restrict__ R16,
    short* __restrict__ Vt)
{
  __shared__ float t[64][65];
  const int bid = blockIdx.x, tid = threadIdx.x;
  if (bid < 1024) {
    const int n = bid >> 4, st = bid & 15;
    {
      const int row = tid >> 2, c0 = (tid & 3) * 16;
      const float* src = V + ((size_t)n * SQ + st * 64 + row) * HD + c0;
#pragma unroll
      for (int i = 0; i < 4; ++i) {
        float4 x = ((const float4*)src)[i];
        t[row][c0 + 4*i + 0] = x.x; t[row][c0 + 4*i + 1] = x.y;
        t[row][c0 + 4*i + 2] = x.z; t[row][c0 + 4*i + 3] = x.w;
      }
    }
    __syncthreads();
    {
      const int d = tid >> 2, s0 = (tid & 3) * 16;
      short* dst = Vt + ((size_t)n * 80 + d) * SQ + st * 64 + s0;
#pragma unroll
      for (int i = 0; i < 8; ++i)
        *(unsigned*)(dst + 2*i) = pkb2(t[s0 + 2*i][d], t[s0 + 2*i + 1][d]);
    }
    if (tid < 64) {          // rows 64..79 unused by main; kept harmless
      const int s = st * 64 + tid;
      Vt[((size_t)n * 80 + 64) * SQ + s] = (short)0x3F80;
#pragma unroll
      for (int r = 65; r < 80; ++r) Vt[((size_t)n * 80 + r) * SQ + s] = 0;
    }
  } else {
    const int idx = (bid - 1024) * 256 + tid;            // float4 index
    const int nk4 = (64 * SQ * HD) / 4;                  // 1048576
    if (idx < nk4) {
      float4 v = ((const float4*)K)[idx];
      f16x4 o = { (_Float16)v.x, (_Float16)v.y, (_Float16)v.z, (_Float16)v.w };
      *(f16x4*)(Kh + 4 * (size_t)idx) = o;
    } else {
      int rr = idx - nk4;                                // < 262144
      int h  = rr >> 14, off = rr & 16383;               // 16384 float4/head
      float4 v = ((const float4*)R)[((size_t)h << 15) + off];
      f16x4 o = { (_Float16)v.x, (_Float16)v.y, (_Float16)v.z, (_Float16)v.w };
      *(f16x4*)(R16 + 4 * (((size_t)h << 14) + off)) = o;
    }
  }
}

// ---------------- main flash kernel (R16) ----------------

__global__ __launch_bounds__(256, 3) void relpos_sdpa_r16(
    const float* __restrict__ Q, const _Float16* __restrict__ Kh,
    const short* __restrict__ Vtg, const _Float16* __restrict__ R16,
    const float* __restrict__ Ub, const float* __restrict__ Vb,
    float* __restrict__ O)
{
  const int n    = blockIdx.x;
  const int h    = n & (NHD - 1);
  const int a0   = blockIdx.y * 64;
  const int tid  = threadIdx.x;
  const int lane = tid & 63, wave = tid >> 6;
  const int l15  = lane & 15, quad = lane >> 4;

  const float*    Qn  = Q   + (size_t)n * SQ * HD;
  const _Float16* Khn = Kh  + (size_t)n * SQ * HD;
  const short*    Vgn = Vtg + (size_t)n * 80 * SQ;
  const _Float16* Rh  = R16 + (size_t)h * SQ * HD;

  // LDS: Kb f16 [64][64] swz 8192 @ 0
  //      Vt bf16 [64][64] swzv 8192 @ 8192
  //      ring u32 [33][132] 17424 @ 16384 (cols 128..130 mirror 0..2)
  __shared__ __align__(16) char lds[33808];
  _Float16*       Kb   = (_Float16*)lds;
  short*          Vt   = (short*)(lds + 8192);
  unsigned*       Pb2  = (unsigned*)(lds + 16384);
  const _Float16* Pb2h = (const _Float16*)Pb2;

  // ---- persistent q fragments, pre-scaled by log2(e) ----
  f16x8 quF[2], qvF[5][2];
#pragma unroll
  for (int ks = 0; ks < 2; ++ks) {
    const int db = ks * 32 + quad * 8;
    float ub[8], vb[8];
#pragma unroll
    for (int j = 0; j < 8; ++j) {
      ub[j] = Ub[h*HD + db + j] * L2E;
      vb[j] = Vb[h*HD + db + j] * L2E;
    }
    {
      const float* p = Qn + (size_t)(a0 + 16*wave + l15) * HD + db;
      float4 x0 = ((const float4*)p)[0], x1 = ((const float4*)p)[1];
      f16x8 f;
#pragma unroll
      for (int t = 0; t < 4; ++t) {
        f[t]   = (_Float16)((&x0.x)[t] * (0.125f * L2E) + ub[t]);
        f[t+4] = (_Float16)((&x1.x)[t] * (0.125f * L2E) + ub[t+4]);
      }
      quF[ks] = f;
    }
#pragma unroll
    for (int rt = 0; rt < 5; ++rt) {
      int row = a0 + 16*rt + l15; if (row > SQ-1) row = SQ-1;
      const float* p = Qn + (size_t)row * HD + db;
      float4 x0 = ((const float4*)p)[0], x1 = ((const float4*)p)[1];
      f16x8 f;
#pragma unroll
      for (int t = 0; t < 4; ++t) {
        f[t]   = (_Float16)((&x0.x)[t] * (0.125f * L2E) + vb[t]);
        f[t+4] = (_Float16)((&x1.x)[t] * (0.125f * L2E) + vb[t+4]);
      }
      qvF[rt][ks] = f;
    }
  }

  f32x4 Oacc[4], acc_l;
#pragma unroll
  for (int ct = 0; ct < 4; ++ct) Oacc[ct] = (f32x4){0.f, 0.f, 0.f, 0.f};
  acc_l = (f32x4){0.f, 0.f, 0.f, 0.f};

  const b16x4 ONESB = {(short)0x3F80, (short)0x3F80, (short)0x3F80, (short)0x3F80};

  // ---- band, split: bandLoad (issue R16 loads early) / bandMFMA (compute) ----
  unsigned ringW[9];
  int ringSlot, ringSlotN;
  f16x8 bB0, bB1;
  auto bandLoad = [&](int jstart) {
    const int c = jstart + 16*wave + l15;
    const int j = (c + 2048) & (SQ - 1);
    ringSlotN   = (c + 2048) & 127;
    const _Float16* rp = Rh + (size_t)j * HD + quad * 8;
    bB0 = *(const f16x8*)rp;
    bB1 = *(const f16x8*)(rp + 32);
  };
  auto bandMFMA = [&]() {
    ringSlot = ringSlotN;
    __builtin_amdgcn_s_setprio(1);
#pragma unroll
    for (int rt = 0; rt < 5; ++rt) {
      f32x4 acc = (f32x4){0.f, 0.f, 0.f, 0.f};
      acc = MFMA_F16(qvF[rt][0], bB0, acc);
      acc = MFMA_F16(qvF[rt][1], bB1, acc);
      if (rt < 4) {
        ringW[2*rt]     = pkh(acc[0], acc[1]);
        ringW[2*rt + 1] = pkh(acc[2], acc[3]);
      } else {
        ringW[8] = pkh(acc[0], acc[1]);   // row 64 (only quad 0's used)
      }
    }
    __builtin_amdgcn_s_setprio(0);
  };
  auto ringFlush = [&]() {
#pragma unroll
    for (int rt = 0; rt < 4; ++rt) {
      const int rp0 = 8*rt + 2*quad;                 // rows 16rt+4q .. +3
      Pb2[rp0*132 + ringSlot]       = ringW[2*rt];
      Pb2[(rp0 + 1)*132 + ringSlot] = ringW[2*rt + 1];
    }
    if (quad == 0) Pb2[32*132 + ringSlot] = ringW[8];
    if (ringSlot < 3) {                              // mirror cols 128..130
      const int ms = ringSlot + 128;
#pragma unroll
      for (int rt = 0; rt < 4; ++rt) {
        const int rp0 = 8*rt + 2*quad;
        Pb2[rp0*132 + ms]       = ringW[2*rt];
        Pb2[(rp0 + 1)*132 + ms] = ringW[2*rt + 1];
      }
      if (quad == 0) Pb2[32*132 + ms] = ringW[8];
    }
  };

  // prologue: fill all 128 ring slots for iter 0 (pre-loop, no races)
  bandLoad(-a0 - 65);  bandMFMA();  ringFlush();
  bandLoad(-a0 - 1);   bandMFMA();  ringFlush();

  // ---- T14 prefetch regs (row = lane, chunks wave / wave+4) ----
  f16x8 kPre[2]; b16x8 vPre[2];
  auto stageLoad = [&](int k0) {
    const _Float16* ks = Khn + (size_t)(k0 + lane) * HD + wave*8;
    kPre[0] = *(const f16x8*)ks;
    kPre[1] = *(const f16x8*)(ks + 32);
    const short* vs = Vgn + (size_t)lane * SQ + k0 + wave*8;
    vPre[0] = *(const b16x8*)vs;
    vPre[1] = *(const b16x8*)(vs + 32);
  };
  auto stageWrite = [&]() {
    *(f16x8*)&Kb[swz(lane, wave*8)]      = kPre[0];
    *(f16x8*)&Kb[swz(lane, 32 + wave*8)] = kPre[1];
    // Vt: 4x b64 writes into the half-XOR layout (uniform 4/bank, free)
    const int hx = (lane & 8) >> 1;                      // 0 or 4
    const int c0 = ((wave       ^ lane) & 7) << 3;
    const int c1 = (((wave + 4) ^ lane) & 7) << 3;
    short* vr = &Vt[lane * 64];
    b16x8 v0 = vPre[0], v1 = vPre[1];
    b16x4 v0lo = {v0[0], v0[1], v0[2], v0[3]};
    b16x4 v0hi = {v0[4], v0[5], v0[6], v0[7]};
    b16x4 v1lo = {v1[0], v1[1], v1[2], v1[3]};
    b16x4 v1hi = {v1[4], v1[5], v1[6], v1[7]};
    *(b16x4*)&vr[c0 + hx]       = v0lo;
    *(b16x4*)&vr[c0 + (4 ^ hx)] = v0hi;
    *(b16x4*)&vr[c1 + hx]       = v1lo;
    *(b16x4*)&vr[c1 + (4 ^ hx)] = v1hi;
  };

  stageLoad(0);

  const int iiB = 16*wave + 4*quad;
  const int iQ  = 16*wave + l15;          // this lane's q-local row (swapped)

  for (int k0 = 0; k0 < SQ; k0 += 64) {
    __syncthreads();   // A: prev iter's Kb/Vt fragment reads + ring gathers done

    stageWrite();                     // tile k0 regs -> LDS
    if (k0 > 0) ringFlush();          // cols computed at end of prev iter

    __syncthreads();   // B: Kb/Vt staged + new ring cols visible

    if (k0 < SQ - 64) {
      stageLoad(k0 + 64);             // prefetch next tile (used next A)
      bandLoad(k0 + 64 - a0 - 1);     // hoisted: R16 latency hides under compute
    }

    // ---- content scores, SWAPPED: sc[ct][r] = S[key=16ct+4q+r][q=16w+l15] ----
    f32x4 sc[4];
    __builtin_amdgcn_s_setprio(1);
#pragma unroll
    for (int ct = 0; ct < 4; ++ct) {
      f16x8 ka = *(const f16x8*)&Kb[swz(16*ct + l15, quad*8)];
      f16x8 kb = *(const f16x8*)&Kb[swz(16*ct + l15, 32 + quad*8)];
      f32x4 acc = (f32x4){NSHIFT, NSHIFT, NSHIFT, NSHIFT};
      acc = MFMA_F16(ka, quF[0], acc);        // A = K-frag, B = Q-frag
      acc = MFMA_F16(kb, quF[1], acc);
      sc[ct] = acc;
    }
    __builtin_amdgcn_s_setprio(0);

    // ---- ring gather + exp2 (swapped indexing) ----
    const int base = k0 - a0 - 16*wave;
    if (k0 == a0 || k0 == a0 + 64) {
      // general path (2/16 iters): per-element u / e==1 handling
      const int adA = (iQ >> 1) * 264 + (iQ & 1);                // u=0
      const int adB = ((iQ + 1) >> 1) * 264 + ((iQ + 1) & 1);    // u=1
#pragma unroll
      for (int ct = 0; ct < 4; ++ct) {
        const int e0 = base + 16*ct + 4*quad - l15;
#pragma unroll
        for (int r = 0; r < 4; ++r) {
          const int e    = e0 + r;
          const int u    = (e > 0) ? 1 : 0;
          const int slot = (e - 1 - u) & 127;
          float pos = (float)Pb2h[(u ? adB : adA) + 2*slot];
          float s   = sc[ct][r] + ((e == 1) ? 0.f : pos);
          sc[ct][r] = exp2fast(s);
        }
      }
    } else {
      // fast path: u uniform, 4 consecutive ring words per ct (mirror cols
      // 128..130 absorb the slot wrap) -> compiler merges to ds_read2_b32
      const int u  = (k0 > a0) ? 1 : 0;
      const int iu = iQ + u;
      const unsigned* wrow = &Pb2[(iu >> 1) * 132];
      const int sh = (iu & 1) << 4;
      const int sb = base - 1 - u + 4*quad - l15 + 2048;
#pragma unroll
      for (int ct = 0; ct < 4; ++ct) {
        const int s0 = (sb + 16*ct) & 127;
        unsigned w0 = wrow[s0];
        unsigned w1 = wrow[s0 + 1];
        unsigned w2 = wrow[s0 + 2];
        unsigned w3 = wrow[s0 + 3];
        sc[ct][0] = exp2fast(sc[ct][0] + h2f(w0, sh));
        sc[ct][1] = exp2fast(sc[ct][1] + h2f(w1, sh));
        sc[ct][2] = exp2fast(sc[ct][2] + h2f(w2, sh));
        sc[ct][3] = exp2fast(sc[ct][3] + h2f(w3, sh));
      }
    }

    // ---- PV straight from registers: 4x4 K=16 bf16 MFMAs + ones-l ----
    __builtin_amdgcn_s_setprio(1);
#pragma unroll
    for (int ctk = 0; ctk < 4; ++ctk) {
      unsigned lo = pkb2(sc[ctk][0], sc[ctk][1]);
      unsigned hi = pkb2(sc[ctk][2], sc[ctk][3]);
      b16x4 aF = __builtin_bit_cast(b16x4, (u32x2){lo, hi});
      acc_l = mfma16bf(aF, ONESB, acc_l);     // l partial (all cols equal)
#pragma unroll
      for (int ctd = 0; ctd < 4; ++ctd) {
        b16x4 bF = *(const b16x4*)&Vt[swzv(16*ctd + l15, 16*ctk + 4*quad)];
        Oacc[ctd] = mfma16bf(aF, bF, Oacc[ctd]);
      }
    }
    __builtin_amdgcn_s_setprio(0);

    if (k0 < SQ - 64) bandMFMA();     // next iter's 64 new ring cols (regs)
  }

  // ---- epilogue: O = Oacc / l, l in-lane from ones-MFMA ----
#pragma unroll
  for (int r = 0; r < 4; ++r) {
    float inv = 1.0f / acc_l[r];
    const size_t rowo = (size_t)n * SQ * HD + (size_t)(a0 + iiB + r) * HD;
#pragma unroll
    for (int ct = 0; ct < 4; ++ct)
      O[rowo + 16*ct + l15] = Oacc[ct][r] * inv;
  }
}

// ---------------- fallback (R3-style, raw inputs) for small ws ----------------

__global__ __launch_bounds__(256, 4) void relpos_sdpa_fb(
    const float* __restrict__ Q, const float* __restrict__ K,
    const float* __restrict__ V, const float* __restrict__ Ub,
    const float* __restrict__ Vb, const float* __restrict__ R,
    float* __restrict__ O)
{
  const int n    = blockIdx.x;
  const int h    = n & (NHD - 1);
  const int a0   = blockIdx.y * 64;
  const int tid  = threadIdx.x;
  const int lane = tid & 63, wave = tid >> 6;
  const int l15  = lane & 15, quad = lane >> 4;

  const float* Qn = Q + (size_t)n * SQ * HD;
  const float* Kn = K + (size_t)n * SQ * HD;
  const float* Vn = V + (size_t)n * SQ * HD;
  const float* Rh = R + (size_t)h * RMAX * HD;

  __shared__ __align__(16) char lds[38656];
  _Float16* Kb = (_Float16*)lds;
  short*    Ps = (short*)lds;
  short*    Vt = (short*)(lds + 9216);
  _Float16* Pb = (_Float16*)(lds + 9216 + 11520);

  f16x8 quF[2], qvF[5][2];
#pragma unroll
  for (int ks = 0; ks < 2; ++ks) {
    const int db = ks * 32 + quad * 8;
    float ub[8], vb[8];
#pragma unroll
    for (int j = 0; j < 8; ++j) { ub[j] = Ub[h*HD + db + j]; vb[j] = Vb[h*HD + db + j]; }
    {
      const float* p = Qn + (size_t)(a0 + 16*wave + l15) * HD + db;
      f16x8 f;
#pragma unroll
      for (int j = 0; j < 8; ++j) f[j] = (_Float16)(p[j] * 0.125f + ub[j]);
      quF[ks] = f;
    }
#pragma unroll
    for (int rt = 0; rt < 5; ++rt) {
      int row = a0 + 16*rt + l15; if (row > SQ-1) row = SQ-1;
      const float* p = Qn + (size_t)row * HD + db;
      f16x8 f;
#pragma unroll
      for (int j = 0; j < 8; ++j) f[j] = (_Float16)(p[j] * 0.125f + vb[j]);
      qvF[rt][ks] = f;
    }
  }

  if (tid < 64) Vt[64*72 + tid] = (short)0x3F80;

  f32x4 Oacc[5];
#pragma unroll
  for (int ct = 0; ct < 5; ++ct) Oacc[ct] = (f32x4){0.f, 0.f, 0.f, 0.f};

  auto band = [&](int jstart) {
    const int c    = jstart + 16*wave + l15;
    const int j    = (c + 2048) & (SQ - 1);
    const int slot = (c + 2048) & 127;
    const float* rp = Rh + (size_t)j * HD + quad * 8;
    f16x8 B0, B1;
    {
      float4 x0 = *(const float4*)(rp),      x1 = *(const float4*)(rp + 4);
      float4 y0 = *(const float4*)(rp + 32), y1 = *(const float4*)(rp + 36);
#pragma unroll
      for (int t = 0; t < 4; ++t) { B0[t] = (_Float16)(&x0.x)[t]; B0[t+4] = (_Float16)(&x1.x)[t]; }
#pragma unroll
      for (int t = 0; t < 4; ++t) { B1[t] = (_Float16)(&y0.x)[t]; B1[t+4] = (_Float16)(&y1.x)[t]; }
    }
#pragma unroll
    for (int rt = 0; rt < 5; ++rt) {
      f32x4 acc = (f32x4){0.f, 0.f, 0.f, 0.f};
      acc = MFMA_F16(qvF[rt][0], B0, acc);
      acc = MFMA_F16(qvF[rt][1], B1, acc);
      const int row = 16*rt + 4*quad;
      if (rt < 4) {
        *(unsigned*)&Pb[slot*70 + row]     = pkh(acc[0], acc[1]);
        *(unsigned*)&Pb[slot*70 + row + 2] = pkh(acc[2], acc[3]);
      } else if (quad == 0) {
        *(unsigned*)&Pb[slot*70 + row]     = pkh(acc[0], acc[1]);
      }
    }
  };

  band(-a0 - 65);
  band(-a0 - 1);

  const int sr = tid >> 2, sc4 = tid & 3;
  const int iiB = 16*wave + 4*quad;

  for (int k0 = 0; k0 < SQ; k0 += 64) {
    __syncthreads();
    {
      const float* src = Kn + (size_t)(k0 + sr) * HD + sc4 * 16;
      float4 x0 = *(const float4*)(src),     x1 = *(const float4*)(src + 4);
      float4 y0 = *(const float4*)(src + 8), y1 = *(const float4*)(src + 12);
      f16x8 lo, hi;
#pragma unroll
      for (int t = 0; t < 4; ++t) { lo[t] = (_Float16)(&x0.x)[t]; lo[t+4] = (_Float16)(&x1.x)[t]; }
#pragma unroll
      for (int t = 0; t < 4; ++t) { hi[t] = (_Float16)(&y0.x)[t]; hi[t+4] = (_Float16)(&y1.x)[t]; }
      *(f16x8*)&Kb[sr*72 + sc4*16]     = lo;
      *(f16x8*)&Kb[sr*72 + sc4*16 + 8] = hi;
    }
    {
      const int g = lane >> 3;
#pragma unroll
      for (int i = 0; i < 8; ++i) {
        int bp = 8*wave + (i ^ g);
        float v0 = Vn[(size_t)(k0 + 2*bp)     * HD + lane];
        float v1 = Vn[(size_t)(k0 + 2*bp + 1) * HD + lane];
        *(unsigned*)&Vt[lane*72 + 2*bp] = pkb2(v0, v1);
      }
    }
    __syncthreads();

    f32x4 sc[4];
#pragma unroll
    for (int ct = 0; ct < 4; ++ct) {
      f16x8 b0 = *(const f16x8*)&Kb[(16*ct + l15)*72 + quad*8];
      f16x8 b1 = *(const f16x8*)&Kb[(16*ct + l15)*72 + 32 + quad*8];
      f32x4 acc = (f32x4){0.f, 0.f, 0.f, 0.f};
      acc = MFMA_F16(quF[0], b0, acc);
      acc = MFMA_F16(quF[1], b1, acc);
      sc[ct] = acc;
    }

    const int dlt = k0 - a0;
#pragma unroll
    for (int r = 0; r < 4; ++r) {
      const int ii = iiB + r;
#pragma unroll
      for (int ct = 0; ct < 4; ++ct) {
        const int e    = dlt + 16*ct + l15 - ii;
        const int u    = (e > 0) ? 1 : 0;
        const int slot = (e - 1 - u + 2048) & 127;
        float pos = (float)Pb[slot*70 + ii + u];
        float s   = sc[ct][r] + ((e == 1) ? 0.f : pos);
        sc[ct][r] = __expf(s - 40.0f);
      }
    }
    __syncthreads();

#pragma unroll
    for (int r = 0; r < 4; ++r)
#pragma unroll
      for (int ct = 0; ct < 4; ++ct)
        Ps[(iiB + r)*68 + 16*ct + l15] = f2b(sc[ct][r]);

    b16x8 pA0 = *(const b16x8*)&Ps[(16*wave + l15)*68 + quad*8];
    b16x8 pA1 = *(const b16x8*)&Ps[(16*wave + l15)*68 + 32 + quad*8];
#pragma unroll
    for (int ct = 0; ct < 5; ++ct) {
      b16x8 v0 = *(const b16x8*)&Vt[(16*ct + l15)*72 + quad*8];
      b16x8 v1 = *(const b16x8*)&Vt[(16*ct + l15)*72 + 32 + quad*8];
      Oacc[ct] = MFMA_BF16(pA0, v0, Oacc[ct]);
      Oacc[ct] = MFMA_BF16(pA1, v1, Oacc[ct]);
    }

    if (k0 < SQ - 64) band(k0 + 64 - a0 - 1);
  }

#pragma unroll
  for (int r = 0; r < 4; ++r) {
    float l   = __shfl(Oacc[4][r], lane & 48);
    float inv = 1.0f / l;
    const size_t rowo = (size_t)n * SQ * HD + (size_t)(a0 + iiB + r) * HD;
#pragma unroll
    for (int ct = 0; ct < 4; ++ct)
      O[rowo + 16*ct + l15] = Oacc[ct][r] * inv;
  }
}

extern "C" void kernel_launch(void* const* d_in, const int* in_sizes, int n_in,
                              void* d_out, int out_size, void* d_ws, size_t ws_size,
                              hipStream_t stream) {
  const float* Q  = (const float*)d_in[0];
  const float* K  = (const float*)d_in[1];
  const float* V  = (const float*)d_in[2];
  const float* Ub = (const float*)d_in[3];  // (1,16,1,64)
  const float* Vb = (const float*)d_in[4];
  const float* R  = (const float*)d_in[5];  // (16,2048,64)
  float* O = (float*)d_out;

  if (ws_size >= WS_NEED) {
    _Float16* Kh  = (_Float16*)((char*)d_ws + KH_OFF);
    short*    Vt  = (short*)((char*)d_ws + VT_OFF);
    _Float16* R16 = (_Float16*)((char*)d_ws + R16_OFF);

    preprep<<<6144, 256, 0, stream>>>(K, R, V, Kh, R16, Vt);

    dim3 grid(64, 16);   // x = n (XCD locality), y = q-tile
    relpos_sdpa_r16<<<grid, 256, 0, stream>>>(Q, Kh, Vt, R16, Ub, Vb, O);
  } else {
    dim3 grid(64, 16);
    relpos_sdpa_fb<<<grid, 256, 0, stream>>>(Q, K, V, Ub, Vb, R, O);
  }
}

// Round 10
// 167.864 us; speedup vs baseline: 1.6708x; 1.0122x over previous
//
#include <hip/hip_runtime.h>

// RelativePositionSDPA — R17: R16 compute structure + DMA staging (T3/T4-lite).
//
// R16 post-mortem: batched gather + setprio null; conflicts bit-identical
// 3211264 across 6 kernels with different ring layouts => counter no longer
// localizes anything real (~2% of time). LDS pipe ~54% (not saturated);
// occupancy register-pinned at 2 blocks/CU. Lever: remove the staging VGPR
// round-trip + barrier drains.
//
// R17:
//  1. Kb/Vt staged via __builtin_amdgcn_global_load_lds width=16 (4 DMA ops/
//     wave/iter). Linear LDS dest + pre-swizzled per-lane GLOBAL source
//     (m173): slot = lane + 64*(2w+i) => r = 8*(2w+i)+(l>>3),
//     g = (l&7)^((l>>3)&7) reproduces swz() exactly. Vt's half-XOR is baked
//     into the ws by preprep (u32-granular ^4 on rows with bit3) so swzv()
//     reads are unchanged. Read side untouched => numerics identical.
//  2. Double-buffered Kb/Vt (LDS 50192 B; still 2 blocks/CU — free) + raw
//     s_barrier with counted vmcnt(6) (never 0 mid-loop): DMA for tile k+1
//     flies across the whole compute phase. sched_barrier(0) fences pin
//     issue order so the counts are exact (rules #18/#19).
//
// Everything else identical to R16: swapped-operand QK^T, reg-direct PV
// (K=16 bf16), band-load hoist, deferred ring flush + mirror cols, batched
// gather, setprio, C-init softmax shift, exp2 domain.

#define SQ    1024
#define HD    64
#define NHD   16
#define RMAX  2048

typedef _Float16 f16x8 __attribute__((ext_vector_type(8)));
typedef _Float16 f16x4 __attribute__((ext_vector_type(4)));
typedef short    b16x8 __attribute__((ext_vector_type(8)));
typedef short    b16x4 __attribute__((ext_vector_type(4)));
typedef float    f32x4 __attribute__((ext_vector_type(4)));
typedef unsigned u32x2 __attribute__((ext_vector_type(2)));
typedef unsigned u32x4 __attribute__((ext_vector_type(4)));

#define MFMA_F16(A,B,C)  __builtin_amdgcn_mfma_f32_16x16x32_f16((A),(B),(C),0,0,0)
#define MFMA_BF16(A,B,C) __builtin_amdgcn_mfma_f32_16x16x32_bf16((A),(B),(C),0,0,0)

#define L2E    1.44269504088896f    // log2(e)
#define NSHIFT (-57.7078016f)       // -40 * log2(e)

// ws layout
#define KH_OFF   0                       // f16 [64][1024][64]   8 MB
#define VT_OFF   (8u << 20)              // bf16 [64][80][1024]  10 MB (half-XOR'd rows)
#define R16_OFF  (18u << 20)             // f16 [16][1024][64]   2 MB
#define WS_NEED  (20u << 20)

__device__ __forceinline__ float exp2fast(float x) {
#if __has_builtin(__builtin_amdgcn_exp2f)
  return __builtin_amdgcn_exp2f(x);          // v_exp_f32 (2^x native)
#else
  return __expf(x * 0.693147180559945f);
#endif
}

// K=16 bf16 MFMA; zero-padded K=32 fallback is mathematically identical.
__device__ __forceinline__ f32x4 mfma16bf(b16x4 a, b16x4 b, f32x4 c) {
#if __has_builtin(__builtin_amdgcn_mfma_f32_16x16x16bf16_1k)
  return __builtin_amdgcn_mfma_f32_16x16x16bf16_1k(a, b, c, 0, 0, 0);
#else
  b16x8 az = {a[0], a[1], a[2], a[3], 0, 0, 0, 0};
  b16x8 bz = {b[0], b[1], b[2], b[3], 0, 0, 0, 0};
  return MFMA_BF16(az, bz, c);
#endif
}

__device__ __forceinline__ short f2b(float f) {          // fp32 -> bf16 RTN-even
  unsigned u = __builtin_bit_cast(unsigned, f);
  u += 0x7FFFu + ((u >> 16) & 1u);
  return (short)(u >> 16);
}
__device__ __forceinline__ unsigned pkh(float a, float b) {  // 2xf32 -> packed f16 RTN
  _Float16 h0 = (_Float16)a, h1 = (_Float16)b;
  return (unsigned)__builtin_bit_cast(unsigned short, h0)
       | ((unsigned)__builtin_bit_cast(unsigned short, h1) << 16);
}
// 2xf32 -> packed bf16, round-half-away (differs from RTN-even only on ties)
__device__ __forceinline__ unsigned pkb2(float a, float b) {
  unsigned ua = __builtin_bit_cast(unsigned, a) + 0x8000u;
  unsigned ub = __builtin_bit_cast(unsigned, b) + 0x8000u;
  return (ub & 0xFFFF0000u) | (ua >> 16);
}
// f16 half (sh=0 lo, sh=16 hi) of a packed u32 -> float
__device__ __forceinline__ float h2f(unsigned w, int sh) {
  return (float)__builtin_bit_cast(_Float16, (unsigned short)(w >> sh));
}
// XOR-swizzled element address inside a [rows][64] 2B-elem tile (Kb).
__device__ __forceinline__ int swz(int row, int col) {
  return row*64 + ((((col >> 3) ^ row) & 7) << 3) + (col & 7);
}
// Vt variant: + half-XOR with row bit3 (conflict-free b64 PV reads).
__device__ __forceinline__ int swzv(int row, int col) {
  return row*64 + ((((col >> 3) ^ row) & 7) << 3)
       + ((col & 7) ^ ((row & 8) >> 1));
}

// ---------------- merged precompute kernel ----------------
// Vt ws rows now stored with half-XOR baked in: within each 16-elem group,
// elem offset ^= 4 when (row & 8) — so the main kernel's 16B DMA chunks
// deposit the swzv() in-granule order directly.

__global__ __launch_bounds__(256) void preprep(
    const float* __restrict__ K, const float* __restrict__ R,
    const float* __restrict__ V,
    _Float16* __restrict__ Kh, _Float16* __restrict__ R16,
    short* __restrict__ Vt)
{
  __shared__ float t[64][65];
  const int bid = blockIdx.x, tid = threadIdx.x;
  if (bid < 1024) {
    const int n = bid >> 4, st = bid & 15;
    {
      const int row = tid >> 2, c0 = (tid & 3) * 16;
      const float* src = V + ((size_t)n * SQ + st * 64 + row) * HD + c0;
#pragma unroll
      for (int i = 0; i < 4; ++i) {
        float4 x = ((const float4*)src)[i];
        t[row][c0 + 4*i + 0] = x.x; t[row][c0 + 4*i + 1] = x.y;
        t[row][c0 + 4*i + 2] = x.z; t[row][c0 + 4*i + 3] = x.w;
      }
    }
    __syncthreads();
    {
      const int d = tid >> 2, s0 = (tid & 3) * 16;
      const int xo = (d & 8) ? 4 : 0;                 // half-XOR baked into ws
      short* dst = Vt + ((size_t)n * 80 + d) * SQ + st * 64 + s0;
#pragma unroll
      for (int i = 0; i < 8; ++i)
        *(unsigned*)(dst + (2*i ^ xo)) = pkb2(t[s0 + 2*i][d], t[s0 + 2*i + 1][d]);
    }
    if (tid < 64) {          // rows 64..79 unused by main; kept harmless
      const int s = st * 64 + tid;
      Vt[((size_t)n * 80 + 64) * SQ + s] = (short)0x3F80;
#pragma unroll
      for (int r = 65; r < 80; ++r) Vt[((size_t)n * 80 + r) * SQ + s] = 0;
    }
  } else {
    const int idx = (bid - 1024) * 256 + tid;            // float4 index
    const int nk4 = (64 * SQ * HD) / 4;                  // 1048576
    if (idx < nk4) {
      float4 v = ((const float4*)K)[idx];
      f16x4 o = { (_Float16)v.x, (_Float16)v.y, (_Float16)v.z, (_Float16)v.w };
      *(f16x4*)(Kh + 4 * (size_t)idx) = o;
    } else {
      int rr = idx - nk4;                                // < 262144
      int h  = rr >> 14, off = rr & 16383;               // 16384 float4/head
      float4 v = ((const float4*)R)[((size_t)h << 15) + off];
      f16x4 o = { (_Float16)v.x, (_Float16)v.y, (_Float16)v.z, (_Float16)v.w };
      *(f16x4*)(R16 + 4 * (((size_t)h << 14) + off)) = o;
    }
  }
}

// ---------------- main flash kernel (R17) ----------------

__global__ __launch_bounds__(256, 3) void relpos_sdpa_r17(
    const float* __restrict__ Q, const _Float16* __restrict__ Kh,
    const short* __restrict__ Vtg, const _Float16* __restrict__ R16,
    const float* __restrict__ Ub, const float* __restrict__ Vb,
    float* __restrict__ O)
{
  const int n    = blockIdx.x;
  const int h    = n & (NHD - 1);
  const int a0   = blockIdx.y * 64;
  const int tid  = threadIdx.x;
  const int lane = tid & 63, wave = tid >> 6;
  const int l15  = lane & 15, quad = lane >> 4;

  const float*    Qn  = Q   + (size_t)n * SQ * HD;
  const _Float16* Khn = Kh  + (size_t)n * SQ * HD;
  const short*    Vgn = Vtg + (size_t)n * 80 * SQ;
  const _Float16* Rh  = R16 + (size_t)h * SQ * HD;

  // LDS: Kb f16 [2][64][64] swz   @ 0      (2 x 8192)
  //      Vt bf16 [2][64][64] swzv @ 16384  (2 x 8192)
  //      ring u32 [33][132]       @ 32768  (17424; cols 128..130 mirror 0..2)
  // total 50192 B -> 2 blocks/CU (occupancy is register-pinned at 2 anyway).
  __shared__ __align__(16) char lds[50192];
  unsigned*       Pb2  = (unsigned*)(lds + 32768);
  const _Float16* Pb2h = (const _Float16*)Pb2;

  // DMA: linear LDS dest (slot = lane + 64*(2w+i)), pre-swizzled global src.
  auto gload16 = [&](const void* g, void* l) {
#if __has_builtin(__builtin_amdgcn_global_load_lds)
    __builtin_amdgcn_global_load_lds(
        (const __attribute__((address_space(1))) unsigned*)g,
        (__attribute__((address_space(3))) unsigned*)l, 16, 0, 0);
#else
    *(u32x4*)((char*)l + lane * 16) = *(const u32x4*)g;   // reg round-trip
#endif
  };
  auto dmaStage = [&](int kk, int buf) {
    const int rb = lane >> 3;
    const int g  = (lane & 7) ^ ((lane >> 3) & 7);
    char* kdst = lds + buf * 8192;
    char* vdst = lds + 16384 + buf * 8192;
#pragma unroll
    for (int i = 0; i < 2; ++i) {
      const int sub = 2*wave + i;
      const int r   = 8*sub + rb;
      gload16(Khn + (size_t)(kk + r) * HD + 8*g, kdst + sub * 1024);
      gload16(Vgn + (size_t)r * SQ + kk + 8*g,   vdst + sub * 1024);
    }
  };

  dmaStage(0, 0);   // tile 0 in flight under the whole prologue

  // ---- persistent q fragments, pre-scaled by log2(e) ----
  f16x8 quF[2], qvF[5][2];
#pragma unroll
  for (int ks = 0; ks < 2; ++ks) {
    const int db = ks * 32 + quad * 8;
    float ub[8], vb[8];
#pragma unroll
    for (int j = 0; j < 8; ++j) {
      ub[j] = Ub[h*HD + db + j] * L2E;
      vb[j] = Vb[h*HD + db + j] * L2E;
    }
    {
      const float* p = Qn + (size_t)(a0 + 16*wave + l15) * HD + db;
      float4 x0 = ((const float4*)p)[0], x1 = ((const float4*)p)[1];
      f16x8 f;
#pragma unroll
      for (int t = 0; t < 4; ++t) {
        f[t]   = (_Float16)((&x0.x)[t] * (0.125f * L2E) + ub[t]);
        f[t+4] = (_Float16)((&x1.x)[t] * (0.125f * L2E) + ub[t+4]);
      }
      quF[ks] = f;
    }
#pragma unroll
    for (int rt = 0; rt < 5; ++rt) {
      int row = a0 + 16*rt + l15; if (row > SQ-1) row = SQ-1;
      const float* p = Qn + (size_t)row * HD + db;
      float4 x0 = ((const float4*)p)[0], x1 = ((const float4*)p)[1];
      f16x8 f;
#pragma unroll
      for (int t = 0; t < 4; ++t) {
        f[t]   = (_Float16)((&x0.x)[t] * (0.125f * L2E) + vb[t]);
        f[t+4] = (_Float16)((&x1.x)[t] * (0.125f * L2E) + vb[t+4]);
      }
      qvF[rt][ks] = f;
    }
  }

  f32x4 Oacc[4], acc_l;
#pragma unroll
  for (int ct = 0; ct < 4; ++ct) Oacc[ct] = (f32x4){0.f, 0.f, 0.f, 0.f};
  acc_l = (f32x4){0.f, 0.f, 0.f, 0.f};

  const b16x4 ONESB = {(short)0x3F80, (short)0x3F80, (short)0x3F80, (short)0x3F80};

  // ---- band, split: bandLoad (issue R16 loads early) / bandMFMA (compute) ----
  unsigned ringW[9];
  int ringSlot, ringSlotN;
  f16x8 bB0, bB1;
  auto bandLoad = [&](int jstart) {
    const int c = jstart + 16*wave + l15;
    const int j = (c + 2048) & (SQ - 1);
    ringSlotN   = (c + 2048) & 127;
    const _Float16* rp = Rh + (size_t)j * HD + quad * 8;
    bB0 = *(const f16x8*)rp;
    bB1 = *(const f16x8*)(rp + 32);
  };
  auto bandMFMA = [&]() {
    ringSlot = ringSlotN;
    __builtin_amdgcn_s_setprio(1);
#pragma unroll
    for (int rt = 0; rt < 5; ++rt) {
      f32x4 acc = (f32x4){0.f, 0.f, 0.f, 0.f};
      acc = MFMA_F16(qvF[rt][0], bB0, acc);
      acc = MFMA_F16(qvF[rt][1], bB1, acc);
      if (rt < 4) {
        ringW[2*rt]     = pkh(acc[0], acc[1]);
        ringW[2*rt + 1] = pkh(acc[2], acc[3]);
      } else {
        ringW[8] = pkh(acc[0], acc[1]);   // row 64 (only quad 0's used)
      }
    }
    __builtin_amdgcn_s_setprio(0);
  };
  auto ringFlush = [&]() {
#pragma unroll
    for (int rt = 0; rt < 4; ++rt) {
      const int rp0 = 8*rt + 2*quad;                 // rows 16rt+4q .. +3
      Pb2[rp0*132 + ringSlot]       = ringW[2*rt];
      Pb2[(rp0 + 1)*132 + ringSlot] = ringW[2*rt + 1];
    }
    if (quad == 0) Pb2[32*132 + ringSlot] = ringW[8];
    if (ringSlot < 3) {                              // mirror cols 128..130
      const int ms = ringSlot + 128;
#pragma unroll
      for (int rt = 0; rt < 4; ++rt) {
        const int rp0 = 8*rt + 2*quad;
        Pb2[rp0*132 + ms]       = ringW[2*rt];
        Pb2[(rp0 + 1)*132 + ms] = ringW[2*rt + 1];
      }
      if (quad == 0) Pb2[32*132 + ms] = ringW[8];
    }
  };

  // prologue: fill all 128 ring slots for iter 0 (pre-loop, no races)
  bandLoad(-a0 - 65);  bandMFMA();  ringFlush();
  bandLoad(-a0 - 1);   bandMFMA();  ringFlush();

  const int iiB = 16*wave + 4*quad;
  const int iQ  = 16*wave + l15;          // this lane's q-local row (swapped)

  int cur = 0;
  for (int k0 = 0; k0 < SQ; k0 += 64) {
    // ---- barrier A: prev compute's LDS reads + ring gathers done ----
    __builtin_amdgcn_sched_barrier(0);
    asm volatile("s_waitcnt lgkmcnt(0)" ::: "memory");
    __builtin_amdgcn_s_barrier();
    __builtin_amdgcn_sched_barrier(0);

    if (k0 > 0) ringFlush();          // ring cols from prev iter's bandMFMA
    if (k0 < SQ - 64) {
      bandLoad(k0 + 64 - a0 - 1);     // 2 vmem (for this iter's bandMFMA)
      dmaStage(k0 + 64, cur ^ 1);     // 4 vmem -> other buffer
      __builtin_amdgcn_sched_barrier(0);
      asm volatile("s_waitcnt vmcnt(6) lgkmcnt(0)" ::: "memory");  // tile k0 done
    } else {
      __builtin_amdgcn_sched_barrier(0);
      asm volatile("s_waitcnt vmcnt(0) lgkmcnt(0)" ::: "memory");
    }
    // ---- barrier B: Kb/Vt[cur] staged + ring visible ----
    __builtin_amdgcn_s_barrier();
    __builtin_amdgcn_sched_barrier(0);

    const _Float16* Kb = (const _Float16*)(lds + (cur << 13));
    const short*    Vt = (const short*)(lds + 16384 + (cur << 13));

    // ---- content scores, SWAPPED: sc[ct][r] = S[key=16ct+4q+r][q=16w+l15] ----
    f32x4 sc[4];
    __builtin_amdgcn_s_setprio(1);
#pragma unroll
    for (int ct = 0; ct < 4; ++ct) {
      f16x8 ka = *(const f16x8*)&Kb[swz(16*ct + l15, quad*8)];
      f16x8 kb = *(const f16x8*)&Kb[swz(16*ct + l15, 32 + quad*8)];
      f32x4 acc = (f32x4){NSHIFT, NSHIFT, NSHIFT, NSHIFT};
      acc = MFMA_F16(ka, quF[0], acc);        // A = K-frag, B = Q-frag
      acc = MFMA_F16(kb, quF[1], acc);
      sc[ct] = acc;
    }
    __builtin_amdgcn_s_setprio(0);

    // ---- ring gather + exp2 (swapped indexing) ----
    const int base = k0 - a0 - 16*wave;
    if (k0 == a0 || k0 == a0 + 64) {
      // general path (2/16 iters): per-element u / e==1 handling
      const int adA = (iQ >> 1) * 264 + (iQ & 1);                // u=0
      const int adB = ((iQ + 1) >> 1) * 264 + ((iQ + 1) & 1);    // u=1
#pragma unroll
      for (int ct = 0; ct < 4; ++ct) {
        const int e0 = base + 16*ct + 4*quad - l15;
#pragma unroll
        for (int r = 0; r < 4; ++r) {
          const int e    = e0 + r;
          const int u    = (e > 0) ? 1 : 0;
          const int slot = (e - 1 - u) & 127;
          float pos = (float)Pb2h[(u ? adB : adA) + 2*slot];
          float s   = sc[ct][r] + ((e == 1) ? 0.f : pos);
          sc[ct][r] = exp2fast(s);
        }
      }
    } else {
      // fast path: u uniform, 4 consecutive ring words per ct (mirrors absorb wrap)
      const int u  = (k0 > a0) ? 1 : 0;
      const int iu = iQ + u;
      const unsigned* wrow = &Pb2[(iu >> 1) * 132];
      const int sh = (iu & 1) << 4;
      const int sb = base - 1 - u + 4*quad - l15 + 2048;
#pragma unroll
      for (int ct = 0; ct < 4; ++ct) {
        const int s0 = (sb + 16*ct) & 127;
        unsigned w0 = wrow[s0];
        unsigned w1 = wrow[s0 + 1];
        unsigned w2 = wrow[s0 + 2];
        unsigned w3 = wrow[s0 + 3];
        sc[ct][0] = exp2fast(sc[ct][0] + h2f(w0, sh));
        sc[ct][1] = exp2fast(sc[ct][1] + h2f(w1, sh));
        sc[ct][2] = exp2fast(sc[ct][2] + h2f(w2, sh));
        sc[ct][3] = exp2fast(sc[ct][3] + h2f(w3, sh));
      }
    }

    // ---- PV straight from registers: 4x4 K=16 bf16 MFMAs + ones-l ----
    __builtin_amdgcn_s_setprio(1);
#pragma unroll
    for (int ctk = 0; ctk < 4; ++ctk) {
      unsigned lo = pkb2(sc[ctk][0], sc[ctk][1]);
      unsigned hi = pkb2(sc[ctk][2], sc[ctk][3]);
      b16x4 aF = __builtin_bit_cast(b16x4, (u32x2){lo, hi});
      acc_l = mfma16bf(aF, ONESB, acc_l);     // l partial (all cols equal)
#pragma unroll
      for (int ctd = 0; ctd < 4; ++ctd) {
        b16x4 bF = *(const b16x4*)&Vt[swzv(16*ctd + l15, 16*ctk + 4*quad)];
        Oacc[ctd] = mfma16bf(aF, bF, Oacc[ctd]);
      }
    }
    __builtin_amdgcn_s_setprio(0);

    if (k0 < SQ - 64) bandMFMA();     // next iter's 64 new ring cols (regs)
    cur ^= 1;
  }

  // ---- epilogue: O = Oacc / l, l in-lane from ones-MFMA ----
#pragma unroll
  for (int r = 0; r < 4; ++r) {
    float inv = 1.0f / acc_l[r];
    const size_t rowo = (size_t)n * SQ * HD + (size_t)(a0 + iiB + r) * HD;
#pragma unroll
    for (int ct = 0; ct < 4; ++ct)
      O[rowo + 16*ct + l15] = Oacc[ct][r] * inv;
  }
}

// ---------------- fallback (R3-style, raw inputs) for small ws ----------------

__global__ __launch_bounds__(256, 4) void relpos_sdpa_fb(
    const float* __restrict__ Q, const float* __restrict__ K,
    const float* __restrict__ V, const float* __restrict__ Ub,
    const float* __restrict__ Vb, const float* __restrict__ R,
    float* __restrict__ O)
{
  const int n    = blockIdx.x;
  const int h    = n & (NHD - 1);
  const int a0   = blockIdx.y * 64;
  const int tid  = threadIdx.x;
  const int lane = tid & 63, wave = tid >> 6;
  const int l15  = lane & 15, quad = lane >> 4;

  const float* Qn = Q + (size_t)n * SQ * HD;
  const float* Kn = K + (size_t)n * SQ * HD;
  const float* Vn = V + (size_t)n * SQ * HD;
  const float* Rh = R + (size_t)h * RMAX * HD;

  __shared__ __align__(16) char lds[38656];
  _Float16* Kb = (_Float16*)lds;
  short*    Ps = (short*)lds;
  short*    Vt = (short*)(lds + 9216);
  _Float16* Pb = (_Float16*)(lds + 9216 + 11520);

  f16x8 quF[2], qvF[5][2];
#pragma unroll
  for (int ks = 0; ks < 2; ++ks) {
    const int db = ks * 32 + quad * 8;
    float ub[8], vb[8];
#pragma unroll
    for (int j = 0; j < 8; ++j) { ub[j] = Ub[h*HD + db + j]; vb[j] = Vb[h*HD + db + j]; }
    {
      const float* p = Qn + (size_t)(a0 + 16*wave + l15) * HD + db;
      f16x8 f;
#pragma unroll
      for (int j = 0; j < 8; ++j) f[j] = (_Float16)(p[j] * 0.125f + ub[j]);
      quF[ks] = f;
    }
#pragma unroll
    for (int rt = 0; rt < 5; ++rt) {
      int row = a0 + 16*rt + l15; if (row > SQ-1) row = SQ-1;
      const float* p = Qn + (size_t)row * HD + db;
      f16x8 f;
#pragma unroll
      for (int j = 0; j < 8; ++j) f[j] = (_Float16)(p[j] * 0.125f + vb[j]);
      qvF[rt][ks] = f;
    }
  }

  if (tid < 64) Vt[64*72 + tid] = (short)0x3F80;

  f32x4 Oacc[5];
#pragma unroll
  for (int ct = 0; ct < 5; ++ct) Oacc[ct] = (f32x4){0.f, 0.f, 0.f, 0.f};

  auto band = [&](int jstart) {
    const int c    = jstart + 16*wave + l15;
    const int j    = (c + 2048) & (SQ - 1);
    const int slot = (c + 2048) & 127;
    const float* rp = Rh + (size_t)j * HD + quad * 8;
    f16x8 B0, B1;
    {
      float4 x0 = *(const float4*)(rp),      x1 = *(const float4*)(rp + 4);
      float4 y0 = *(const float4*)(rp + 32), y1 = *(const float4*)(rp + 36);
#pragma unroll
      for (int t = 0; t < 4; ++t) { B0[t] = (_Float16)(&x0.x)[t]; B0[t+4] = (_Float16)(&x1.x)[t]; }
#pragma unroll
      for (int t = 0; t < 4; ++t) { B1[t] = (_Float16)(&y0.x)[t]; B1[t+4] = (_Float16)(&y1.x)[t]; }
    }
#pragma unroll
    for (int rt = 0; rt < 5; ++rt) {
      f32x4 acc = (f32x4){0.f, 0.f, 0.f, 0.f};
      acc = MFMA_F16(qvF[rt][0], B0, acc);
      acc = MFMA_F16(qvF[rt][1], B1, acc);
      const int row = 16*rt + 4*quad;
      if (rt < 4) {
        *(unsigned*)&Pb[slot*70 + row]     = pkh(acc[0], acc[1]);
        *(unsigned*)&Pb[slot*70 + row + 2] = pkh(acc[2], acc[3]);
      } else if (quad == 0) {
        *(unsigned*)&Pb[slot*70 + row]     = pkh(acc[0], acc[1]);
      }
    }
  };

  band(-a0 - 65);
  band(-a0 - 1);

  const int sr = tid >> 2, sc4 = tid & 3;
  const int iiB = 16*wave + 4*quad;

  for (int k0 = 0; k0 < SQ; k0 += 64) {
    __syncthreads();
    {
      const float* src = Kn + (size_t)(k0 + sr) * HD + sc4 * 16;
      float4 x0 = *(const float4*)(src),     x1 = *(const float4*)(src + 4);
      float4 y0 = *(const float4*)(src + 8), y1 = *(const float4*)(src + 12);
      f16x8 lo, hi;
#pragma unroll
      for (int t = 0; t < 4; ++t) { lo[t] = (_Float16)(&x0.x)[t]; lo[t+4] = (_Float16)(&x1.x)[t]; }
#pragma unroll
      for (int t = 0; t < 4; ++t) { hi[t] = (_Float16)(&y0.x)[t]; hi[t+4] = (_Float16)(&y1.x)[t]; }
      *(f16x8*)&Kb[sr*72 + sc4*16]     = lo;
      *(f16x8*)&Kb[sr*72 + sc4*16 + 8] = hi;
    }
    {
      const int g = lane >> 3;
#pragma unroll
      for (int i = 0; i < 8; ++i) {
        int bp = 8*wave + (i ^ g);
        float v0 = Vn[(size_t)(k0 + 2*bp)     * HD + lane];
        float v1 = Vn[(size_t)(k0 + 2*bp + 1) * HD + lane];
        *(unsigned*)&Vt[lane*72 + 2*bp] = pkb2(v0, v1);
      }
    }
    __syncthreads();

    f32x4 sc[4];
#pragma unroll
    for (int ct = 0; ct < 4; ++ct) {
      f16x8 b0 = *(const f16x8*)&Kb[(16*ct + l15)*72 + quad*8];
      f16x8 b1 = *(const f16x8*)&Kb[(16*ct + l15)*72 + 32 + quad*8];
      f32x4 acc = (f32x4){0.f, 0.f, 0.f, 0.f};
      acc = MFMA_F16(quF[0], b0, acc);
      acc = MFMA_F16(quF[1], b1, acc);
      sc[ct] = acc;
    }

    const int dlt = k0 - a0;
#pragma unroll
    for (int r = 0; r < 4; ++r) {
      const int ii = iiB + r;
#pragma unroll
      for (int ct = 0; ct < 4; ++ct) {
        const int e    = dlt + 16*ct + l15 - ii;
        const int u    = (e > 0) ? 1 : 0;
        const int slot = (e - 1 - u + 2048) & 127;
        float pos = (float)Pb[slot*70 + ii + u];
        float s   = sc[ct][r] + ((e == 1) ? 0.f : pos);
        sc[ct][r] = __expf(s - 40.0f);
      }
    }
    __syncthreads();

#pragma unroll
    for (int r = 0; r < 4; ++r)
#pragma unroll
      for (int ct = 0; ct < 4; ++ct)
        Ps[(iiB + r)*68 + 16*ct + l15] = f2b(sc[ct][r]);

    b16x8 pA0 = *(const b16x8*)&Ps[(16*wave + l15)*68 + quad*8];
    b16x8 pA1 = *(const b16x8*)&Ps[(16*wave + l15)*68 + 32 + quad*8];
#pragma unroll
    for (int ct = 0; ct < 5; ++ct) {
      b16x8 v0 = *(const b16x8*)&Vt[(16*ct + l15)*72 + quad*8];
      b16x8 v1 = *(const b16x8*)&Vt[(16*ct + l15)*72 + 32 + quad*8];
      Oacc[ct] = MFMA_BF16(pA0, v0, Oacc[ct]);
      Oacc[ct] = MFMA_BF16(pA1, v1, Oacc[ct]);
    }

    if (k0 < SQ - 64) band(k0 + 64 - a0 - 1);
  }

#pragma unroll
  for (int r = 0; r < 4; ++r) {
    float l   = __shfl(Oacc[4][r], lane & 48);
    float inv = 1.0f / l;
    const size_t rowo = (size_t)n * SQ * HD + (size_t)(a0 + iiB + r) * HD;
#pragma unroll
    for (int ct = 0; ct < 4; ++ct)
      O[rowo + 16*ct + l15] = Oacc[ct][r] * inv;
  }
}

extern "C" void kernel_launch(void* const* d_in, const int* in_sizes, int n_in,
                              void* d_out, int out_size, void* d_ws, size_t ws_size,
                              hipStream_t stream) {
  const float* Q  = (const float*)d_in[0];
  const float* K  = (const float*)d_in[1];
  const float* V  = (const float*)d_in[2];
  const float* Ub = (const float*)d_in[3];  // (1,16,1,64)
  const float* Vb = (const float*)d_in[4];
  const float* R  = (const float*)d_in[5];  // (16,2048,64)
  float* O = (float*)d_out;

  if (ws_size >= WS_NEED) {
    _Float16* Kh  = (_Float16*)((char*)d_ws + KH_OFF);
    short*    Vt  = (short*)((char*)d_ws + VT_OFF);
    _Float16* R16 = (_Float16*)((char*)d_ws + R16_OFF);

    preprep<<<6144, 256, 0, stream>>>(K, R, V, Kh, R16, Vt);

    dim3 grid(64, 16);   // x = n (XCD locality), y = q-tile
    relpos_sdpa_r17<<<grid, 256, 0, stream>>>(Q, Kh, Vt, R16, Ub, Vb, O);
  } else {
    dim3 grid(64, 16);
    relpos_sdpa_fb<<<grid, 256, 0, stream>>>(Q, K, V, Ub, Vb, R, O);
  }
}

// Round 11
// 165.919 us; speedup vs baseline: 1.6903x; 1.0117x over previous
//
#include <hip/hip_runtime.h>

// RelativePositionSDPA — R18: R17 + gather-load hoist + cvt_pkrtz ring pack.
//
// R17 post-mortem: DMA staging + counted vmcnt WORKED (83.4 -> 77.0us, absmax
// bit-identical, no spill). Pipes still unsaturated at 2 blocks/CU =>
// latency-bound. Remaining chain items:
//  1. The 16 gather u32 loads (fast path) have NO dependency on QK (ring was
//     written last iter) but sit after the QK MFMAs in program order. Hoist
//     them to right after barrier B so their LDS latency hides under the
//     QK matrix work. (+16 transient VGPRs.)
//  2. pkh (3 VALU) -> v_cvt_pkrtz_f16_f32 (1 instr) for the 9 ring packs.
//     RTZ vs RTN: <=1 ulp f16 on pos-scores; absmax may wiggle ~1e-3.
//
// Everything else identical to R17: DMA staging via global_load_lds w=16
// (linear LDS dest + pre-swizzled global src; Vt half-XOR baked in ws),
// double-buffered Kb/Vt, raw s_barrier + counted vmcnt(6), swapped-operand
// QK^T, reg-direct PV (K=16 bf16), band split load/MFMA, deferred ring
// flush + mirror cols, setprio, C-init softmax shift, exp2 domain.

#define SQ    1024
#define HD    64
#define NHD   16
#define RMAX  2048

typedef _Float16 f16x8 __attribute__((ext_vector_type(8)));
typedef _Float16 f16x4 __attribute__((ext_vector_type(4)));
typedef _Float16 f16x2 __attribute__((ext_vector_type(2)));
typedef short    b16x8 __attribute__((ext_vector_type(8)));
typedef short    b16x4 __attribute__((ext_vector_type(4)));
typedef float    f32x4 __attribute__((ext_vector_type(4)));
typedef unsigned u32x2 __attribute__((ext_vector_type(2)));
typedef unsigned u32x4 __attribute__((ext_vector_type(4)));

#define MFMA_F16(A,B,C)  __builtin_amdgcn_mfma_f32_16x16x32_f16((A),(B),(C),0,0,0)
#define MFMA_BF16(A,B,C) __builtin_amdgcn_mfma_f32_16x16x32_bf16((A),(B),(C),0,0,0)

#define L2E    1.44269504088896f    // log2(e)
#define NSHIFT (-57.7078016f)       // -40 * log2(e)

// ws layout
#define KH_OFF   0                       // f16 [64][1024][64]   8 MB
#define VT_OFF   (8u << 20)              // bf16 [64][80][1024]  10 MB (half-XOR'd rows)
#define R16_OFF  (18u << 20)             // f16 [16][1024][64]   2 MB
#define WS_NEED  (20u << 20)

__device__ __forceinline__ float exp2fast(float x) {
#if __has_builtin(__builtin_amdgcn_exp2f)
  return __builtin_amdgcn_exp2f(x);          // v_exp_f32 (2^x native)
#else
  return __expf(x * 0.693147180559945f);
#endif
}

// K=16 bf16 MFMA; zero-padded K=32 fallback is mathematically identical.
__device__ __forceinline__ f32x4 mfma16bf(b16x4 a, b16x4 b, f32x4 c) {
#if __has_builtin(__builtin_amdgcn_mfma_f32_16x16x16bf16_1k)
  return __builtin_amdgcn_mfma_f32_16x16x16bf16_1k(a, b, c, 0, 0, 0);
#else
  b16x8 az = {a[0], a[1], a[2], a[3], 0, 0, 0, 0};
  b16x8 bz = {b[0], b[1], b[2], b[3], 0, 0, 0, 0};
  return MFMA_BF16(az, bz, c);
#endif
}

__device__ __forceinline__ short f2b(float f) {          // fp32 -> bf16 RTN-even
  unsigned u = __builtin_bit_cast(unsigned, f);
  u += 0x7FFFu + ((u >> 16) & 1u);
  return (short)(u >> 16);
}
// 2xf32 -> packed f16 (v_cvt_pkrtz_f16_f32, single instr, RTZ)
__device__ __forceinline__ unsigned pkh(float a, float b) {
#if __has_builtin(__builtin_amdgcn_cvt_pkrtz)
  return __builtin_bit_cast(unsigned, __builtin_amdgcn_cvt_pkrtz(a, b));
#else
  _Float16 h0 = (_Float16)a, h1 = (_Float16)b;
  return (unsigned)__builtin_bit_cast(unsigned short, h0)
       | ((unsigned)__builtin_bit_cast(unsigned short, h1) << 16);
#endif
}
// 2xf32 -> packed bf16, round-half-away (differs from RTN-even only on ties)
__device__ __forceinline__ unsigned pkb2(float a, float b) {
  unsigned ua = __builtin_bit_cast(unsigned, a) + 0x8000u;
  unsigned ub = __builtin_bit_cast(unsigned, b) + 0x8000u;
  return (ub & 0xFFFF0000u) | (ua >> 16);
}
// f16 half (sh=0 lo, sh=16 hi) of a packed u32 -> float
__device__ __forceinline__ float h2f(unsigned w, int sh) {
  return (float)__builtin_bit_cast(_Float16, (unsigned short)(w >> sh));
}
// XOR-swizzled element address inside a [rows][64] 2B-elem tile (Kb).
__device__ __forceinline__ int swz(int row, int col) {
  return row*64 + ((((col >> 3) ^ row) & 7) << 3) + (col & 7);
}
// Vt variant: + half-XOR with row bit3 (conflict-free b64 PV reads).
__device__ __forceinline__ int swzv(int row, int col) {
  return row*64 + ((((col >> 3) ^ row) & 7) << 3)
       + ((col & 7) ^ ((row & 8) >> 1));
}

// ---------------- merged precompute kernel (R17 version) ----------------
// Vt ws rows stored with half-XOR baked in (u32-granular ^4 on rows with
// bit3) so the main kernel's 16B DMA chunks deposit swzv() order directly.

__global__ __launch_bounds__(256) void preprep(
    const float* __restrict__ K, const float* __restrict__ R,
    const float* __restrict__ V,
    _Float16* __restrict__ Kh, _Float16* __restrict__ R16,
    short* __restrict__ Vt)
{
  __shared__ float t[64][65];
  const int bid = blockIdx.x, tid = threadIdx.x;
  if (bid < 1024) {
    const int n = bid >> 4, st = bid & 15;
    {
      const int row = tid >> 2, c0 = (tid & 3) * 16;
      const float* src = V + ((size_t)n * SQ + st * 64 + row) * HD + c0;
#pragma unroll
      for (int i = 0; i < 4; ++i) {
        float4 x = ((const float4*)src)[i];
        t[row][c0 + 4*i + 0] = x.x; t[row][c0 + 4*i + 1] = x.y;
        t[row][c0 + 4*i + 2] = x.z; t[row][c0 + 4*i + 3] = x.w;
      }
    }
    __syncthreads();
    {
      const int d = tid >> 2, s0 = (tid & 3) * 16;
      const int xo = (d & 8) ? 4 : 0;                 // half-XOR baked into ws
      short* dst = Vt + ((size_t)n * 80 + d) * SQ + st * 64 + s0;
#pragma unroll
      for (int i = 0; i < 8; ++i)
        *(unsigned*)(dst + (2*i ^ xo)) = pkb2(t[s0 + 2*i][d], t[s0 + 2*i + 1][d]);
    }
    if (tid < 64) {          // rows 64..79 unused by main; kept harmless
      const int s = st * 64 + tid;
      Vt[((size_t)n * 80 + 64) * SQ + s] = (short)0x3F80;
#pragma unroll
      for (int r = 65; r < 80; ++r) Vt[((size_t)n * 80 + r) * SQ + s] = 0;
    }
  } else {
    const int idx = (bid - 1024) * 256 + tid;            // float4 index
    const int nk4 = (64 * SQ * HD) / 4;                  // 1048576
    if (idx < nk4) {
      float4 v = ((const float4*)K)[idx];
      f16x4 o = { (_Float16)v.x, (_Float16)v.y, (_Float16)v.z, (_Float16)v.w };
      *(f16x4*)(Kh + 4 * (size_t)idx) = o;
    } else {
      int rr = idx - nk4;                                // < 262144
      int h  = rr >> 14, off = rr & 16383;               // 16384 float4/head
      float4 v = ((const float4*)R)[((size_t)h << 15) + off];
      f16x4 o = { (_Float16)v.x, (_Float16)v.y, (_Float16)v.z, (_Float16)v.w };
      *(f16x4*)(R16 + 4 * (((size_t)h << 14) + off)) = o;
    }
  }
}

// ---------------- main flash kernel (R18) ----------------

__global__ __launch_bounds__(256, 3) void relpos_sdpa_r18(
    const float* __restrict__ Q, const _Float16* __restrict__ Kh,
    const short* __restrict__ Vtg, const _Float16* __restrict__ R16,
    const float* __restrict__ Ub, const float* __restrict__ Vb,
    float* __restrict__ O)
{
  const int n    = blockIdx.x;
  const int h    = n & (NHD - 1);
  const int a0   = blockIdx.y * 64;
  const int tid  = threadIdx.x;
  const int lane = tid & 63, wave = tid >> 6;
  const int l15  = lane & 15, quad = lane >> 4;

  const float*    Qn  = Q   + (size_t)n * SQ * HD;
  const _Float16* Khn = Kh  + (size_t)n * SQ * HD;
  const short*    Vgn = Vtg + (size_t)n * 80 * SQ;
  const _Float16* Rh  = R16 + (size_t)h * SQ * HD;

  // LDS: Kb f16 [2][64][64] swz   @ 0      (2 x 8192)
  //      Vt bf16 [2][64][64] swzv @ 16384  (2 x 8192)
  //      ring u32 [33][132]       @ 32768  (17424; cols 128..130 mirror 0..2)
  __shared__ __align__(16) char lds[50192];
  unsigned*       Pb2  = (unsigned*)(lds + 32768);
  const _Float16* Pb2h = (const _Float16*)Pb2;

  // DMA: linear LDS dest (slot = lane + 64*(2w+i)), pre-swizzled global src.
  auto gload16 = [&](const void* g, void* l) {
#if __has_builtin(__builtin_amdgcn_global_load_lds)
    __builtin_amdgcn_global_load_lds(
        (const __attribute__((address_space(1))) unsigned*)g,
        (__attribute__((address_space(3))) unsigned*)l, 16, 0, 0);
#else
    *(u32x4*)((char*)l + lane * 16) = *(const u32x4*)g;   // reg round-trip
#endif
  };
  auto dmaStage = [&](int kk, int buf) {
    const int rb = lane >> 3;
    const int g  = (lane & 7) ^ ((lane >> 3) & 7);
    char* kdst = lds + buf * 8192;
    char* vdst = lds + 16384 + buf * 8192;
#pragma unroll
    for (int i = 0; i < 2; ++i) {
      const int sub = 2*wave + i;
      const int r   = 8*sub + rb;
      gload16(Khn + (size_t)(kk + r) * HD + 8*g, kdst + sub * 1024);
      gload16(Vgn + (size_t)r * SQ + kk + 8*g,   vdst + sub * 1024);
    }
  };

  dmaStage(0, 0);   // tile 0 in flight under the whole prologue

  // ---- persistent q fragments, pre-scaled by log2(e) ----
  f16x8 quF[2], qvF[5][2];
#pragma unroll
  for (int ks = 0; ks < 2; ++ks) {
    const int db = ks * 32 + quad * 8;
    float ub[8], vb[8];
#pragma unroll
    for (int j = 0; j < 8; ++j) {
      ub[j] = Ub[h*HD + db + j] * L2E;
      vb[j] = Vb[h*HD + db + j] * L2E;
    }
    {
      const float* p = Qn + (size_t)(a0 + 16*wave + l15) * HD + db;
      float4 x0 = ((const float4*)p)[0], x1 = ((const float4*)p)[1];
      f16x8 f;
#pragma unroll
      for (int t = 0; t < 4; ++t) {
        f[t]   = (_Float16)((&x0.x)[t] * (0.125f * L2E) + ub[t]);
        f[t+4] = (_Float16)((&x1.x)[t] * (0.125f * L2E) + ub[t+4]);
      }
      quF[ks] = f;
    }
#pragma unroll
    for (int rt = 0; rt < 5; ++rt) {
      int row = a0 + 16*rt + l15; if (row > SQ-1) row = SQ-1;
      const float* p = Qn + (size_t)row * HD + db;
      float4 x0 = ((const float4*)p)[0], x1 = ((const float4*)p)[1];
      f16x8 f;
#pragma unroll
      for (int t = 0; t < 4; ++t) {
        f[t]   = (_Float16)((&x0.x)[t] * (0.125f * L2E) + vb[t]);
        f[t+4] = (_Float16)((&x1.x)[t] * (0.125f * L2E) + vb[t+4]);
      }
      qvF[rt][ks] = f;
    }
  }

  f32x4 Oacc[4], acc_l;
#pragma unroll
  for (int ct = 0; ct < 4; ++ct) Oacc[ct] = (f32x4){0.f, 0.f, 0.f, 0.f};
  acc_l = (f32x4){0.f, 0.f, 0.f, 0.f};

  const b16x4 ONESB = {(short)0x3F80, (short)0x3F80, (short)0x3F80, (short)0x3F80};

  // ---- band, split: bandLoad (issue R16 loads early) / bandMFMA (compute) ----
  unsigned ringW[9];
  int ringSlot, ringSlotN;
  f16x8 bB0, bB1;
  auto bandLoad = [&](int jstart) {
    const int c = jstart + 16*wave + l15;
    const int j = (c + 2048) & (SQ - 1);
    ringSlotN   = (c + 2048) & 127;
    const _Float16* rp = Rh + (size_t)j * HD + quad * 8;
    bB0 = *(const f16x8*)rp;
    bB1 = *(const f16x8*)(rp + 32);
  };
  auto bandMFMA = [&]() {
    ringSlot = ringSlotN;
    __builtin_amdgcn_s_setprio(1);
#pragma unroll
    for (int rt = 0; rt < 5; ++rt) {
      f32x4 acc = (f32x4){0.f, 0.f, 0.f, 0.f};
      acc = MFMA_F16(qvF[rt][0], bB0, acc);
      acc = MFMA_F16(qvF[rt][1], bB1, acc);
      if (rt < 4) {
        ringW[2*rt]     = pkh(acc[0], acc[1]);
        ringW[2*rt + 1] = pkh(acc[2], acc[3]);
      } else {
        ringW[8] = pkh(acc[0], acc[1]);   // row 64 (only quad 0's used)
      }
    }
    __builtin_amdgcn_s_setprio(0);
  };
  auto ringFlush = [&]() {
#pragma unroll
    for (int rt = 0; rt < 4; ++rt) {
      const int rp0 = 8*rt + 2*quad;                 // rows 16rt+4q .. +3
      Pb2[rp0*132 + ringSlot]       = ringW[2*rt];
      Pb2[(rp0 + 1)*132 + ringSlot] = ringW[2*rt + 1];
    }
    if (quad == 0) Pb2[32*132 + ringSlot] = ringW[8];
    if (ringSlot < 3) {                              // mirror cols 128..130
      const int ms = ringSlot + 128;
#pragma unroll
      for (int rt = 0; rt < 4; ++rt) {
        const int rp0 = 8*rt + 2*quad;
        Pb2[rp0*132 + ms]       = ringW[2*rt];
        Pb2[(rp0 + 1)*132 + ms] = ringW[2*rt + 1];
      }
      if (quad == 0) Pb2[32*132 + ms] = ringW[8];
    }
  };

  // prologue: fill all 128 ring slots for iter 0 (pre-loop, no races)
  bandLoad(-a0 - 65);  bandMFMA();  ringFlush();
  bandLoad(-a0 - 1);   bandMFMA();  ringFlush();

  const int iiB = 16*wave + 4*quad;
  const int iQ  = 16*wave + l15;          // this lane's q-local row (swapped)

  int cur = 0;
  for (int k0 = 0; k0 < SQ; k0 += 64) {
    // ---- barrier A: prev compute's LDS reads + ring gathers done ----
    __builtin_amdgcn_sched_barrier(0);
    asm volatile("s_waitcnt lgkmcnt(0)" ::: "memory");
    __builtin_amdgcn_s_barrier();
    __builtin_amdgcn_sched_barrier(0);

    if (k0 > 0) ringFlush();          // ring cols from prev iter's bandMFMA
    if (k0 < SQ - 64) {
      bandLoad(k0 + 64 - a0 - 1);     // 2 vmem (for this iter's bandMFMA)
      dmaStage(k0 + 64, cur ^ 1);     // 4 vmem -> other buffer
      __builtin_amdgcn_sched_barrier(0);
      asm volatile("s_waitcnt vmcnt(6) lgkmcnt(0)" ::: "memory");  // tile k0 done
    } else {
      __builtin_amdgcn_sched_barrier(0);
      asm volatile("s_waitcnt vmcnt(0) lgkmcnt(0)" ::: "memory");
    }
    // ---- barrier B: Kb/Vt[cur] staged + ring visible ----
    __builtin_amdgcn_s_barrier();
    __builtin_amdgcn_sched_barrier(0);

    const _Float16* Kb = (const _Float16*)(lds + (cur << 13));
    const short*    Vt = (const short*)(lds + 16384 + (cur << 13));

    // ---- HOISTED gather loads (fast path): no dependency on QK — issue
    //      before the MFMA cluster so LDS latency hides under matrix work ----
    const int  base  = k0 - a0 - 16*wave;
    const bool gFast = !(k0 == a0 || k0 == a0 + 64);
    unsigned gw[16];
    int shG = 0;
    if (gFast) {
      const int u  = (k0 > a0) ? 1 : 0;
      const int iu = iQ + u;
      const unsigned* wrow = &Pb2[(iu >> 1) * 132];
      shG = (iu & 1) << 4;
      const int sb = base - 1 - u + 4*quad - l15 + 2048;
#pragma unroll
      for (int ct = 0; ct < 4; ++ct) {
        const int s0 = (sb + 16*ct) & 127;
        gw[4*ct + 0] = wrow[s0];
        gw[4*ct + 1] = wrow[s0 + 1];
        gw[4*ct + 2] = wrow[s0 + 2];
        gw[4*ct + 3] = wrow[s0 + 3];
      }
    }

    // ---- content scores, SWAPPED: sc[ct][r] = S[key=16ct+4q+r][q=16w+l15] ----
    f32x4 sc[4];
    __builtin_amdgcn_s_setprio(1);
#pragma unroll
    for (int ct = 0; ct < 4; ++ct) {
      f16x8 ka = *(const f16x8*)&Kb[swz(16*ct + l15, quad*8)];
      f16x8 kb = *(const f16x8*)&Kb[swz(16*ct + l15, 32 + quad*8)];
      f32x4 acc = (f32x4){NSHIFT, NSHIFT, NSHIFT, NSHIFT};
      acc = MFMA_F16(ka, quF[0], acc);        // A = K-frag, B = Q-frag
      acc = MFMA_F16(kb, quF[1], acc);
      sc[ct] = acc;
    }
    __builtin_amdgcn_s_setprio(0);

    // ---- exp2 (fast path uses hoisted words; general path 2/16 iters) ----
    if (gFast) {
#pragma unroll
      for (int ct = 0; ct < 4; ++ct) {
        sc[ct][0] = exp2fast(sc[ct][0] + h2f(gw[4*ct + 0], shG));
        sc[ct][1] = exp2fast(sc[ct][1] + h2f(gw[4*ct + 1], shG));
        sc[ct][2] = exp2fast(sc[ct][2] + h2f(gw[4*ct + 2], shG));
        sc[ct][3] = exp2fast(sc[ct][3] + h2f(gw[4*ct + 3], shG));
      }
    } else {
      const int adA = (iQ >> 1) * 264 + (iQ & 1);                // u=0
      const int adB = ((iQ + 1) >> 1) * 264 + ((iQ + 1) & 1);    // u=1
#pragma unroll
      for (int ct = 0; ct < 4; ++ct) {
        const int e0 = base + 16*ct + 4*quad - l15;
#pragma unroll
        for (int r = 0; r < 4; ++r) {
          const int e    = e0 + r;
          const int u    = (e > 0) ? 1 : 0;
          const int slot = (e - 1 - u) & 127;
          float pos = (float)Pb2h[(u ? adB : adA) + 2*slot];
          float s   = sc[ct][r] + ((e == 1) ? 0.f : pos);
          sc[ct][r] = exp2fast(s);
        }
      }
    }

    // ---- PV straight from registers: 4x4 K=16 bf16 MFMAs + ones-l ----
    __builtin_amdgcn_s_setprio(1);
#pragma unroll
    for (int ctk = 0; ctk < 4; ++ctk) {
      unsigned lo = pkb2(sc[ctk][0], sc[ctk][1]);
      unsigned hi = pkb2(sc[ctk][2], sc[ctk][3]);
      b16x4 aF = __builtin_bit_cast(b16x4, (u32x2){lo, hi});
      acc_l = mfma16bf(aF, ONESB, acc_l);     // l partial (all cols equal)
#pragma unroll
      for (int ctd = 0; ctd < 4; ++ctd) {
        b16x4 bF = *(const b16x4*)&Vt[swzv(16*ctd + l15, 16*ctk + 4*quad)];
        Oacc[ctd] = mfma16bf(aF, bF, Oacc[ctd]);
      }
    }
    __builtin_amdgcn_s_setprio(0);

    if (k0 < SQ - 64) bandMFMA();     // next iter's 64 new ring cols (regs)
    cur ^= 1;
  }

  // ---- epilogue: O = Oacc / l, l in-lane from ones-MFMA ----
#pragma unroll
  for (int r = 0; r < 4; ++r) {
    float inv = 1.0f / acc_l[r];
    const size_t rowo = (size_t)n * SQ * HD + (size_t)(a0 + iiB + r) * HD;
#pragma unroll
    for (int ct = 0; ct < 4; ++ct)
      O[rowo + 16*ct + l15] = Oacc[ct][r] * inv;
  }
}

// ---------------- fallback (R3-style, raw inputs) for small ws ----------------

__global__ __launch_bounds__(256, 4) void relpos_sdpa_fb(
    const float* __restrict__ Q, const float* __restrict__ K,
    const float* __restrict__ V, const float* __restrict__ Ub,
    const float* __restrict__ Vb, const float* __restrict__ R,
    float* __restrict__ O)
{
  const int n    = blockIdx.x;
  const int h    = n & (NHD - 1);
  const int a0   = blockIdx.y * 64;
  const int tid  = threadIdx.x;
  const int lane = tid & 63, wave = tid >> 6;
  const int l15  = lane & 15, quad = lane >> 4;

  const float* Qn = Q + (size_t)n * SQ * HD;
  const float* Kn = K + (size_t)n * SQ * HD;
  const float* Vn = V + (size_t)n * SQ * HD;
  const float* Rh = R + (size_t)h * RMAX * HD;

  __shared__ __align__(16) char lds[38656];
  _Float16* Kb = (_Float16*)lds;
  short*    Ps = (short*)lds;
  short*    Vt = (short*)(lds + 9216);
  _Float16* Pb = (_Float16*)(lds + 9216 + 11520);

  f16x8 quF[2], qvF[5][2];
#pragma unroll
  for (int ks = 0; ks < 2; ++ks) {
    const int db = ks * 32 + quad * 8;
    float ub[8], vb[8];
#pragma unroll
    for (int j = 0; j < 8; ++j) { ub[j] = Ub[h*HD + db + j]; vb[j] = Vb[h*HD + db + j]; }
    {
      const float* p = Qn + (size_t)(a0 + 16*wave + l15) * HD + db;
      f16x8 f;
#pragma unroll
      for (int j = 0; j < 8; ++j) f[j] = (_Float16)(p[j] * 0.125f + ub[j]);
      quF[ks] = f;
    }
#pragma unroll
    for (int rt = 0; rt < 5; ++rt) {
      int row = a0 + 16*rt + l15; if (row > SQ-1) row = SQ-1;
      const float* p = Qn + (size_t)row * HD + db;
      f16x8 f;
#pragma unroll
      for (int j = 0; j < 8; ++j) f[j] = (_Float16)(p[j] * 0.125f + vb[j]);
      qvF[rt][ks] = f;
    }
  }

  if (tid < 64) Vt[64*72 + tid] = (short)0x3F80;

  f32x4 Oacc[5];
#pragma unroll
  for (int ct = 0; ct < 5; ++ct) Oacc[ct] = (f32x4){0.f, 0.f, 0.f, 0.f};

  auto band = [&](int jstart) {
    const int c    = jstart + 16*wave + l15;
    const int j    = (c + 2048) & (SQ - 1);
    const int slot = (c + 2048) & 127;
    const float* rp = Rh + (size_t)j * HD + quad * 8;
    f16x8 B0, B1;
    {
      float4 x0 = *(const float4*)(rp),      x1 = *(const float4*)(rp + 4);
      float4 y0 = *(const float4*)(rp + 32), y1 = *(const float4*)(rp + 36);
#pragma unroll
      for (int t = 0; t < 4; ++t) { B0[t] = (_Float16)(&x0.x)[t]; B0[t+4] = (_Float16)(&x1.x)[t]; }
#pragma unroll
      for (int t = 0; t < 4; ++t) { B1[t] = (_Float16)(&y0.x)[t]; B1[t+4] = (_Float16)(&y1.x)[t]; }
    }
#pragma unroll
    for (int rt = 0; rt < 5; ++rt) {
      f32x4 acc = (f32x4){0.f, 0.f, 0.f, 0.f};
      acc = MFMA_F16(qvF[rt][0], B0, acc);
      acc = MFMA_F16(qvF[rt][1], B1, acc);
      const int row = 16*rt + 4*quad;
      if (rt < 4) {
        *(unsigned*)&Pb[slot*70 + row]     = pkh(acc[0], acc[1]);
        *(unsigned*)&Pb[slot*70 + row + 2] = pkh(acc[2], acc[3]);
      } else if (quad == 0) {
        *(unsigned*)&Pb[slot*70 + row]     = pkh(acc[0], acc[1]);
      }
    }
  };

  band(-a0 - 65);
  band(-a0 - 1);

  const int sr = tid >> 2, sc4 = tid & 3;
  const int iiB = 16*wave + 4*quad;

  for (int k0 = 0; k0 < SQ; k0 += 64) {
    __syncthreads();
    {
      const float* src = Kn + (size_t)(k0 + sr) * HD + sc4 * 16;
      float4 x0 = *(const float4*)(src),     x1 = *(const float4*)(src + 4);
      float4 y0 = *(const float4*)(src + 8), y1 = *(const float4*)(src + 12);
      f16x8 lo, hi;
#pragma unroll
      for (int t = 0; t < 4; ++t) { lo[t] = (_Float16)(&x0.x)[t]; lo[t+4] = (_Float16)(&x1.x)[t]; }
#pragma unroll
      for (int t = 0; t < 4; ++t) { hi[t] = (_Float16)(&y0.x)[t]; hi[t+4] = (_Float16)(&y1.x)[t]; }
      *(f16x8*)&Kb[sr*72 + sc4*16]     = lo;
      *(f16x8*)&Kb[sr*72 + sc4*16 + 8] = hi;
    }
    {
      const int g = lane >> 3;
#pragma unroll
      for (int i = 0; i < 8; ++i) {
        int bp = 8*wave + (i ^ g);
        float v0 = Vn[(size_t)(k0 + 2*bp)     * HD + lane];
        float v1 = Vn[(size_t)(k0 + 2*bp + 1) * HD + lane];
        *(unsigned*)&Vt[lane*72 + 2*bp] = pkb2(v0, v1);
      }
    }
    __syncthreads();

    f32x4 sc[4];
#pragma unroll
    for (int ct = 0; ct < 4; ++ct) {
      f16x8 b0 = *(const f16x8*)&Kb[(16*ct + l15)*72 + quad*8];
      f16x8 b1 = *(const f16x8*)&Kb[(16*ct + l15)*72 + 32 + quad*8];
      f32x4 acc = (f32x4){0.f, 0.f, 0.f, 0.f};
      acc = MFMA_F16(quF[0], b0, acc);
      acc = MFMA_F16(quF[1], b1, acc);
      sc[ct] = acc;
    }

    const int dlt = k0 - a0;
#pragma unroll
    for (int r = 0; r < 4; ++r) {
      const int ii = iiB + r;
#pragma unroll
      for (int ct = 0; ct < 4; ++ct) {
        const int e    = dlt + 16*ct + l15 - ii;
        const int u    = (e > 0) ? 1 : 0;
        const int slot = (e - 1 - u + 2048) & 127;
        float pos = (float)Pb[slot*70 + ii + u];
        float s   = sc[ct][r] + ((e == 1) ? 0.f : pos);
        sc[ct][r] = __expf(s - 40.0f);
      }
    }
    __syncthreads();

#pragma unroll
    for (int r = 0; r < 4; ++r)
#pragma unroll
      for (int ct = 0; ct < 4; ++ct)
        Ps[(iiB + r)*68 + 16*ct + l15] = f2b(sc[ct][r]);

    b16x8 pA0 = *(const b16x8*)&Ps[(16*wave + l15)*68 + quad*8];
    b16x8 pA1 = *(const b16x8*)&Ps[(16*wave + l15)*68 + 32 + quad*8];
#pragma unroll
    for (int ct = 0; ct < 5; ++ct) {
      b16x8 v0 = *(const b16x8*)&Vt[(16*ct + l15)*72 + quad*8];
      b16x8 v1 = *(const b16x8*)&Vt[(16*ct + l15)*72 + 32 + quad*8];
      Oacc[ct] = MFMA_BF16(pA0, v0, Oacc[ct]);
      Oacc[ct] = MFMA_BF16(pA1, v1, Oacc[ct]);
    }

    if (k0 < SQ - 64) band(k0 + 64 - a0 - 1);
  }

#pragma unroll
  for (int r = 0; r < 4; ++r) {
    float l   = __shfl(Oacc[4][r], lane & 48);
    float inv = 1.0f / l;
    const size_t rowo = (size_t)n * SQ * HD + (size_t)(a0 + iiB + r) * HD;
#pragma unroll
    for (int ct = 0; ct < 4; ++ct)
      O[rowo + 16*ct + l15] = Oacc[ct][r] * inv;
  }
}

extern "C" void kernel_launch(void* const* d_in, const int* in_sizes, int n_in,
                              void* d_out, int out_size, void* d_ws, size_t ws_size,
                              hipStream_t stream) {
  const float* Q  = (const float*)d_in[0];
  const float* K  = (const float*)d_in[1];
  const float* V  = (const float*)d_in[2];
  const float* Ub = (const float*)d_in[3];  // (1,16,1,64)
  const float* Vb = (const float*)d_in[4];
  const float* R  = (const float*)d_in[5];  // (16,2048,64)
  float* O = (float*)d_out;

  if (ws_size >= WS_NEED) {
    _Float16* Kh  = (_Float16*)((char*)d_ws + KH_OFF);
    short*    Vt  = (short*)((char*)d_ws + VT_OFF);
    _Float16* R16 = (_Float16*)((char*)d_ws + R16_OFF);

    preprep<<<6144, 256, 0, stream>>>(K, R, V, Kh, R16, Vt);

    dim3 grid(64, 16);   // x = n (XCD locality), y = q-tile
    relpos_sdpa_r18<<<grid, 256, 0, stream>>>(Q, Kh, Vt, R16, Ub, Vb, O);
  } else {
    dim3 grid(64, 16);
    relpos_sdpa_fb<<<grid, 256, 0, stream>>>(Q, K, V, Ub, Vb, R, O);
  }
}